// Round 1
// baseline (1394.671 us; speedup 1.0000x reference)
//
#include <hip/hip_runtime.h>
#include <hip/hip_bf16.h>
#include <math.h>

#define NEG_SLOPE 0.2f

__device__ __forceinline__ float leaky(float x) { return x > 0.f ? x : NEG_SLOPE * x; }

// ---------------- GAT layer 1 linear: h1[N,128] = x[N,64] @ W1[64,128]
// plus per-(node,head) attention dots a_s1/a_d1 [N,2].
// block = 256 threads = 2 nodes x 128 outputs; each block loops 16 iters (32 nodes).
__global__ void k_h1(const float* __restrict__ x, const float* __restrict__ W1,
                     const float* __restrict__ att_src, const float* __restrict__ att_dst,
                     float* __restrict__ h1, float* __restrict__ a_s, float* __restrict__ a_d,
                     int N) {
  __shared__ __align__(16) float W1s[64 * 128];
  __shared__ __align__(16) float xs[2][64];
  for (int i = threadIdx.x; i < 64 * 128; i += 256) W1s[i] = W1[i];
  const int ln = threadIdx.x >> 7;   // which of the 2 nodes
  const int t  = threadIdx.x & 127;  // output channel 0..127
  const int head = t >> 6;
  const int c = t & 63;
  const float as_w = att_src[head * 64 + c];
  const float ad_w = att_dst[head * 64 + c];
  const int node0 = blockIdx.x * 32;
  for (int it = 0; it < 16; ++it) {
    const int n = node0 + it * 2 + ln;
    __syncthreads();
    if (t < 64 && n < N) xs[ln][t] = x[(size_t)n * 64 + t];
    __syncthreads();
    if (n >= N) continue;
    float acc = 0.f;
#pragma unroll
    for (int cc = 0; cc < 64; ++cc) acc = fmaf(xs[ln][cc], W1s[cc * 128 + t], acc);
    h1[(size_t)n * 128 + t] = acc;
    // wave = one (node, head): reduce 64 lanes
    float vs = acc * as_w;
    float vd = acc * ad_w;
#pragma unroll
    for (int off = 32; off > 0; off >>= 1) {
      vs += __shfl_down(vs, off, 64);
      vd += __shfl_down(vd, off, 64);
    }
    if (c == 0) { a_s[n * 2 + head] = vs; a_d[n * 2 + head] = vd; }
  }
}

// ---------------- CSR build ----------------
__global__ void k_zero_int(int* __restrict__ p, int n) {
  int i = blockIdx.x * 256 + threadIdx.x;
  if (i < n) p[i] = 0;
}

__global__ void k_copy_int(const int* __restrict__ a, int* __restrict__ b, int n) {
  int i = blockIdx.x * 256 + threadIdx.x;
  if (i < n) b[i] = a[i];
}

// degree count over E real edges + N self loops
__global__ void k_deg(const int* __restrict__ dst, int E, int N, int* __restrict__ deg) {
  int e = blockIdx.x * 256 + threadIdx.x;
  if (e < E + N) {
    int d = (e < E) ? dst[e] : (e - E);
    atomicAdd(&deg[d], 1);
  }
}

// single-block exclusive scan of deg[N] -> rowptr[N+1]
__global__ void k_scan(const int* __restrict__ deg, int* __restrict__ rowptr, int N) {
  __shared__ int sums[1024];
  const int tid = threadIdx.x;
  const int chunk = (N + 1023) / 1024;
  const int start = min(tid * chunk, N);
  const int end = min(start + chunk, N);
  int s = 0;
  for (int i = start; i < end; ++i) s += deg[i];
  sums[tid] = s;
  __syncthreads();
  for (int off = 1; off < 1024; off <<= 1) {
    int v = (tid >= off) ? sums[tid - off] : 0;
    __syncthreads();
    sums[tid] += v;
    __syncthreads();
  }
  int excl = (tid == 0) ? 0 : sums[tid - 1];
  for (int i = start; i < end; ++i) { rowptr[i] = excl; excl += deg[i]; }
  if (tid == 1023) rowptr[N] = sums[1023];
}

__global__ void k_fill(const int* __restrict__ src, const int* __restrict__ dst, int E, int N,
                       int* __restrict__ cursor, int* __restrict__ adj) {
  int e = blockIdx.x * 256 + threadIdx.x;
  if (e < E + N) {
    int s, d;
    if (e < E) { s = src[e]; d = dst[e]; } else { s = d = e - E; }
    int pos = atomicAdd(&cursor[d], 1);
    adj[pos] = s;
  }
}

// ---------------- GAT layer 1 aggregate ----------------
// wave per dst node; lane l owns channels 2l,2l+1 (head = l/32).
// g = elu( (sum_e exp(e)*h1[src]) / (sum_e exp(e)) + b1 )
__global__ void k_gat1(const float* __restrict__ h1, const float* __restrict__ as1,
                       const float* __restrict__ ad1, const int* __restrict__ rowptr,
                       const int* __restrict__ adj, const float* __restrict__ b1,
                       float* __restrict__ g, int N) {
  const int w = threadIdx.x >> 6;
  const int l = threadIdx.x & 63;
  const int n = blockIdx.x * 4 + w;
  if (n >= N) return;
  const int head = l >> 5;
  const float adh = ad1[n * 2 + head];
  const float2* __restrict__ h12 = (const float2*)h1;
  float2 acc = make_float2(0.f, 0.f);
  float dsum = 0.f;
  const int kb = rowptr[n], ke = rowptr[n + 1];
  for (int k = kb; k < ke; ++k) {
    const int s = adj[k];
    float e = as1[s * 2 + head] + adh;
    e = leaky(e);
    const float wgt = expf(e);
    dsum += wgt;
    const float2 v = h12[(size_t)s * 64 + l];
    acc.x = fmaf(wgt, v.x, acc.x);
    acc.y = fmaf(wgt, v.y, acc.y);
  }
  const float inv = 1.f / (dsum + 1e-16f);
  const float2 bv = ((const float2*)b1)[l];
  float gx = acc.x * inv + bv.x;
  float gy = acc.y * inv + bv.y;
  gx = gx > 0.f ? gx : expm1f(gx);
  gy = gy > 0.f ? gy : expm1f(gy);
  ((float2*)g)[(size_t)n * 64 + l] = make_float2(gx, gy);
}

// ---------------- GAT layer 2 linear: h2[N,64] = g[N,128] @ W2[128,64]
__global__ void k_h2(const float* __restrict__ g, const float* __restrict__ W2,
                     const float* __restrict__ att_s, const float* __restrict__ att_d,
                     float* __restrict__ h2, float* __restrict__ a_s, float* __restrict__ a_d,
                     int N) {
  __shared__ __align__(16) float W2s[128 * 64];
  __shared__ __align__(16) float gs[4][128];
  for (int i = threadIdx.x; i < 128 * 64; i += 256) W2s[i] = W2[i];
  const int w = threadIdx.x >> 6, l = threadIdx.x & 63;
  const float as_w = att_s[l], ad_w = att_d[l];
  const int node0 = blockIdx.x * 32;
  for (int it = 0; it < 8; ++it) {
    const int nb = node0 + it * 4;
    __syncthreads();
    for (int i = threadIdx.x; i < 512; i += 256) {
      int nn = nb + (i >> 7);
      if (nn < N) gs[i >> 7][i & 127] = g[(size_t)nn * 128 + (i & 127)];
    }
    __syncthreads();
    const int n = nb + w;
    if (n >= N) continue;
    float acc = 0.f;
#pragma unroll
    for (int cc = 0; cc < 128; ++cc) acc = fmaf(gs[w][cc], W2s[cc * 64 + l], acc);
    h2[(size_t)n * 64 + l] = acc;
    float vs = acc * as_w, vd = acc * ad_w;
#pragma unroll
    for (int off = 32; off > 0; off >>= 1) {
      vs += __shfl_down(vs, off, 64);
      vd += __shfl_down(vd, off, 64);
    }
    if (l == 0) { a_s[n] = vs; a_d[n] = vd; }
  }
}

// ---------------- GAT layer 2 aggregate (no elu, bias b2) ----------------
__global__ void k_gat2(const float* __restrict__ h2, const float* __restrict__ as2,
                       const float* __restrict__ ad2, const int* __restrict__ rowptr,
                       const int* __restrict__ adj, const float* __restrict__ b2,
                       float* __restrict__ g2, int N) {
  const int w = threadIdx.x >> 6;
  const int l = threadIdx.x & 63;
  const int n = blockIdx.x * 4 + w;
  if (n >= N) return;
  const float adh = ad2[n];
  float acc = 0.f, dsum = 0.f;
  const int kb = rowptr[n], ke = rowptr[n + 1];
  for (int k = kb; k < ke; ++k) {
    const int s = adj[k];
    float e = as2[s] + adh;
    e = leaky(e);
    const float wgt = expf(e);
    dsum += wgt;
    acc = fmaf(wgt, h2[(size_t)s * 64 + l], acc);
  }
  g2[(size_t)n * 64 + l] = acc / (dsum + 1e-16f) + b2[l];
}

// ---------------- build x matrix [B, 256] ----------------
__global__ void k_xmat(const int* __restrict__ user_idx, const int* __restrict__ ctx_idx,
                       const float* __restrict__ user_emb, const float* __restrict__ g2,
                       float* __restrict__ xmat) {
  const int b = blockIdx.x;
  const int k = threadIdx.x;  // 0..255
  float v;
  if (k < 64) {
    v = user_emb[(size_t)user_idx[b] * 64 + k];
  } else {
    const int c = (k - 64) >> 6;
    v = g2[(size_t)ctx_idx[b * 3 + c] * 64 + (k & 63)];
  }
  xmat[b * 256 + k] = v;
}

// ---------------- final FC: out[B, NSRV] = xmat[B,256] @ fc_w[256,NSRV] + fc_b
// block = 256 threads; tile 64 rows x 256 cols; thread tile 8x8.
__global__ void k_fc(const float* __restrict__ xmat, const float* __restrict__ fc_w,
                     const float* __restrict__ fc_b, float* __restrict__ out, int NSRV) {
  __shared__ __align__(16) float wt[32][256];
  __shared__ __align__(16) float xsT[32][64];
  const int j0 = blockIdx.x * 256;
  const int r0 = blockIdx.y * 64;
  const int tid = threadIdx.x;
  const int tr = tid >> 5;   // 0..7 row-group
  const int tc = tid & 31;   // 0..31 col-group
  float acc[8][8];
#pragma unroll
  for (int i = 0; i < 8; ++i)
#pragma unroll
    for (int j = 0; j < 8; ++j) acc[i][j] = 0.f;

  for (int k0 = 0; k0 < 256; k0 += 32) {
    __syncthreads();
    // stage fc_w tile [32 k][256 j]
    {
      const int j = j0 + tid;
      const bool ok = (j < NSRV);
#pragma unroll
      for (int kk = 0; kk < 32; ++kk)
        wt[kk][tid] = ok ? fc_w[(size_t)(k0 + kk) * NSRV + j] : 0.f;
    }
    // stage x^T tile [32 k][64 r]
    for (int idx = tid; idx < 32 * 64; idx += 256) {
      const int kk = idx >> 6, r = idx & 63;
      xsT[kk][r] = xmat[(r0 + r) * 256 + k0 + kk];
    }
    __syncthreads();
#pragma unroll
    for (int kk = 0; kk < 32; ++kk) {
      const float4 xa = *(const float4*)&xsT[kk][tr * 8];
      const float4 xb = *(const float4*)&xsT[kk][tr * 8 + 4];
      const float4 wa = *(const float4*)&wt[kk][tc * 8];
      const float4 wb = *(const float4*)&wt[kk][tc * 8 + 4];
      const float xr[8] = {xa.x, xa.y, xa.z, xa.w, xb.x, xb.y, xb.z, xb.w};
      const float wc[8] = {wa.x, wa.y, wa.z, wa.w, wb.x, wb.y, wb.z, wb.w};
#pragma unroll
      for (int i = 0; i < 8; ++i)
#pragma unroll
        for (int j = 0; j < 8; ++j) acc[i][j] = fmaf(xr[i], wc[j], acc[i][j]);
    }
  }
#pragma unroll
  for (int i = 0; i < 8; ++i) {
    const int r = r0 + tr * 8 + i;
#pragma unroll
    for (int jj = 0; jj < 8; ++jj) {
      const int j = j0 + tc * 8 + jj;
      if (j < NSRV) out[(size_t)r * NSRV + j] = acc[i][jj] + fc_b[j];
    }
  }
}

// =====================================================================
extern "C" void kernel_launch(void* const* d_in, const int* in_sizes, int n_in,
                              void* d_out, int out_size, void* d_ws, size_t ws_size,
                              hipStream_t stream) {
  const int* user_idx    = (const int*)d_in[0];
  const int* context_idx = (const int*)d_in[1];
  const int* edge_index  = (const int*)d_in[2];
  const float* user_emb  = (const float*)d_in[3];
  const float* service_emb = (const float*)d_in[4];
  const float* W1        = (const float*)d_in[5];
  const float* att_src1  = (const float*)d_in[6];
  const float* att_dst1  = (const float*)d_in[7];
  const float* b1        = (const float*)d_in[8];
  const float* W2        = (const float*)d_in[9];
  const float* att_src2  = (const float*)d_in[10];
  const float* att_dst2  = (const float*)d_in[11];
  const float* b2        = (const float*)d_in[12];
  const float* fc_w      = (const float*)d_in[13];
  const float* fc_b      = (const float*)d_in[14];
  float* out = (float*)d_out;

  const int B    = in_sizes[0];
  const int E    = in_sizes[2] / 2;
  const int N    = in_sizes[4] / 64;  // service nodes
  const int NSRV = in_sizes[14];
  const int Etot = E + N;

  const int* edge_src = edge_index;
  const int* edge_dst = edge_index + E;

  // ---- workspace layout ----
  char* ws = (char*)d_ws;
  size_t off = 0;
  auto alloc = [&](size_t bytes) {
    void* p = ws + off;
    off = (off + bytes + 255) & ~(size_t)255;
    return p;
  };
  float* h1     = (float*)alloc((size_t)N * 128 * 4);  // reused as h2
  float* g      = (float*)alloc((size_t)N * 128 * 4);  // reused as g2
  float* as1    = (float*)alloc((size_t)N * 2 * 4);
  float* ad1    = (float*)alloc((size_t)N * 2 * 4);
  float* as2    = (float*)alloc((size_t)N * 4);
  float* ad2    = (float*)alloc((size_t)N * 4);
  int*   deg    = (int*)alloc((size_t)N * 4);
  int*   rowptr = (int*)alloc((size_t)(N + 1) * 4);
  int*   cursor = (int*)alloc((size_t)N * 4);
  int*   adj    = (int*)alloc((size_t)Etot * 4);
  float* xmat   = (float*)alloc((size_t)B * 256 * 4);
  float* h2 = h1;
  float* g2 = g;
  (void)ws_size;

  const int nblk_N   = (N + 255) / 256;
  const int nblk_E   = (Etot + 255) / 256;

  // GAT layer 1 linear (independent of CSR build)
  k_h1<<<(N + 31) / 32, 256, 0, stream>>>(service_emb, W1, att_src1, att_dst1, h1, as1, ad1, N);

  // CSR build
  k_zero_int<<<nblk_N, 256, 0, stream>>>(deg, N);
  k_deg<<<nblk_E, 256, 0, stream>>>(edge_dst, E, N, deg);
  k_scan<<<1, 1024, 0, stream>>>(deg, rowptr, N);
  k_copy_int<<<nblk_N, 256, 0, stream>>>(rowptr, cursor, N);
  k_fill<<<nblk_E, 256, 0, stream>>>(edge_src, edge_dst, E, N, cursor, adj);

  // layer 1 aggregate -> g (elu'd)
  k_gat1<<<(N + 3) / 4, 256, 0, stream>>>(h1, as1, ad1, rowptr, adj, b1, g, N);

  // layer 2 linear (h2 overlays h1: h1 dead now)
  k_h2<<<(N + 31) / 32, 256, 0, stream>>>(g, W2, att_src2, att_dst2, h2, as2, ad2, N);

  // layer 2 aggregate -> g2 (overlays g: g dead now)
  k_gat2<<<(N + 3) / 4, 256, 0, stream>>>(h2, as2, ad2, rowptr, adj, b2, g2, N);

  // gather features
  k_xmat<<<B, 256, 0, stream>>>(user_idx, context_idx, user_emb, g2, xmat);

  // final FC
  dim3 fgrid((NSRV + 255) / 256, B / 64);
  k_fc<<<fgrid, 256, 0, stream>>>(xmat, fc_w, fc_b, out, NSRV);
}

// Round 2
// 1108.107 us; speedup vs baseline: 1.2586x; 1.2586x over previous
//
#include <hip/hip_runtime.h>
#include <hip/hip_bf16.h>
#include <math.h>

#define NEG_SLOPE 0.2f

typedef __attribute__((ext_vector_type(8))) short short8;
typedef __attribute__((ext_vector_type(4))) float f32x4;

__device__ __forceinline__ float leaky(float x) { return x > 0.f ? x : NEG_SLOPE * x; }

__device__ __forceinline__ unsigned short f2bf(float f) {
  unsigned u = __float_as_uint(f);
  unsigned r = (u + 0x7FFFu + ((u >> 16) & 1u)) >> 16;  // RNE
  return (unsigned short)r;
}

// ---------------- GAT layer 1 linear: h1[N,128] = x[N,64] @ W1[64,128]
// W column in registers (64 VGPR), x row broadcast from LDS. VALU-bound.
__global__ void k_h1(const float* __restrict__ x, const float* __restrict__ W1,
                     const float* __restrict__ att_src, const float* __restrict__ att_dst,
                     float* __restrict__ h1, float* __restrict__ a_s, float* __restrict__ a_d,
                     int N) {
  __shared__ __align__(16) float W1s[64 * 128];
  __shared__ __align__(16) float xs[2][64];
  for (int i = threadIdx.x; i < 64 * 128; i += 256) W1s[i] = W1[i];
  const int ln  = threadIdx.x >> 7;   // node slot 0/1
  const int col = threadIdx.x & 127;  // output channel
  const int head = col >> 6;
  const int c = col & 63;
  const float as_w = att_src[head * 64 + c];
  const float ad_w = att_dst[head * 64 + c];
  __syncthreads();
  float wreg[64];
#pragma unroll
  for (int cc = 0; cc < 64; ++cc) wreg[cc] = W1s[cc * 128 + col];

  const int node0 = blockIdx.x * 32;
  for (int it = 0; it < 16; ++it) {
    const int nbase = node0 + it * 2;
    __syncthreads();
    if (threadIdx.x < 128) {
      const int nn = nbase + (threadIdx.x >> 6);
      if (nn < N) xs[threadIdx.x >> 6][threadIdx.x & 63] = x[(size_t)nn * 64 + (threadIdx.x & 63)];
    }
    __syncthreads();
    const int n = nbase + ln;
    if (n >= N) continue;
    float acc = 0.f;
#pragma unroll
    for (int q = 0; q < 16; ++q) {
      const float4 xv = *(const float4*)&xs[ln][q * 4];
      acc = fmaf(xv.x, wreg[q * 4 + 0], acc);
      acc = fmaf(xv.y, wreg[q * 4 + 1], acc);
      acc = fmaf(xv.z, wreg[q * 4 + 2], acc);
      acc = fmaf(xv.w, wreg[q * 4 + 3], acc);
    }
    h1[(size_t)n * 128 + col] = acc;
    float vs = acc * as_w;
    float vd = acc * ad_w;
#pragma unroll
    for (int off = 32; off > 0; off >>= 1) {
      vs += __shfl_down(vs, off, 64);
      vd += __shfl_down(vd, off, 64);
    }
    if (c == 0) { a_s[n * 2 + head] = vs; a_d[n * 2 + head] = vd; }
  }
}

// ---------------- CSR build ----------------
__global__ void k_zero_int(int* __restrict__ p, int n) {
  int i = blockIdx.x * 256 + threadIdx.x;
  if (i < n) p[i] = 0;
}

__global__ void k_deg(const int* __restrict__ dst, int E, int N, int* __restrict__ deg) {
  int e = blockIdx.x * 256 + threadIdx.x;
  if (e < E + N) {
    int d = (e < E) ? dst[e] : (e - E);
    atomicAdd(&deg[d], 1);
  }
}

// exclusive scan; writes rowptr[N+1] and a second copy into cursor[N]
__global__ void k_scan(const int* __restrict__ deg, int* __restrict__ rowptr,
                       int* __restrict__ cursor, int N) {
  __shared__ int sums[1024];
  const int tid = threadIdx.x;
  const int chunk = (N + 1023) / 1024;
  const int start = min(tid * chunk, N);
  const int end = min(start + chunk, N);
  int s = 0;
  for (int i = start; i < end; ++i) s += deg[i];
  sums[tid] = s;
  __syncthreads();
  for (int off = 1; off < 1024; off <<= 1) {
    int v = (tid >= off) ? sums[tid - off] : 0;
    __syncthreads();
    sums[tid] += v;
    __syncthreads();
  }
  int excl = (tid == 0) ? 0 : sums[tid - 1];
  for (int i = start; i < end; ++i) {
    rowptr[i] = excl; cursor[i] = excl; excl += deg[i];
  }
  if (tid == 1023) rowptr[N] = sums[1023];
}

// fill CSR; also precompute layer-1 edge weights (both heads) and store dst per slot
__global__ void k_fill(const int* __restrict__ src, const int* __restrict__ dst, int E, int N,
                       int* __restrict__ cursor, int* __restrict__ adj, int* __restrict__ dstc,
                       const float* __restrict__ as1, const float* __restrict__ ad1,
                       float2* __restrict__ ew1) {
  int e = blockIdx.x * 256 + threadIdx.x;
  if (e < E + N) {
    int s, d;
    if (e < E) { s = src[e]; d = dst[e]; } else { s = d = e - E; }
    int pos = atomicAdd(&cursor[d], 1);
    adj[pos] = s;
    dstc[pos] = d;
    float2 w;
    w.x = expf(leaky(as1[s * 2 + 0] + ad1[d * 2 + 0]));
    w.y = expf(leaky(as1[s * 2 + 1] + ad1[d * 2 + 1]));
    ew1[pos] = w;
  }
}

// ---------------- GAT layer 1 aggregate ----------------
__global__ void k_gat1(const float* __restrict__ h1, const float2* __restrict__ ew1,
                       const int* __restrict__ rowptr, const int* __restrict__ adj,
                       const float* __restrict__ b1, float* __restrict__ g, int N) {
  const int w = threadIdx.x >> 6;
  const int l = threadIdx.x & 63;
  const int n = blockIdx.x * 4 + w;
  if (n >= N) return;
  const int head = l >> 5;
  const float2* __restrict__ h12 = (const float2*)h1;
  float2 acc = make_float2(0.f, 0.f);
  float dsum = 0.f;
  const int kb = rowptr[n], ke = rowptr[n + 1];
  for (int k = kb; k < ke; ++k) {
    const int s = adj[k];
    const float2 wpair = ew1[k];
    const float wgt = head ? wpair.y : wpair.x;
    dsum += wgt;
    const float2 v = h12[(size_t)s * 64 + l];
    acc.x = fmaf(wgt, v.x, acc.x);
    acc.y = fmaf(wgt, v.y, acc.y);
  }
  const float inv = 1.f / (dsum + 1e-16f);
  const float2 bv = ((const float2*)b1)[l];
  float gx = acc.x * inv + bv.x;
  float gy = acc.y * inv + bv.y;
  gx = gx > 0.f ? gx : expm1f(gx);
  gy = gy > 0.f ? gy : expm1f(gy);
  ((float2*)g)[(size_t)n * 64 + l] = make_float2(gx, gy);
}

// ---------------- GAT layer 2 linear: h2[N,64] = g[N,128] @ W2[128,64]
// split-K: thread owns (node slot, k-half, col); W half-column in 64 VGPRs.
__global__ void k_h2(const float* __restrict__ g, const float* __restrict__ W2,
                     const float* __restrict__ att_s, const float* __restrict__ att_d,
                     float* __restrict__ h2, float* __restrict__ a_s, float* __restrict__ a_d,
                     int N) {
  __shared__ __align__(16) float W2s[128 * 64];
  __shared__ __align__(16) float gs[2][128];
  __shared__ float part[2][64];
  for (int i = threadIdx.x; i < 128 * 64; i += 256) W2s[i] = W2[i];
  const int col = threadIdx.x & 63;
  const int kh  = (threadIdx.x >> 6) & 1;
  const int ln  = threadIdx.x >> 7;
  const float as_w = att_s[col], ad_w = att_d[col];
  __syncthreads();
  float wreg[64];
#pragma unroll
  for (int cc = 0; cc < 64; ++cc) wreg[cc] = W2s[(kh * 64 + cc) * 64 + col];

  const int node0 = blockIdx.x * 32;
  for (int it = 0; it < 16; ++it) {
    const int nbase = node0 + it * 2;
    __syncthreads();
    {
      const int nn = nbase + (threadIdx.x >> 7);
      if (nn < N) gs[threadIdx.x >> 7][threadIdx.x & 127] = g[(size_t)nn * 128 + (threadIdx.x & 127)];
    }
    __syncthreads();
    const int n = nbase + ln;
    float acc = 0.f;
    if (n < N) {
#pragma unroll
      for (int q = 0; q < 16; ++q) {
        const float4 gv = *(const float4*)&gs[ln][kh * 64 + q * 4];
        acc = fmaf(gv.x, wreg[q * 4 + 0], acc);
        acc = fmaf(gv.y, wreg[q * 4 + 1], acc);
        acc = fmaf(gv.z, wreg[q * 4 + 2], acc);
        acc = fmaf(gv.w, wreg[q * 4 + 3], acc);
      }
    }
    if (kh == 1) part[ln][col] = acc;
    __syncthreads();
    if (kh == 0 && n < N) {
      acc += part[ln][col];
      h2[(size_t)n * 64 + col] = acc;
      float vs = acc * as_w, vd = acc * ad_w;
#pragma unroll
      for (int off = 32; off > 0; off >>= 1) {
        vs += __shfl_down(vs, off, 64);
        vd += __shfl_down(vd, off, 64);
      }
      if (col == 0) { a_s[n] = vs; a_d[n] = vd; }
    }
  }
}

// layer-2 edge weights
__global__ void k_ew2(const int* __restrict__ adj, const int* __restrict__ dstc,
                      const float* __restrict__ as2, const float* __restrict__ ad2,
                      float* __restrict__ ew2, int Etot) {
  int e = blockIdx.x * 256 + threadIdx.x;
  if (e < Etot) ew2[e] = expf(leaky(as2[adj[e]] + ad2[dstc[e]]));
}

// ---------------- GAT layer 2 aggregate ----------------
__global__ void k_gat2(const float* __restrict__ h2, const float* __restrict__ ew2,
                       const int* __restrict__ rowptr, const int* __restrict__ adj,
                       const float* __restrict__ b2, float* __restrict__ g2, int N) {
  const int w = threadIdx.x >> 6;
  const int l = threadIdx.x & 63;
  const int n = blockIdx.x * 4 + w;
  if (n >= N) return;
  float acc = 0.f, dsum = 0.f;
  const int kb = rowptr[n], ke = rowptr[n + 1];
  for (int k = kb; k < ke; ++k) {
    const int s = adj[k];
    const float wgt = ew2[k];
    dsum += wgt;
    acc = fmaf(wgt, h2[(size_t)s * 64 + l], acc);
  }
  g2[(size_t)n * 64 + l] = acc / (dsum + 1e-16f) + b2[l];
}

// ---------------- build x matrix, bf16, K-blocked: xb[k/32][512][32] ----------------
__global__ void k_xmat(const int* __restrict__ user_idx, const int* __restrict__ ctx_idx,
                       const float* __restrict__ user_emb, const float* __restrict__ g2,
                       unsigned short* __restrict__ xb) {
  const int b = blockIdx.x;
  const int k = threadIdx.x;  // 0..255
  float v;
  if (k < 64) {
    v = user_emb[(size_t)user_idx[b] * 64 + k];
  } else {
    const int c = (k - 64) >> 6;
    v = g2[(size_t)ctx_idx[b * 3 + c] * 64 + (k & 63)];
  }
  xb[(size_t)(k >> 5) * (512 * 32) + b * 32 + (k & 31)] = f2bf(v);
}

// ---------------- final FC via MFMA: out[512, NSRV] = x[512,256] @ fc_w[256,NSRV] + fc_b
// BM=512 (whole batch, fc_w fetched once), BN=32, BK=32, 4 waves.
// LDS rows padded to 80 B -> bank stride 20 words -> 2-way (free).
__global__ __launch_bounds__(256) void k_fc(const unsigned short* __restrict__ xb,
                                            const float* __restrict__ fc_w,
                                            const float* __restrict__ fc_b,
                                            float* __restrict__ out, int NSRV, int nk) {
  __shared__ __align__(16) unsigned char smem[512 * 80 + 32 * 80];
  char* As = (char*)smem;            // [512 rows][80 B]: 32 bf16 k-vals + pad
  char* Bs = (char*)smem + 512 * 80; // [32 cols][80 B]: 32 bf16 k-vals + pad

  const int tid = threadIdx.x;
  const int lane = tid & 63;
  const int wv = tid >> 6;
  const int nf = wv & 1;        // N-fragment (0/1) -> col offset 16*nf
  const int mh = wv >> 1;       // M-half (0/1) -> row offset 256*mh
  const int j0 = blockIdx.x * 32;
  if (j0 >= NSRV) return;
  const bool full = (j0 + 32 <= NSRV);

  f32x4 acc[16];
#pragma unroll
  for (int i = 0; i < 16; ++i) acc[i] = (f32x4){0.f, 0.f, 0.f, 0.f};

  const int l15 = lane & 15;
  const int kg = lane >> 4;  // k-group 0..3 (8 bf16 each)

  for (int ks = 0; ks < nk; ++ks) {
    __syncthreads();
    // stage A: contiguous 32 KB block of xb -> LDS padded rows
    {
      const uint4* srcA = (const uint4*)(xb + (size_t)ks * 16384);
#pragma unroll
      for (int i = 0; i < 8; ++i) {
        const int idx = tid + i * 256;                 // 16B-chunk index, 0..2047
        const uint4 v = srcA[idx];
        *(uint4*)(As + (idx >> 2) * 80 + (idx & 3) * 16) = v;
      }
    }
    // stage B: fc_w[k0..k0+31][j0..j0+31] f32 -> bf16, transposed to [col][k]
    {
      const int kk = tid >> 3;            // 0..31
      const int c4 = (tid & 7) * 4;       // 0,4,..28
      const float* wp = fc_w + (size_t)(ks * 32 + kk) * NSRV + j0 + c4;
      float4 wvv;
      if (full) {
        wvv = *(const float4*)wp;
      } else {
        wvv.x = (j0 + c4 + 0 < NSRV) ? wp[0] : 0.f;
        wvv.y = (j0 + c4 + 1 < NSRV) ? wp[1] : 0.f;
        wvv.z = (j0 + c4 + 2 < NSRV) ? wp[2] : 0.f;
        wvv.w = (j0 + c4 + 3 < NSRV) ? wp[3] : 0.f;
      }
      *(unsigned short*)(Bs + (c4 + 0) * 80 + kk * 2) = f2bf(wvv.x);
      *(unsigned short*)(Bs + (c4 + 1) * 80 + kk * 2) = f2bf(wvv.y);
      *(unsigned short*)(Bs + (c4 + 2) * 80 + kk * 2) = f2bf(wvv.z);
      *(unsigned short*)(Bs + (c4 + 3) * 80 + kk * 2) = f2bf(wvv.w);
    }
    __syncthreads();
    // compute: 16 M-frags per wave
    const short8 bfr = *(const short8*)(Bs + (nf * 16 + l15) * 80 + kg * 16);
    const char* abase = As + (mh * 256 + l15) * 80 + kg * 16;
#pragma unroll
    for (int mf = 0; mf < 16; ++mf) {
      const short8 afr = *(const short8*)(abase + mf * (16 * 80));
      acc[mf] = __builtin_amdgcn_mfma_f32_16x16x32_bf16(afr, bfr, acc[mf], 0, 0, 0);
    }
  }

  // epilogue
  const int n = j0 + nf * 16 + l15;
  if (n < NSRV) {
    const float bias = fc_b[n];
    const int rbase = mh * 256 + kg * 4;
#pragma unroll
    for (int mf = 0; mf < 16; ++mf) {
#pragma unroll
      for (int r = 0; r < 4; ++r) {
        out[(size_t)(rbase + mf * 16 + r) * NSRV + n] = acc[mf][r] + bias;
      }
    }
  }
}

// =====================================================================
extern "C" void kernel_launch(void* const* d_in, const int* in_sizes, int n_in,
                              void* d_out, int out_size, void* d_ws, size_t ws_size,
                              hipStream_t stream) {
  const int* user_idx    = (const int*)d_in[0];
  const int* context_idx = (const int*)d_in[1];
  const int* edge_index  = (const int*)d_in[2];
  const float* user_emb  = (const float*)d_in[3];
  const float* service_emb = (const float*)d_in[4];
  const float* W1        = (const float*)d_in[5];
  const float* att_src1  = (const float*)d_in[6];
  const float* att_dst1  = (const float*)d_in[7];
  const float* b1        = (const float*)d_in[8];
  const float* W2        = (const float*)d_in[9];
  const float* att_src2  = (const float*)d_in[10];
  const float* att_dst2  = (const float*)d_in[11];
  const float* b2        = (const float*)d_in[12];
  const float* fc_w      = (const float*)d_in[13];
  const float* fc_b      = (const float*)d_in[14];
  float* out = (float*)d_out;

  const int B    = in_sizes[0];
  const int E    = in_sizes[2] / 2;
  const int N    = in_sizes[4] / 64;
  const int NSRV = in_sizes[14];
  const int Etot = E + N;
  (void)B;

  const int* edge_src = edge_index;
  const int* edge_dst = edge_index + E;

  // ---- workspace layout ----
  char* ws = (char*)d_ws;
  size_t off = 0;
  auto alloc = [&](size_t bytes) {
    void* p = ws + off;
    off = (off + bytes + 255) & ~(size_t)255;
    return p;
  };
  float* h1     = (float*)alloc((size_t)N * 128 * 4);  // reused as h2
  float* g      = (float*)alloc((size_t)N * 128 * 4);  // reused as g2
  float* as1    = (float*)alloc((size_t)N * 2 * 4);
  float* ad1    = (float*)alloc((size_t)N * 2 * 4);
  float* as2    = (float*)alloc((size_t)N * 4);
  float* ad2    = (float*)alloc((size_t)N * 4);
  int*   deg    = (int*)alloc((size_t)N * 4);
  int*   rowptr = (int*)alloc((size_t)(N + 1) * 4);
  int*   cursor = (int*)alloc((size_t)N * 4);
  int*   adj    = (int*)alloc((size_t)Etot * 4);
  int*   dstc   = (int*)alloc((size_t)Etot * 4);
  float2* ew1   = (float2*)alloc((size_t)Etot * 8);    // reused as ew2
  unsigned short* xb = (unsigned short*)alloc((size_t)512 * 256 * 2);
  float* h2 = h1;
  float* g2 = g;
  float* ew2 = (float*)ew1;
  (void)ws_size;

  const int nblk_N = (N + 255) / 256;
  const int nblk_E = (Etot + 255) / 256;

  // GAT layer 1 linear
  k_h1<<<(N + 31) / 32, 256, 0, stream>>>(service_emb, W1, att_src1, att_dst1, h1, as1, ad1, N);

  // CSR build (k_fill also needs as1/ad1 -> after k_h1, stream-ordered)
  k_zero_int<<<nblk_N, 256, 0, stream>>>(deg, N);
  k_deg<<<nblk_E, 256, 0, stream>>>(edge_dst, E, N, deg);
  k_scan<<<1, 1024, 0, stream>>>(deg, rowptr, cursor, N);
  k_fill<<<nblk_E, 256, 0, stream>>>(edge_src, edge_dst, E, N, cursor, adj, dstc, as1, ad1, ew1);

  // layer 1 aggregate -> g (elu'd)
  k_gat1<<<(N + 3) / 4, 256, 0, stream>>>(h1, ew1, rowptr, adj, b1, g, N);

  // layer 2 linear (h2 overlays h1)
  k_h2<<<(N + 31) / 32, 256, 0, stream>>>(g, W2, att_src2, att_dst2, h2, as2, ad2, N);

  // layer 2 edge weights (ew2 overlays ew1: ew1 dead after k_gat1)
  k_ew2<<<nblk_E, 256, 0, stream>>>(adj, dstc, as2, ad2, ew2, Etot);

  // layer 2 aggregate -> g2 (overlays g)
  k_gat2<<<(N + 3) / 4, 256, 0, stream>>>(h2, ew2, rowptr, adj, b2, g2, N);

  // gather features -> bf16 K-blocked
  k_xmat<<<512, 256, 0, stream>>>(user_idx, context_idx, user_emb, g2, xb);

  // final FC (MFMA)
  k_fc<<<(NSRV + 31) / 32, 256, 0, stream>>>(xb, fc_w, fc_b, out, NSRV, 256 / 32);
}

// Round 3
// 870.807 us; speedup vs baseline: 1.6016x; 1.2725x over previous
//
#include <hip/hip_runtime.h>
#include <hip/hip_bf16.h>
#include <math.h>

#define NEG_SLOPE 0.2f

typedef __attribute__((ext_vector_type(8))) short short8;
typedef __attribute__((ext_vector_type(4))) float f32x4;

__device__ __forceinline__ float leaky(float x) { return x > 0.f ? x : NEG_SLOPE * x; }

__device__ __forceinline__ unsigned short f2bf(float f) {
  unsigned u = __float_as_uint(f);
  unsigned r = (u + 0x7FFFu + ((u >> 16) & 1u)) >> 16;  // RNE
  return (unsigned short)r;
}
__device__ __forceinline__ float bf2f(unsigned short b) {
  return __uint_as_float(((unsigned)b) << 16);
}

// ---------------- GAT layer 1 linear: h1[N,128] = x[N,64] @ W1[64,128] (bf16 out)
__global__ void k_h1(const float* __restrict__ x, const float* __restrict__ W1,
                     const float* __restrict__ att_src, const float* __restrict__ att_dst,
                     unsigned short* __restrict__ h1, float* __restrict__ a_s,
                     float* __restrict__ a_d, int N) {
  __shared__ __align__(16) float W1s[64 * 128];
  __shared__ __align__(16) float xs[2][64];
  for (int i = threadIdx.x; i < 64 * 128; i += 256) W1s[i] = W1[i];
  const int ln  = threadIdx.x >> 7;   // node slot 0/1
  const int col = threadIdx.x & 127;  // output channel
  const int head = col >> 6;
  const int c = col & 63;
  const float as_w = att_src[head * 64 + c];
  const float ad_w = att_dst[head * 64 + c];
  __syncthreads();
  float wreg[64];
#pragma unroll
  for (int cc = 0; cc < 64; ++cc) wreg[cc] = W1s[cc * 128 + col];

  const int node0 = blockIdx.x * 32;
  for (int it = 0; it < 16; ++it) {
    const int nbase = node0 + it * 2;
    __syncthreads();
    if (threadIdx.x < 128) {
      const int nn = nbase + (threadIdx.x >> 6);
      if (nn < N) xs[threadIdx.x >> 6][threadIdx.x & 63] = x[(size_t)nn * 64 + (threadIdx.x & 63)];
    }
    __syncthreads();
    const int n = nbase + ln;
    if (n >= N) continue;
    float acc = 0.f;
#pragma unroll
    for (int q = 0; q < 16; ++q) {
      const float4 xv = *(const float4*)&xs[ln][q * 4];
      acc = fmaf(xv.x, wreg[q * 4 + 0], acc);
      acc = fmaf(xv.y, wreg[q * 4 + 1], acc);
      acc = fmaf(xv.z, wreg[q * 4 + 2], acc);
      acc = fmaf(xv.w, wreg[q * 4 + 3], acc);
    }
    h1[(size_t)n * 128 + col] = f2bf(acc);
    float vs = acc * as_w;
    float vd = acc * ad_w;
#pragma unroll
    for (int off = 32; off > 0; off >>= 1) {
      vs += __shfl_down(vs, off, 64);
      vd += __shfl_down(vd, off, 64);
    }
    if (c == 0) { a_s[n * 2 + head] = vs; a_d[n * 2 + head] = vd; }
  }
}

// ---------------- CSR build ----------------
__global__ void k_zero_int(int* __restrict__ p, int n) {
  int i = blockIdx.x * 256 + threadIdx.x;
  if (i < n) p[i] = 0;
}

__global__ void k_deg(const int* __restrict__ dst, int E, int N, int* __restrict__ deg) {
  int e = blockIdx.x * 256 + threadIdx.x;
  if (e < E + N) {
    int d = (e < E) ? dst[e] : (e - E);
    atomicAdd(&deg[d], 1);
  }
}

// hierarchical scan, pass 1: per-1024-tile exclusive scan + tile totals
__global__ void k_scan1(const int* __restrict__ deg, int* __restrict__ tilescan,
                        int* __restrict__ blocksum, int N) {
  __shared__ int s[1024];
  const int tid = threadIdx.x;
  const int gid = blockIdx.x * 1024 + tid;
  const int v = (gid < N) ? deg[gid] : 0;
  s[tid] = v;
  __syncthreads();
  for (int off = 1; off < 1024; off <<= 1) {
    const int t = (tid >= off) ? s[tid - off] : 0;
    __syncthreads();
    s[tid] += t;
    __syncthreads();
  }
  if (gid < N) tilescan[gid] = s[tid] - v;  // exclusive within tile
  if (tid == 1023) blocksum[blockIdx.x] = s[1023];
}

// pass 2: single block exclusive scan of tile totals (nb <= 1024)
__global__ void k_scan2(int* __restrict__ blocksum, int nb) {
  __shared__ int s[1024];
  const int tid = threadIdx.x;
  const int v = (tid < nb) ? blocksum[tid] : 0;
  s[tid] = v;
  __syncthreads();
  for (int off = 1; off < 1024; off <<= 1) {
    const int t = (tid >= off) ? s[tid - off] : 0;
    __syncthreads();
    s[tid] += t;
    __syncthreads();
  }
  if (tid < nb) blocksum[tid] = s[tid] - v;
}

// pass 3: add tile offsets -> rowptr, cursor; rowptr[N] = Etot
__global__ void k_scan3(int* __restrict__ rowptr, const int* __restrict__ blocksum,
                        int* __restrict__ cursor, int N, int Etot) {
  const int gid = blockIdx.x * 256 + threadIdx.x;
  if (gid < N) {
    const int r = rowptr[gid] + blocksum[gid >> 10];
    rowptr[gid] = r;
    cursor[gid] = r;
  }
  if (gid == 0) rowptr[N] = Etot;
}

__global__ void k_fill(const int* __restrict__ src, const int* __restrict__ dst, int E, int N,
                       int* __restrict__ cursor, int* __restrict__ adj) {
  int e = blockIdx.x * 256 + threadIdx.x;
  if (e < E + N) {
    int s, d;
    if (e < E) { s = src[e]; d = dst[e]; } else { s = d = e - E; }
    int pos = atomicAdd(&cursor[d], 1);
    adj[pos] = s;
  }
}

// ---------------- GAT layer 1 aggregate (bf16 gather, on-the-fly weights) ----------------
__global__ void k_gat1(const unsigned short* __restrict__ h1, const float* __restrict__ as1,
                       const float* __restrict__ ad1, const int* __restrict__ rowptr,
                       const int* __restrict__ adj, const float* __restrict__ b1,
                       float* __restrict__ g, int N) {
  const int w = threadIdx.x >> 6;
  const int l = threadIdx.x & 63;
  const int n = blockIdx.x * 4 + w;
  if (n >= N) return;
  const int head = l >> 5;
  const float adh = ad1[n * 2 + head];
  float accx = 0.f, accy = 0.f;
  float dsum = 0.f;
  const int kb = rowptr[n], ke = rowptr[n + 1];
  for (int k = kb; k < ke; ++k) {
    const int s = adj[k];
    const float wgt = __expf(leaky(as1[s * 2 + head] + adh));
    dsum += wgt;
    const unsigned v = *(const unsigned*)(h1 + (size_t)s * 128 + 2 * l);
    accx = fmaf(wgt, __uint_as_float(v << 16), accx);
    accy = fmaf(wgt, __uint_as_float(v & 0xFFFF0000u), accy);
  }
  const float inv = 1.f / (dsum + 1e-16f);
  const float2 bv = ((const float2*)b1)[l];
  float gx = accx * inv + bv.x;
  float gy = accy * inv + bv.y;
  gx = gx > 0.f ? gx : expm1f(gx);
  gy = gy > 0.f ? gy : expm1f(gy);
  ((float2*)g)[(size_t)n * 64 + l] = make_float2(gx, gy);
}

// ---------------- GAT layer 2 linear: h2[N,64] = g[N,128] @ W2[128,64] (bf16 out)
__global__ void k_h2(const float* __restrict__ g, const float* __restrict__ W2,
                     const float* __restrict__ att_s, const float* __restrict__ att_d,
                     unsigned short* __restrict__ h2, float* __restrict__ a_s,
                     float* __restrict__ a_d, int N) {
  __shared__ __align__(16) float W2s[128 * 64];
  __shared__ __align__(16) float gs[2][128];
  __shared__ float part[2][64];
  for (int i = threadIdx.x; i < 128 * 64; i += 256) W2s[i] = W2[i];
  const int col = threadIdx.x & 63;
  const int kh  = (threadIdx.x >> 6) & 1;
  const int ln  = threadIdx.x >> 7;
  const float as_w = att_s[col], ad_w = att_d[col];
  __syncthreads();
  float wreg[64];
#pragma unroll
  for (int cc = 0; cc < 64; ++cc) wreg[cc] = W2s[(kh * 64 + cc) * 64 + col];

  const int node0 = blockIdx.x * 32;
  for (int it = 0; it < 16; ++it) {
    const int nbase = node0 + it * 2;
    __syncthreads();
    {
      const int nn = nbase + (threadIdx.x >> 7);
      if (nn < N) gs[threadIdx.x >> 7][threadIdx.x & 127] = g[(size_t)nn * 128 + (threadIdx.x & 127)];
    }
    __syncthreads();
    const int n = nbase + ln;
    float acc = 0.f;
    if (n < N) {
#pragma unroll
      for (int q = 0; q < 16; ++q) {
        const float4 gv = *(const float4*)&gs[ln][kh * 64 + q * 4];
        acc = fmaf(gv.x, wreg[q * 4 + 0], acc);
        acc = fmaf(gv.y, wreg[q * 4 + 1], acc);
        acc = fmaf(gv.z, wreg[q * 4 + 2], acc);
        acc = fmaf(gv.w, wreg[q * 4 + 3], acc);
      }
    }
    if (kh == 1) part[ln][col] = acc;
    __syncthreads();
    if (kh == 0 && n < N) {
      acc += part[ln][col];
      h2[(size_t)n * 64 + col] = f2bf(acc);
      float vs = acc * as_w, vd = acc * ad_w;
#pragma unroll
      for (int off = 32; off > 0; off >>= 1) {
        vs += __shfl_down(vs, off, 64);
        vd += __shfl_down(vd, off, 64);
      }
      if (col == 0) { a_s[n] = vs; a_d[n] = vd; }
    }
  }
}

// ---------------- GAT layer 2 aggregate (bf16 gather, on-the-fly weights) ----------------
__global__ void k_gat2(const unsigned short* __restrict__ h2, const float* __restrict__ as2,
                       const float* __restrict__ ad2, const int* __restrict__ rowptr,
                       const int* __restrict__ adj, const float* __restrict__ b2,
                       float* __restrict__ g2, int N) {
  const int w = threadIdx.x >> 6;
  const int l = threadIdx.x & 63;
  const int n = blockIdx.x * 4 + w;
  if (n >= N) return;
  const float adh = ad2[n];
  float acc = 0.f, dsum = 0.f;
  const int kb = rowptr[n], ke = rowptr[n + 1];
  for (int k = kb; k < ke; ++k) {
    const int s = adj[k];
    const float wgt = __expf(leaky(as2[s] + adh));
    dsum += wgt;
    acc = fmaf(wgt, bf2f(h2[(size_t)s * 64 + l]), acc);
  }
  g2[(size_t)n * 64 + l] = acc / (dsum + 1e-16f) + b2[l];
}

// ---------------- build x matrix, bf16, K-blocked: xb[k/32][512][32] ----------------
__global__ void k_xmat(const int* __restrict__ user_idx, const int* __restrict__ ctx_idx,
                       const float* __restrict__ user_emb, const float* __restrict__ g2,
                       unsigned short* __restrict__ xb) {
  const int b = blockIdx.x;
  const int k = threadIdx.x;  // 0..255
  float v;
  if (k < 64) {
    v = user_emb[(size_t)user_idx[b] * 64 + k];
  } else {
    const int c = (k - 64) >> 6;
    v = g2[(size_t)ctx_idx[b * 3 + c] * 64 + (k & 63)];
  }
  xb[(size_t)(k >> 5) * (512 * 32) + b * 32 + (k & 31)] = f2bf(v);
}

// ---------------- final FC via MFMA: out[512, NSRV] = x[512,256] @ fc_w[256,NSRV] + fc_b
__global__ __launch_bounds__(256) void k_fc(const unsigned short* __restrict__ xb,
                                            const float* __restrict__ fc_w,
                                            const float* __restrict__ fc_b,
                                            float* __restrict__ out, int NSRV, int nk) {
  __shared__ __align__(16) unsigned char smem[512 * 80 + 32 * 80];
  char* As = (char*)smem;            // [512 rows][80 B]
  char* Bs = (char*)smem + 512 * 80; // [32 cols][80 B]

  const int tid = threadIdx.x;
  const int lane = tid & 63;
  const int wv = tid >> 6;
  const int nf = wv & 1;
  const int mh = wv >> 1;
  const int j0 = blockIdx.x * 32;
  if (j0 >= NSRV) return;
  const bool full = (j0 + 32 <= NSRV);

  f32x4 acc[16];
#pragma unroll
  for (int i = 0; i < 16; ++i) acc[i] = (f32x4){0.f, 0.f, 0.f, 0.f};

  const int l15 = lane & 15;
  const int kg = lane >> 4;

  for (int ks = 0; ks < nk; ++ks) {
    __syncthreads();
    {
      const uint4* srcA = (const uint4*)(xb + (size_t)ks * 16384);
#pragma unroll
      for (int i = 0; i < 8; ++i) {
        const int idx = tid + i * 256;
        const uint4 v = srcA[idx];
        *(uint4*)(As + (idx >> 2) * 80 + (idx & 3) * 16) = v;
      }
    }
    {
      const int kk = tid >> 3;
      const int c4 = (tid & 7) * 4;
      const float* wp = fc_w + (size_t)(ks * 32 + kk) * NSRV + j0 + c4;
      float4 wvv;
      if (full) {
        wvv = *(const float4*)wp;
      } else {
        wvv.x = (j0 + c4 + 0 < NSRV) ? wp[0] : 0.f;
        wvv.y = (j0 + c4 + 1 < NSRV) ? wp[1] : 0.f;
        wvv.z = (j0 + c4 + 2 < NSRV) ? wp[2] : 0.f;
        wvv.w = (j0 + c4 + 3 < NSRV) ? wp[3] : 0.f;
      }
      *(unsigned short*)(Bs + (c4 + 0) * 80 + kk * 2) = f2bf(wvv.x);
      *(unsigned short*)(Bs + (c4 + 1) * 80 + kk * 2) = f2bf(wvv.y);
      *(unsigned short*)(Bs + (c4 + 2) * 80 + kk * 2) = f2bf(wvv.z);
      *(unsigned short*)(Bs + (c4 + 3) * 80 + kk * 2) = f2bf(wvv.w);
    }
    __syncthreads();
    const short8 bfr = *(const short8*)(Bs + (nf * 16 + l15) * 80 + kg * 16);
    const char* abase = As + (mh * 256 + l15) * 80 + kg * 16;
#pragma unroll
    for (int mf = 0; mf < 16; ++mf) {
      const short8 afr = *(const short8*)(abase + mf * (16 * 80));
      acc[mf] = __builtin_amdgcn_mfma_f32_16x16x32_bf16(afr, bfr, acc[mf], 0, 0, 0);
    }
  }

  const int n = j0 + nf * 16 + l15;
  if (n < NSRV) {
    const float bias = fc_b[n];
    const int rbase = mh * 256 + kg * 4;
#pragma unroll
    for (int mf = 0; mf < 16; ++mf) {
#pragma unroll
      for (int r = 0; r < 4; ++r) {
        out[(size_t)(rbase + mf * 16 + r) * NSRV + n] = acc[mf][r] + bias;
      }
    }
  }
}

// =====================================================================
extern "C" void kernel_launch(void* const* d_in, const int* in_sizes, int n_in,
                              void* d_out, int out_size, void* d_ws, size_t ws_size,
                              hipStream_t stream) {
  const int* user_idx    = (const int*)d_in[0];
  const int* context_idx = (const int*)d_in[1];
  const int* edge_index  = (const int*)d_in[2];
  const float* user_emb  = (const float*)d_in[3];
  const float* service_emb = (const float*)d_in[4];
  const float* W1        = (const float*)d_in[5];
  const float* att_src1  = (const float*)d_in[6];
  const float* att_dst1  = (const float*)d_in[7];
  const float* b1        = (const float*)d_in[8];
  const float* W2        = (const float*)d_in[9];
  const float* att_src2  = (const float*)d_in[10];
  const float* att_dst2  = (const float*)d_in[11];
  const float* b2        = (const float*)d_in[12];
  const float* fc_w      = (const float*)d_in[13];
  const float* fc_b      = (const float*)d_in[14];
  float* out = (float*)d_out;

  const int B    = in_sizes[0];
  const int E    = in_sizes[2] / 2;
  const int N    = in_sizes[4] / 64;
  const int NSRV = in_sizes[14];
  const int Etot = E + N;
  (void)B;

  const int* edge_src = edge_index;
  const int* edge_dst = edge_index + E;

  // ---- workspace layout ----
  char* ws = (char*)d_ws;
  size_t off = 0;
  auto alloc = [&](size_t bytes) {
    void* p = ws + off;
    off = (off + bytes + 255) & ~(size_t)255;
    return p;
  };
  unsigned short* h1 = (unsigned short*)alloc((size_t)N * 128 * 2);  // reused as h2
  float* g      = (float*)alloc((size_t)N * 128 * 4);                // reused as g2
  float* as1    = (float*)alloc((size_t)N * 2 * 4);
  float* ad1    = (float*)alloc((size_t)N * 2 * 4);
  float* as2    = (float*)alloc((size_t)N * 4);
  float* ad2    = (float*)alloc((size_t)N * 4);
  int*   deg    = (int*)alloc((size_t)N * 4);
  int*   rowptr = (int*)alloc((size_t)(N + 1) * 4);
  int*   cursor = (int*)alloc((size_t)N * 4);
  int*   adj    = (int*)alloc((size_t)Etot * 4);
  int*   blocksum = (int*)alloc(1024 * 4);
  unsigned short* xb = (unsigned short*)alloc((size_t)512 * 256 * 2);
  unsigned short* h2 = h1;
  float* g2 = g;
  (void)ws_size;

  const int nblk_N = (N + 255) / 256;
  const int nblk_E = (Etot + 255) / 256;
  const int ntile  = (N + 1023) / 1024;

  // GAT layer 1 linear
  k_h1<<<(N + 31) / 32, 256, 0, stream>>>(service_emb, W1, att_src1, att_dst1, h1, as1, ad1, N);

  // CSR build
  k_zero_int<<<nblk_N, 256, 0, stream>>>(deg, N);
  k_deg<<<nblk_E, 256, 0, stream>>>(edge_dst, E, N, deg);
  k_scan1<<<ntile, 1024, 0, stream>>>(deg, rowptr, blocksum, N);
  k_scan2<<<1, 1024, 0, stream>>>(blocksum, ntile);
  k_scan3<<<nblk_N, 256, 0, stream>>>(rowptr, blocksum, cursor, N, Etot);
  k_fill<<<nblk_E, 256, 0, stream>>>(edge_src, edge_dst, E, N, cursor, adj);

  // layer 1 aggregate -> g (elu'd)
  k_gat1<<<(N + 3) / 4, 256, 0, stream>>>(h1, as1, ad1, rowptr, adj, b1, g, N);

  // layer 2 linear (h2 overlays h1)
  k_h2<<<(N + 31) / 32, 256, 0, stream>>>(g, W2, att_src2, att_dst2, h2, as2, ad2, N);

  // layer 2 aggregate -> g2 (overlays g)
  k_gat2<<<(N + 3) / 4, 256, 0, stream>>>(h2, as2, ad2, rowptr, adj, b2, g2, N);

  // gather features -> bf16 K-blocked
  k_xmat<<<512, 256, 0, stream>>>(user_idx, context_idx, user_emb, g2, xb);

  // final FC (MFMA)
  k_fc<<<(NSRV + 31) / 32, 256, 0, stream>>>(xb, fc_w, fc_b, out, NSRV, 256 / 32);
}

// Round 4
// 677.229 us; speedup vs baseline: 2.0594x; 1.2858x over previous
//
#include <hip/hip_runtime.h>
#include <hip/hip_bf16.h>
#include <math.h>

#define NEG_SLOPE 0.2f

typedef __attribute__((ext_vector_type(8))) short short8;
typedef __attribute__((ext_vector_type(4))) float f32x4;

__device__ __forceinline__ float leaky(float x) { return x > 0.f ? x : NEG_SLOPE * x; }

__device__ __forceinline__ unsigned short f2bf(float f) {
  unsigned u = __float_as_uint(f);
  unsigned r = (u + 0x7FFFu + ((u >> 16) & 1u)) >> 16;  // RNE
  return (unsigned short)r;
}
__device__ __forceinline__ float bf2f(unsigned short b) {
  return __uint_as_float(((unsigned)b) << 16);
}

// ---------------- GAT layer 1 linear: h1[N,128] = x[N,64] @ W1[64,128] (bf16 out)
__global__ void k_h1(const float* __restrict__ x, const float* __restrict__ W1,
                     const float* __restrict__ att_src, const float* __restrict__ att_dst,
                     unsigned short* __restrict__ h1, float* __restrict__ a_s,
                     float* __restrict__ a_d, int N) {
  __shared__ __align__(16) float W1s[64 * 128];
  __shared__ __align__(16) float xs[2][64];
  for (int i = threadIdx.x; i < 64 * 128; i += 256) W1s[i] = W1[i];
  const int ln  = threadIdx.x >> 7;   // node slot 0/1
  const int col = threadIdx.x & 127;  // output channel
  const int head = col >> 6;
  const int c = col & 63;
  const float as_w = att_src[head * 64 + c];
  const float ad_w = att_dst[head * 64 + c];
  __syncthreads();
  float wreg[64];
#pragma unroll
  for (int cc = 0; cc < 64; ++cc) wreg[cc] = W1s[cc * 128 + col];

  const int node0 = blockIdx.x * 32;
  for (int it = 0; it < 16; ++it) {
    const int nbase = node0 + it * 2;
    __syncthreads();
    if (threadIdx.x < 128) {
      const int nn = nbase + (threadIdx.x >> 6);
      if (nn < N) xs[threadIdx.x >> 6][threadIdx.x & 63] = x[(size_t)nn * 64 + (threadIdx.x & 63)];
    }
    __syncthreads();
    const int n = nbase + ln;
    if (n >= N) continue;
    float acc = 0.f;
#pragma unroll
    for (int q = 0; q < 16; ++q) {
      const float4 xv = *(const float4*)&xs[ln][q * 4];
      acc = fmaf(xv.x, wreg[q * 4 + 0], acc);
      acc = fmaf(xv.y, wreg[q * 4 + 1], acc);
      acc = fmaf(xv.z, wreg[q * 4 + 2], acc);
      acc = fmaf(xv.w, wreg[q * 4 + 3], acc);
    }
    h1[(size_t)n * 128 + col] = f2bf(acc);
    float vs = acc * as_w;
    float vd = acc * ad_w;
#pragma unroll
    for (int off = 32; off > 0; off >>= 1) {
      vs += __shfl_down(vs, off, 64);
      vd += __shfl_down(vd, off, 64);
    }
    if (c == 0) { a_s[n * 2 + head] = vs; a_d[n * 2 + head] = vd; }
  }
}

// ---------------- CSR build ----------------
__global__ void k_zero_int(int* __restrict__ p, int n) {
  int i = blockIdx.x * 256 + threadIdx.x;
  if (i < n) p[i] = 0;
}

__global__ void k_deg(const int* __restrict__ dst, int E, int N, int* __restrict__ deg) {
  int e = blockIdx.x * 256 + threadIdx.x;
  if (e < E + N) {
    int d = (e < E) ? dst[e] : (e - E);
    atomicAdd(&deg[d], 1);
  }
}

// hierarchical scan, pass 1
__global__ void k_scan1(const int* __restrict__ deg, int* __restrict__ tilescan,
                        int* __restrict__ blocksum, int N) {
  __shared__ int s[1024];
  const int tid = threadIdx.x;
  const int gid = blockIdx.x * 1024 + tid;
  const int v = (gid < N) ? deg[gid] : 0;
  s[tid] = v;
  __syncthreads();
  for (int off = 1; off < 1024; off <<= 1) {
    const int t = (tid >= off) ? s[tid - off] : 0;
    __syncthreads();
    s[tid] += t;
    __syncthreads();
  }
  if (gid < N) tilescan[gid] = s[tid] - v;
  if (tid == 1023) blocksum[blockIdx.x] = s[1023];
}

// pass 2
__global__ void k_scan2(int* __restrict__ blocksum, int nb) {
  __shared__ int s[1024];
  const int tid = threadIdx.x;
  const int v = (tid < nb) ? blocksum[tid] : 0;
  s[tid] = v;
  __syncthreads();
  for (int off = 1; off < 1024; off <<= 1) {
    const int t = (tid >= off) ? s[tid - off] : 0;
    __syncthreads();
    s[tid] += t;
    __syncthreads();
  }
  if (tid < nb) blocksum[tid] = s[tid] - v;
}

// pass 3
__global__ void k_scan3(int* __restrict__ rowptr, const int* __restrict__ blocksum,
                        int* __restrict__ cursor, int N, int Etot) {
  const int gid = blockIdx.x * 256 + threadIdx.x;
  if (gid < N) {
    const int r = rowptr[gid] + blocksum[gid >> 10];
    rowptr[gid] = r;
    cursor[gid] = r;
  }
  if (gid == 0) rowptr[N] = Etot;
}

__global__ void k_fill(const int* __restrict__ src, const int* __restrict__ dst, int E, int N,
                       int* __restrict__ cursor, int* __restrict__ adj) {
  int e = blockIdx.x * 256 + threadIdx.x;
  if (e < E + N) {
    int s, d;
    if (e < E) { s = src[e]; d = dst[e]; } else { s = d = e - E; }
    int pos = atomicAdd(&cursor[d], 1);
    adj[pos] = s;
  }
}

// ---------------- GAT layer 1 aggregate ----------------
// wave per node; lane = (half, q): half-wave covers the 128-ch row (8 B/lane),
// halves take alternating edges; x2 manual unroll -> 4 gathers in flight.
__global__ void k_gat1(const unsigned short* __restrict__ h1, const float* __restrict__ as1,
                       const float* __restrict__ ad1, const int* __restrict__ rowptr,
                       const int* __restrict__ adj, const float* __restrict__ b1,
                       float* __restrict__ g, int N) {
  const int w = threadIdx.x >> 6;
  const int l = threadIdx.x & 63;
  const int n = blockIdx.x * 4 + w;
  if (n >= N) return;
  const int half = l >> 5;
  const int q = l & 31;       // channels 4q..4q+3
  const int head = q >> 4;    // 0 for ch<64, 1 for ch>=64
  const float adh = ad1[n * 2 + head];
  float a0 = 0.f, a1 = 0.f, a2 = 0.f, a3 = 0.f, dsum = 0.f;
  const int kb = rowptr[n], ke = rowptr[n + 1];
  const int kend = ke - 1;
  for (int k = kb + half; k < ke; k += 4) {
    const int eB = k + 2;
    const bool vB = eB < ke;
    const int sA = adj[k];
    const int sB = adj[min(eB, kend)];
    const float xA = as1[sA * 2 + head] + adh;
    const float xB = as1[sB * 2 + head] + adh;
    const uint2 hA = *(const uint2*)(h1 + (size_t)sA * 128 + 4 * q);
    const uint2 hB = *(const uint2*)(h1 + (size_t)sB * 128 + 4 * q);
    const float wA = __expf(leaky(xA));
    const float wB = vB ? __expf(leaky(xB)) : 0.f;
    dsum += wA + wB;
    a0 = fmaf(wA, __uint_as_float(hA.x << 16), a0);
    a1 = fmaf(wA, __uint_as_float(hA.x & 0xFFFF0000u), a1);
    a2 = fmaf(wA, __uint_as_float(hA.y << 16), a2);
    a3 = fmaf(wA, __uint_as_float(hA.y & 0xFFFF0000u), a3);
    a0 = fmaf(wB, __uint_as_float(hB.x << 16), a0);
    a1 = fmaf(wB, __uint_as_float(hB.x & 0xFFFF0000u), a1);
    a2 = fmaf(wB, __uint_as_float(hB.y << 16), a2);
    a3 = fmaf(wB, __uint_as_float(hB.y & 0xFFFF0000u), a3);
  }
  a0 += __shfl_xor(a0, 32, 64);
  a1 += __shfl_xor(a1, 32, 64);
  a2 += __shfl_xor(a2, 32, 64);
  a3 += __shfl_xor(a3, 32, 64);
  dsum += __shfl_xor(dsum, 32, 64);
  if (half == 0) {
    const float inv = 1.f / (dsum + 1e-16f);
    const float4 bv = *(const float4*)(b1 + 4 * q);
    float g0 = fmaf(a0, inv, bv.x);
    float g1 = fmaf(a1, inv, bv.y);
    float g2v = fmaf(a2, inv, bv.z);
    float g3 = fmaf(a3, inv, bv.w);
    g0 = g0 > 0.f ? g0 : expm1f(g0);
    g1 = g1 > 0.f ? g1 : expm1f(g1);
    g2v = g2v > 0.f ? g2v : expm1f(g2v);
    g3 = g3 > 0.f ? g3 : expm1f(g3);
    *(float4*)(g + (size_t)n * 128 + 4 * q) = make_float4(g0, g1, g2v, g3);
  }
}

// ---------------- GAT layer 2 linear: h2[N,64] = g[N,128] @ W2[128,64] (bf16 out)
__global__ void k_h2(const float* __restrict__ g, const float* __restrict__ W2,
                     const float* __restrict__ att_s, const float* __restrict__ att_d,
                     unsigned short* __restrict__ h2, float* __restrict__ a_s,
                     float* __restrict__ a_d, int N) {
  __shared__ __align__(16) float W2s[128 * 64];
  __shared__ __align__(16) float gs[2][128];
  __shared__ float part[2][64];
  for (int i = threadIdx.x; i < 128 * 64; i += 256) W2s[i] = W2[i];
  const int col = threadIdx.x & 63;
  const int kh  = (threadIdx.x >> 6) & 1;
  const int ln  = threadIdx.x >> 7;
  const float as_w = att_s[col], ad_w = att_d[col];
  __syncthreads();
  float wreg[64];
#pragma unroll
  for (int cc = 0; cc < 64; ++cc) wreg[cc] = W2s[(kh * 64 + cc) * 64 + col];

  const int node0 = blockIdx.x * 32;
  for (int it = 0; it < 16; ++it) {
    const int nbase = node0 + it * 2;
    __syncthreads();
    {
      const int nn = nbase + (threadIdx.x >> 7);
      if (nn < N) gs[threadIdx.x >> 7][threadIdx.x & 127] = g[(size_t)nn * 128 + (threadIdx.x & 127)];
    }
    __syncthreads();
    const int n = nbase + ln;
    float acc = 0.f;
    if (n < N) {
#pragma unroll
      for (int q = 0; q < 16; ++q) {
        const float4 gv = *(const float4*)&gs[ln][kh * 64 + q * 4];
        acc = fmaf(gv.x, wreg[q * 4 + 0], acc);
        acc = fmaf(gv.y, wreg[q * 4 + 1], acc);
        acc = fmaf(gv.z, wreg[q * 4 + 2], acc);
        acc = fmaf(gv.w, wreg[q * 4 + 3], acc);
      }
    }
    if (kh == 1) part[ln][col] = acc;
    __syncthreads();
    if (kh == 0 && n < N) {
      acc += part[ln][col];
      h2[(size_t)n * 64 + col] = f2bf(acc);
      float vs = acc * as_w, vd = acc * ad_w;
#pragma unroll
      for (int off = 32; off > 0; off >>= 1) {
        vs += __shfl_down(vs, off, 64);
        vd += __shfl_down(vd, off, 64);
      }
      if (col == 0) { a_s[n] = vs; a_d[n] = vd; }
    }
  }
}

// ---------------- GAT layer 2 aggregate ----------------
// same 2-edges-per-wave scheme: lane = (half, q), channels 2q,2q+1 (4 B/lane).
__global__ void k_gat2(const unsigned short* __restrict__ h2, const float* __restrict__ as2,
                       const float* __restrict__ ad2, const int* __restrict__ rowptr,
                       const int* __restrict__ adj, const float* __restrict__ b2,
                       float* __restrict__ g2, int N) {
  const int w = threadIdx.x >> 6;
  const int l = threadIdx.x & 63;
  const int n = blockIdx.x * 4 + w;
  if (n >= N) return;
  const int half = l >> 5;
  const int q = l & 31;       // channels 2q, 2q+1
  const float adh = ad2[n];
  float a0 = 0.f, a1 = 0.f, dsum = 0.f;
  const int kb = rowptr[n], ke = rowptr[n + 1];
  const int kend = ke - 1;
  for (int k = kb + half; k < ke; k += 4) {
    const int eB = k + 2;
    const bool vB = eB < ke;
    const int sA = adj[k];
    const int sB = adj[min(eB, kend)];
    const float xA = as2[sA] + adh;
    const float xB = as2[sB] + adh;
    const unsigned hA = *(const unsigned*)(h2 + (size_t)sA * 64 + 2 * q);
    const unsigned hB = *(const unsigned*)(h2 + (size_t)sB * 64 + 2 * q);
    const float wA = __expf(leaky(xA));
    const float wB = vB ? __expf(leaky(xB)) : 0.f;
    dsum += wA + wB;
    a0 = fmaf(wA, __uint_as_float(hA << 16), a0);
    a1 = fmaf(wA, __uint_as_float(hA & 0xFFFF0000u), a1);
    a0 = fmaf(wB, __uint_as_float(hB << 16), a0);
    a1 = fmaf(wB, __uint_as_float(hB & 0xFFFF0000u), a1);
  }
  a0 += __shfl_xor(a0, 32, 64);
  a1 += __shfl_xor(a1, 32, 64);
  dsum += __shfl_xor(dsum, 32, 64);
  if (half == 0) {
    const float inv = 1.f / (dsum + 1e-16f);
    const float2 bv = *(const float2*)(b2 + 2 * q);
    ((float2*)g2)[(size_t)n * 32 + q] =
        make_float2(fmaf(a0, inv, bv.x), fmaf(a1, inv, bv.y));
  }
}

// ---------------- build x matrix, bf16, K-blocked: xb[k/32][512][32] ----------------
__global__ void k_xmat(const int* __restrict__ user_idx, const int* __restrict__ ctx_idx,
                       const float* __restrict__ user_emb, const float* __restrict__ g2,
                       unsigned short* __restrict__ xb) {
  const int b = blockIdx.x;
  const int k = threadIdx.x;  // 0..255
  float v;
  if (k < 64) {
    v = user_emb[(size_t)user_idx[b] * 64 + k];
  } else {
    const int c = (k - 64) >> 6;
    v = g2[(size_t)ctx_idx[b * 3 + c] * 64 + (k & 63)];
  }
  xb[(size_t)(k >> 5) * (512 * 32) + b * 32 + (k & 31)] = f2bf(v);
}

// ---------------- final FC via MFMA ----------------
__global__ __launch_bounds__(256) void k_fc(const unsigned short* __restrict__ xb,
                                            const float* __restrict__ fc_w,
                                            const float* __restrict__ fc_b,
                                            float* __restrict__ out, int NSRV, int nk) {
  __shared__ __align__(16) unsigned char smem[512 * 80 + 32 * 80];
  char* As = (char*)smem;            // [512 rows][80 B]
  char* Bs = (char*)smem + 512 * 80; // [32 cols][80 B]

  const int tid = threadIdx.x;
  const int lane = tid & 63;
  const int wv = tid >> 6;
  const int nf = wv & 1;
  const int mh = wv >> 1;
  const int j0 = blockIdx.x * 32;
  if (j0 >= NSRV) return;
  const bool full = (j0 + 32 <= NSRV);

  f32x4 acc[16];
#pragma unroll
  for (int i = 0; i < 16; ++i) acc[i] = (f32x4){0.f, 0.f, 0.f, 0.f};

  const int l15 = lane & 15;
  const int kg = lane >> 4;

  for (int ks = 0; ks < nk; ++ks) {
    __syncthreads();
    {
      const uint4* srcA = (const uint4*)(xb + (size_t)ks * 16384);
#pragma unroll
      for (int i = 0; i < 8; ++i) {
        const int idx = tid + i * 256;
        const uint4 v = srcA[idx];
        *(uint4*)(As + (idx >> 2) * 80 + (idx & 3) * 16) = v;
      }
    }
    {
      const int kk = tid >> 3;
      const int c4 = (tid & 7) * 4;
      const float* wp = fc_w + (size_t)(ks * 32 + kk) * NSRV + j0 + c4;
      float4 wvv;
      if (full) {
        wvv = *(const float4*)wp;
      } else {
        wvv.x = (j0 + c4 + 0 < NSRV) ? wp[0] : 0.f;
        wvv.y = (j0 + c4 + 1 < NSRV) ? wp[1] : 0.f;
        wvv.z = (j0 + c4 + 2 < NSRV) ? wp[2] : 0.f;
        wvv.w = (j0 + c4 + 3 < NSRV) ? wp[3] : 0.f;
      }
      *(unsigned short*)(Bs + (c4 + 0) * 80 + kk * 2) = f2bf(wvv.x);
      *(unsigned short*)(Bs + (c4 + 1) * 80 + kk * 2) = f2bf(wvv.y);
      *(unsigned short*)(Bs + (c4 + 2) * 80 + kk * 2) = f2bf(wvv.z);
      *(unsigned short*)(Bs + (c4 + 3) * 80 + kk * 2) = f2bf(wvv.w);
    }
    __syncthreads();
    const short8 bfr = *(const short8*)(Bs + (nf * 16 + l15) * 80 + kg * 16);
    const char* abase = As + (mh * 256 + l15) * 80 + kg * 16;
#pragma unroll
    for (int mf = 0; mf < 16; ++mf) {
      const short8 afr = *(const short8*)(abase + mf * (16 * 80));
      acc[mf] = __builtin_amdgcn_mfma_f32_16x16x32_bf16(afr, bfr, acc[mf], 0, 0, 0);
    }
  }

  const int n = j0 + nf * 16 + l15;
  if (n < NSRV) {
    const float bias = fc_b[n];
    const int rbase = mh * 256 + kg * 4;
#pragma unroll
    for (int mf = 0; mf < 16; ++mf) {
#pragma unroll
      for (int r = 0; r < 4; ++r) {
        out[(size_t)(rbase + mf * 16 + r) * NSRV + n] = acc[mf][r] + bias;
      }
    }
  }
}

// =====================================================================
extern "C" void kernel_launch(void* const* d_in, const int* in_sizes, int n_in,
                              void* d_out, int out_size, void* d_ws, size_t ws_size,
                              hipStream_t stream) {
  const int* user_idx    = (const int*)d_in[0];
  const int* context_idx = (const int*)d_in[1];
  const int* edge_index  = (const int*)d_in[2];
  const float* user_emb  = (const float*)d_in[3];
  const float* service_emb = (const float*)d_in[4];
  const float* W1        = (const float*)d_in[5];
  const float* att_src1  = (const float*)d_in[6];
  const float* att_dst1  = (const float*)d_in[7];
  const float* b1        = (const float*)d_in[8];
  const float* W2        = (const float*)d_in[9];
  const float* att_src2  = (const float*)d_in[10];
  const float* att_dst2  = (const float*)d_in[11];
  const float* b2        = (const float*)d_in[12];
  const float* fc_w      = (const float*)d_in[13];
  const float* fc_b      = (const float*)d_in[14];
  float* out = (float*)d_out;

  const int B    = in_sizes[0];
  const int E    = in_sizes[2] / 2;
  const int N    = in_sizes[4] / 64;
  const int NSRV = in_sizes[14];
  const int Etot = E + N;
  (void)B;

  const int* edge_src = edge_index;
  const int* edge_dst = edge_index + E;

  // ---- workspace layout ----
  char* ws = (char*)d_ws;
  size_t off = 0;
  auto alloc = [&](size_t bytes) {
    void* p = ws + off;
    off = (off + bytes + 255) & ~(size_t)255;
    return p;
  };
  unsigned short* h1 = (unsigned short*)alloc((size_t)N * 128 * 2);  // reused as h2
  float* g      = (float*)alloc((size_t)N * 128 * 4);                // reused as g2
  float* as1    = (float*)alloc((size_t)N * 2 * 4);
  float* ad1    = (float*)alloc((size_t)N * 2 * 4);
  float* as2    = (float*)alloc((size_t)N * 4);
  float* ad2    = (float*)alloc((size_t)N * 4);
  int*   deg    = (int*)alloc((size_t)N * 4);
  int*   rowptr = (int*)alloc((size_t)(N + 1) * 4);
  int*   cursor = (int*)alloc((size_t)N * 4);
  int*   adj    = (int*)alloc((size_t)Etot * 4);
  int*   blocksum = (int*)alloc(1024 * 4);
  unsigned short* xb = (unsigned short*)alloc((size_t)512 * 256 * 2);
  unsigned short* h2 = h1;
  float* g2 = g;
  (void)ws_size;

  const int nblk_N = (N + 255) / 256;
  const int nblk_E = (Etot + 255) / 256;
  const int ntile  = (N + 1023) / 1024;

  // GAT layer 1 linear
  k_h1<<<(N + 31) / 32, 256, 0, stream>>>(service_emb, W1, att_src1, att_dst1, h1, as1, ad1, N);

  // CSR build
  k_zero_int<<<nblk_N, 256, 0, stream>>>(deg, N);
  k_deg<<<nblk_E, 256, 0, stream>>>(edge_dst, E, N, deg);
  k_scan1<<<ntile, 1024, 0, stream>>>(deg, rowptr, blocksum, N);
  k_scan2<<<1, 1024, 0, stream>>>(blocksum, ntile);
  k_scan3<<<nblk_N, 256, 0, stream>>>(rowptr, blocksum, cursor, N, Etot);
  k_fill<<<nblk_E, 256, 0, stream>>>(edge_src, edge_dst, E, N, cursor, adj);

  // layer 1 aggregate -> g (elu'd)
  k_gat1<<<(N + 3) / 4, 256, 0, stream>>>(h1, as1, ad1, rowptr, adj, b1, g, N);

  // layer 2 linear (h2 overlays h1)
  k_h2<<<(N + 31) / 32, 256, 0, stream>>>(g, W2, att_src2, att_dst2, h2, as2, ad2, N);

  // layer 2 aggregate -> g2 (overlays g)
  k_gat2<<<(N + 3) / 4, 256, 0, stream>>>(h2, as2, ad2, rowptr, adj, b2, g2, N);

  // gather features -> bf16 K-blocked
  k_xmat<<<512, 256, 0, stream>>>(user_idx, context_idx, user_emb, g2, xb);

  // final FC (MFMA)
  k_fc<<<(NSRV + 31) / 32, 256, 0, stream>>>(xb, fc_w, fc_b, out, NSRV, 256 / 32);
}

// Round 5
// 637.934 us; speedup vs baseline: 2.1862x; 1.0616x over previous
//
#include <hip/hip_runtime.h>
#include <hip/hip_bf16.h>
#include <math.h>

#define NEG_SLOPE 0.2f

typedef __attribute__((ext_vector_type(8))) short short8;
typedef __attribute__((ext_vector_type(4))) float f32x4;

__device__ __forceinline__ float leaky(float x) { return x > 0.f ? x : NEG_SLOPE * x; }

__device__ __forceinline__ unsigned short f2bf(float f) {
  unsigned u = __float_as_uint(f);
  unsigned r = (u + 0x7FFFu + ((u >> 16) & 1u)) >> 16;  // RNE
  return (unsigned short)r;
}
__device__ __forceinline__ float bf2f(unsigned short b) {
  return __uint_as_float(((unsigned)b) << 16);
}

// ---------------- GAT layer 1 linear: h1[N,128] = x[N,64] @ W1[64,128] (bf16 out)
__global__ void k_h1(const float* __restrict__ x, const float* __restrict__ W1,
                     const float* __restrict__ att_src, const float* __restrict__ att_dst,
                     unsigned short* __restrict__ h1, float* __restrict__ a_s,
                     float* __restrict__ a_d, int N) {
  __shared__ __align__(16) float W1s[64 * 128];
  __shared__ __align__(16) float xs[2][64];
  for (int i = threadIdx.x; i < 64 * 128; i += 256) W1s[i] = W1[i];
  const int ln  = threadIdx.x >> 7;   // node slot 0/1
  const int col = threadIdx.x & 127;  // output channel
  const int head = col >> 6;
  const int c = col & 63;
  const float as_w = att_src[head * 64 + c];
  const float ad_w = att_dst[head * 64 + c];
  __syncthreads();
  float wreg[64];
#pragma unroll
  for (int cc = 0; cc < 64; ++cc) wreg[cc] = W1s[cc * 128 + col];

  const int node0 = blockIdx.x * 32;
  for (int it = 0; it < 16; ++it) {
    const int nbase = node0 + it * 2;
    __syncthreads();
    if (threadIdx.x < 128) {
      const int nn = nbase + (threadIdx.x >> 6);
      if (nn < N) xs[threadIdx.x >> 6][threadIdx.x & 63] = x[(size_t)nn * 64 + (threadIdx.x & 63)];
    }
    __syncthreads();
    const int n = nbase + ln;
    if (n >= N) continue;
    float acc = 0.f;
#pragma unroll
    for (int q = 0; q < 16; ++q) {
      const float4 xv = *(const float4*)&xs[ln][q * 4];
      acc = fmaf(xv.x, wreg[q * 4 + 0], acc);
      acc = fmaf(xv.y, wreg[q * 4 + 1], acc);
      acc = fmaf(xv.z, wreg[q * 4 + 2], acc);
      acc = fmaf(xv.w, wreg[q * 4 + 3], acc);
    }
    h1[(size_t)n * 128 + col] = f2bf(acc);
    float vs = acc * as_w;
    float vd = acc * ad_w;
#pragma unroll
    for (int off = 32; off > 0; off >>= 1) {
      vs += __shfl_down(vs, off, 64);
      vd += __shfl_down(vd, off, 64);
    }
    if (c == 0) { a_s[n * 2 + head] = vs; a_d[n * 2 + head] = vd; }
  }
}

// ---------------- CSR build ----------------
__global__ void k_zero_int(int* __restrict__ p, int n) {
  int i = blockIdx.x * 256 + threadIdx.x;
  if (i < n) p[i] = 0;
}

__global__ void k_deg(const int* __restrict__ dst, int E, int N, int* __restrict__ deg) {
  int e = blockIdx.x * 256 + threadIdx.x;
  if (e < E + N) {
    int d = (e < E) ? dst[e] : (e - E);
    atomicAdd(&deg[d], 1);
  }
}

// hierarchical scan, pass 1
__global__ void k_scan1(const int* __restrict__ deg, int* __restrict__ tilescan,
                        int* __restrict__ blocksum, int N) {
  __shared__ int s[1024];
  const int tid = threadIdx.x;
  const int gid = blockIdx.x * 1024 + tid;
  const int v = (gid < N) ? deg[gid] : 0;
  s[tid] = v;
  __syncthreads();
  for (int off = 1; off < 1024; off <<= 1) {
    const int t = (tid >= off) ? s[tid - off] : 0;
    __syncthreads();
    s[tid] += t;
    __syncthreads();
  }
  if (gid < N) tilescan[gid] = s[tid] - v;
  if (tid == 1023) blocksum[blockIdx.x] = s[1023];
}

// pass 2
__global__ void k_scan2(int* __restrict__ blocksum, int nb) {
  __shared__ int s[1024];
  const int tid = threadIdx.x;
  const int v = (tid < nb) ? blocksum[tid] : 0;
  s[tid] = v;
  __syncthreads();
  for (int off = 1; off < 1024; off <<= 1) {
    const int t = (tid >= off) ? s[tid - off] : 0;
    __syncthreads();
    s[tid] += t;
    __syncthreads();
  }
  if (tid < nb) blocksum[tid] = s[tid] - v;
}

// pass 3
__global__ void k_scan3(int* __restrict__ rowptr, const int* __restrict__ blocksum,
                        int* __restrict__ cursor, int N, int Etot) {
  const int gid = blockIdx.x * 256 + threadIdx.x;
  if (gid < N) {
    const int r = rowptr[gid] + blocksum[gid >> 10];
    rowptr[gid] = r;
    cursor[gid] = r;
  }
  if (gid == 0) rowptr[N] = Etot;
}

__global__ void k_fill(const int* __restrict__ src, const int* __restrict__ dst, int E, int N,
                       int* __restrict__ cursor, int* __restrict__ adj) {
  int e = blockIdx.x * 256 + threadIdx.x;
  if (e < E + N) {
    int s, d;
    if (e < E) { s = src[e]; d = dst[e]; } else { s = d = e - E; }
    int pos = atomicAdd(&cursor[d], 1);
    adj[pos] = s;
  }
}

// ---------------- GAT layer 1 aggregate ----------------
__global__ void k_gat1(const unsigned short* __restrict__ h1, const float* __restrict__ as1,
                       const float* __restrict__ ad1, const int* __restrict__ rowptr,
                       const int* __restrict__ adj, const float* __restrict__ b1,
                       float* __restrict__ g, int N) {
  const int w = threadIdx.x >> 6;
  const int l = threadIdx.x & 63;
  const int n = blockIdx.x * 4 + w;
  if (n >= N) return;
  const int half = l >> 5;
  const int q = l & 31;       // channels 4q..4q+3
  const int head = q >> 4;
  const float adh = ad1[n * 2 + head];
  float a0 = 0.f, a1 = 0.f, a2 = 0.f, a3 = 0.f, dsum = 0.f;
  const int kb = rowptr[n], ke = rowptr[n + 1];
  const int kend = ke - 1;
  for (int k = kb + half; k < ke; k += 4) {
    const int eB = k + 2;
    const bool vB = eB < ke;
    const int sA = adj[k];
    const int sB = adj[min(eB, kend)];
    const float xA = as1[sA * 2 + head] + adh;
    const float xB = as1[sB * 2 + head] + adh;
    const uint2 hA = *(const uint2*)(h1 + (size_t)sA * 128 + 4 * q);
    const uint2 hB = *(const uint2*)(h1 + (size_t)sB * 128 + 4 * q);
    const float wA = __expf(leaky(xA));
    const float wB = vB ? __expf(leaky(xB)) : 0.f;
    dsum += wA + wB;
    a0 = fmaf(wA, __uint_as_float(hA.x << 16), a0);
    a1 = fmaf(wA, __uint_as_float(hA.x & 0xFFFF0000u), a1);
    a2 = fmaf(wA, __uint_as_float(hA.y << 16), a2);
    a3 = fmaf(wA, __uint_as_float(hA.y & 0xFFFF0000u), a3);
    a0 = fmaf(wB, __uint_as_float(hB.x << 16), a0);
    a1 = fmaf(wB, __uint_as_float(hB.x & 0xFFFF0000u), a1);
    a2 = fmaf(wB, __uint_as_float(hB.y << 16), a2);
    a3 = fmaf(wB, __uint_as_float(hB.y & 0xFFFF0000u), a3);
  }
  a0 += __shfl_xor(a0, 32, 64);
  a1 += __shfl_xor(a1, 32, 64);
  a2 += __shfl_xor(a2, 32, 64);
  a3 += __shfl_xor(a3, 32, 64);
  dsum += __shfl_xor(dsum, 32, 64);
  if (half == 0) {
    const float inv = 1.f / (dsum + 1e-16f);
    const float4 bv = *(const float4*)(b1 + 4 * q);
    float g0 = fmaf(a0, inv, bv.x);
    float g1 = fmaf(a1, inv, bv.y);
    float g2v = fmaf(a2, inv, bv.z);
    float g3 = fmaf(a3, inv, bv.w);
    g0 = g0 > 0.f ? g0 : expm1f(g0);
    g1 = g1 > 0.f ? g1 : expm1f(g1);
    g2v = g2v > 0.f ? g2v : expm1f(g2v);
    g3 = g3 > 0.f ? g3 : expm1f(g3);
    *(float4*)(g + (size_t)n * 128 + 4 * q) = make_float4(g0, g1, g2v, g3);
  }
}

// ---------------- GAT layer 2 linear: h2[N,64] = g[N,128] @ W2[128,64] (bf16 out)
__global__ void k_h2(const float* __restrict__ g, const float* __restrict__ W2,
                     const float* __restrict__ att_s, const float* __restrict__ att_d,
                     unsigned short* __restrict__ h2, float* __restrict__ a_s,
                     float* __restrict__ a_d, int N) {
  __shared__ __align__(16) float W2s[128 * 64];
  __shared__ __align__(16) float gs[2][128];
  __shared__ float part[2][64];
  for (int i = threadIdx.x; i < 128 * 64; i += 256) W2s[i] = W2[i];
  const int col = threadIdx.x & 63;
  const int kh  = (threadIdx.x >> 6) & 1;
  const int ln  = threadIdx.x >> 7;
  const float as_w = att_s[col], ad_w = att_d[col];
  __syncthreads();
  float wreg[64];
#pragma unroll
  for (int cc = 0; cc < 64; ++cc) wreg[cc] = W2s[(kh * 64 + cc) * 64 + col];

  const int node0 = blockIdx.x * 32;
  for (int it = 0; it < 16; ++it) {
    const int nbase = node0 + it * 2;
    __syncthreads();
    {
      const int nn = nbase + (threadIdx.x >> 7);
      if (nn < N) gs[threadIdx.x >> 7][threadIdx.x & 127] = g[(size_t)nn * 128 + (threadIdx.x & 127)];
    }
    __syncthreads();
    const int n = nbase + ln;
    float acc = 0.f;
    if (n < N) {
#pragma unroll
      for (int q = 0; q < 16; ++q) {
        const float4 gv = *(const float4*)&gs[ln][kh * 64 + q * 4];
        acc = fmaf(gv.x, wreg[q * 4 + 0], acc);
        acc = fmaf(gv.y, wreg[q * 4 + 1], acc);
        acc = fmaf(gv.z, wreg[q * 4 + 2], acc);
        acc = fmaf(gv.w, wreg[q * 4 + 3], acc);
      }
    }
    if (kh == 1) part[ln][col] = acc;
    __syncthreads();
    if (kh == 0 && n < N) {
      acc += part[ln][col];
      h2[(size_t)n * 64 + col] = f2bf(acc);
      float vs = acc * as_w, vd = acc * ad_w;
#pragma unroll
      for (int off = 32; off > 0; off >>= 1) {
        vs += __shfl_down(vs, off, 64);
        vd += __shfl_down(vd, off, 64);
      }
      if (col == 0) { a_s[n] = vs; a_d[n] = vd; }
    }
  }
}

// ---------------- GAT layer 2 aggregate ----------------
__global__ void k_gat2(const unsigned short* __restrict__ h2, const float* __restrict__ as2,
                       const float* __restrict__ ad2, const int* __restrict__ rowptr,
                       const int* __restrict__ adj, const float* __restrict__ b2,
                       float* __restrict__ g2, int N) {
  const int w = threadIdx.x >> 6;
  const int l = threadIdx.x & 63;
  const int n = blockIdx.x * 4 + w;
  if (n >= N) return;
  const int half = l >> 5;
  const int q = l & 31;       // channels 2q, 2q+1
  const float adh = ad2[n];
  float a0 = 0.f, a1 = 0.f, dsum = 0.f;
  const int kb = rowptr[n], ke = rowptr[n + 1];
  const int kend = ke - 1;
  for (int k = kb + half; k < ke; k += 4) {
    const int eB = k + 2;
    const bool vB = eB < ke;
    const int sA = adj[k];
    const int sB = adj[min(eB, kend)];
    const float xA = as2[sA] + adh;
    const float xB = as2[sB] + adh;
    const unsigned hA = *(const unsigned*)(h2 + (size_t)sA * 64 + 2 * q);
    const unsigned hB = *(const unsigned*)(h2 + (size_t)sB * 64 + 2 * q);
    const float wA = __expf(leaky(xA));
    const float wB = vB ? __expf(leaky(xB)) : 0.f;
    dsum += wA + wB;
    a0 = fmaf(wA, __uint_as_float(hA << 16), a0);
    a1 = fmaf(wA, __uint_as_float(hA & 0xFFFF0000u), a1);
    a0 = fmaf(wB, __uint_as_float(hB << 16), a0);
    a1 = fmaf(wB, __uint_as_float(hB & 0xFFFF0000u), a1);
  }
  a0 += __shfl_xor(a0, 32, 64);
  a1 += __shfl_xor(a1, 32, 64);
  dsum += __shfl_xor(dsum, 32, 64);
  if (half == 0) {
    const float inv = 1.f / (dsum + 1e-16f);
    const float2 bv = *(const float2*)(b2 + 2 * q);
    ((float2*)g2)[(size_t)n * 32 + q] =
        make_float2(fmaf(a0, inv, bv.x), fmaf(a1, inv, bv.y));
  }
}

// ---------------- build x matrix, bf16, K-blocked: xb[k/32][512][32] ----------------
__global__ void k_xmat(const int* __restrict__ user_idx, const int* __restrict__ ctx_idx,
                       const float* __restrict__ user_emb, const float* __restrict__ g2,
                       unsigned short* __restrict__ xb) {
  const int b = blockIdx.x;
  const int k = threadIdx.x;  // 0..255
  float v;
  if (k < 64) {
    v = user_emb[(size_t)user_idx[b] * 64 + k];
  } else {
    const int c = (k - 64) >> 6;
    v = g2[(size_t)ctx_idx[b * 3 + c] * 64 + (k & 63)];
  }
  xb[(size_t)(k >> 5) * (512 * 32) + b * 32 + (k & 31)] = f2bf(v);
}

// ---------------- final FC via MFMA, A-in-registers / B-streamed ----------------
// 512 threads = 8 waves; wave w owns rows [64w, 64w+64). A frags persistent in
// VGPRs (loaded once from L2-resident xb). Loop over 16-col tiles of fc_w:
// stage 256x16 f32 -> bf16 LDS (col-major, 264-short col stride -> 2-way banks),
// 8 ds_read_b128 + 32 MFMA per wave, write 512x16 outputs. BW-bound.
__global__ __launch_bounds__(512) void k_fc(const unsigned short* __restrict__ xb,
                                            const float* __restrict__ fc_w,
                                            const float* __restrict__ fc_b,
                                            float* __restrict__ out, int NSRV,
                                            int ntiles, int tpb) {
  __shared__ __align__(16) unsigned short Blds[16 * 264];  // [col][k], 8.25 KB

  const int tid = threadIdx.x;
  const int w = tid >> 6;
  const int lane = tid & 63;
  const int l15 = lane & 15;
  const int kg = lane >> 4;

  // persistent A fragments: afr[mf][ks], row = w*64 + mf*16 + l15
  short8 afr[4][8];
#pragma unroll
  for (int mf = 0; mf < 4; ++mf) {
    const int row = w * 64 + mf * 16 + l15;
#pragma unroll
    for (int ks = 0; ks < 8; ++ks) {
      afr[mf][ks] = *(const short8*)(xb + (size_t)ks * 16384 + row * 32 + kg * 8);
    }
  }

  const int sc = tid & 15;   // stage: col in tile
  const int sk = tid >> 4;   // stage: k row 0..31 (covers 256 with 8 iters)

  const int t0 = blockIdx.x * tpb;
  const int t1 = min(t0 + tpb, ntiles);
  for (int t = t0; t < t1; ++t) {
    const int j0 = t * 16;
    const int cg = j0 + sc;
    const bool okc = cg < NSRV;
    // load B tile to regs (coalesced 64B segments)
    float v[8];
#pragma unroll
    for (int i = 0; i < 8; ++i)
      v[i] = okc ? fc_w[(size_t)(sk + i * 32) * NSRV + cg] : 0.f;
    __syncthreads();  // previous tile's ds_reads complete
#pragma unroll
    for (int i = 0; i < 8; ++i)
      Blds[sc * 264 + sk + i * 32] = f2bf(v[i]);
    __syncthreads();
    // B frags
    short8 bfr[8];
#pragma unroll
    for (int ks = 0; ks < 8; ++ks)
      bfr[ks] = *(const short8*)&Blds[l15 * 264 + ks * 32 + kg * 8];
    // MFMA
    f32x4 acc[4];
#pragma unroll
    for (int mf = 0; mf < 4; ++mf) acc[mf] = (f32x4){0.f, 0.f, 0.f, 0.f};
#pragma unroll
    for (int ks = 0; ks < 8; ++ks)
#pragma unroll
      for (int mf = 0; mf < 4; ++mf)
        acc[mf] = __builtin_amdgcn_mfma_f32_16x16x32_bf16(afr[mf][ks], bfr[ks], acc[mf], 0, 0, 0);
    // epilogue
    const int col = j0 + l15;
    if (col < NSRV) {
      const float bias = fc_b[col];
#pragma unroll
      for (int mf = 0; mf < 4; ++mf) {
        const int rbase = w * 64 + mf * 16 + kg * 4;
#pragma unroll
        for (int r = 0; r < 4; ++r)
          out[(size_t)(rbase + r) * NSRV + col] = acc[mf][r] + bias;
      }
    }
  }
}

// =====================================================================
extern "C" void kernel_launch(void* const* d_in, const int* in_sizes, int n_in,
                              void* d_out, int out_size, void* d_ws, size_t ws_size,
                              hipStream_t stream) {
  const int* user_idx    = (const int*)d_in[0];
  const int* context_idx = (const int*)d_in[1];
  const int* edge_index  = (const int*)d_in[2];
  const float* user_emb  = (const float*)d_in[3];
  const float* service_emb = (const float*)d_in[4];
  const float* W1        = (const float*)d_in[5];
  const float* att_src1  = (const float*)d_in[6];
  const float* att_dst1  = (const float*)d_in[7];
  const float* b1        = (const float*)d_in[8];
  const float* W2        = (const float*)d_in[9];
  const float* att_src2  = (const float*)d_in[10];
  const float* att_dst2  = (const float*)d_in[11];
  const float* b2        = (const float*)d_in[12];
  const float* fc_w      = (const float*)d_in[13];
  const float* fc_b      = (const float*)d_in[14];
  float* out = (float*)d_out;

  const int B    = in_sizes[0];
  const int E    = in_sizes[2] / 2;
  const int N    = in_sizes[4] / 64;
  const int NSRV = in_sizes[14];
  const int Etot = E + N;
  (void)B;

  const int* edge_src = edge_index;
  const int* edge_dst = edge_index + E;

  // ---- workspace layout ----
  char* ws = (char*)d_ws;
  size_t off = 0;
  auto alloc = [&](size_t bytes) {
    void* p = ws + off;
    off = (off + bytes + 255) & ~(size_t)255;
    return p;
  };
  unsigned short* h1 = (unsigned short*)alloc((size_t)N * 128 * 2);  // reused as h2
  float* g      = (float*)alloc((size_t)N * 128 * 4);                // reused as g2
  float* as1    = (float*)alloc((size_t)N * 2 * 4);
  float* ad1    = (float*)alloc((size_t)N * 2 * 4);
  float* as2    = (float*)alloc((size_t)N * 4);
  float* ad2    = (float*)alloc((size_t)N * 4);
  int*   deg    = (int*)alloc((size_t)N * 4);
  int*   rowptr = (int*)alloc((size_t)(N + 1) * 4);
  int*   cursor = (int*)alloc((size_t)N * 4);
  int*   adj    = (int*)alloc((size_t)Etot * 4);
  int*   blocksum = (int*)alloc(1024 * 4);
  unsigned short* xb = (unsigned short*)alloc((size_t)512 * 256 * 2);
  unsigned short* h2 = h1;
  float* g2 = g;
  (void)ws_size;

  const int nblk_N = (N + 255) / 256;
  const int nblk_E = (Etot + 255) / 256;
  const int ntile  = (N + 1023) / 1024;

  // GAT layer 1 linear
  k_h1<<<(N + 31) / 32, 256, 0, stream>>>(service_emb, W1, att_src1, att_dst1, h1, as1, ad1, N);

  // CSR build
  k_zero_int<<<nblk_N, 256, 0, stream>>>(deg, N);
  k_deg<<<nblk_E, 256, 0, stream>>>(edge_dst, E, N, deg);
  k_scan1<<<ntile, 1024, 0, stream>>>(deg, rowptr, blocksum, N);
  k_scan2<<<1, 1024, 0, stream>>>(blocksum, ntile);
  k_scan3<<<nblk_N, 256, 0, stream>>>(rowptr, blocksum, cursor, N, Etot);
  k_fill<<<nblk_E, 256, 0, stream>>>(edge_src, edge_dst, E, N, cursor, adj);

  // layer 1 aggregate -> g (elu'd)
  k_gat1<<<(N + 3) / 4, 256, 0, stream>>>(h1, as1, ad1, rowptr, adj, b1, g, N);

  // layer 2 linear (h2 overlays h1)
  k_h2<<<(N + 31) / 32, 256, 0, stream>>>(g, W2, att_src2, att_dst2, h2, as2, ad2, N);

  // layer 2 aggregate -> g2 (overlays g)
  k_gat2<<<(N + 3) / 4, 256, 0, stream>>>(h2, as2, ad2, rowptr, adj, b2, g2, N);

  // gather features -> bf16 K-blocked
  k_xmat<<<512, 256, 0, stream>>>(user_idx, context_idx, user_emb, g2, xb);

  // final FC (MFMA, A-persistent)
  const int nfct = (NSRV + 15) / 16;
  const int tpb = 5;
  k_fc<<<(nfct + tpb - 1) / tpb, 512, 0, stream>>>(xb, fc_w, fc_b, out, NSRV, nfct, tpb);
}

// Round 6
// 474.163 us; speedup vs baseline: 2.9413x; 1.3454x over previous
//
#include <hip/hip_runtime.h>
#include <hip/hip_bf16.h>
#include <math.h>

#define NEG_SLOPE 0.2f

// CSR binning parameters (N=100000, E+N~1.7M; requires N < 2^18 and NB <= 256)
#define NPB 512       // nodes per bucket
#define NPB_SH 9
#define SRC_BITS 18
#define LCAP 16384    // LDS adj staging capacity (edges) per bucket

typedef __attribute__((ext_vector_type(8))) short short8;
typedef __attribute__((ext_vector_type(4))) float f32x4;

__device__ __forceinline__ float leaky(float x) { return x > 0.f ? x : NEG_SLOPE * x; }

__device__ __forceinline__ unsigned short f2bf(float f) {
  unsigned u = __float_as_uint(f);
  unsigned r = (u + 0x7FFFu + ((u >> 16) & 1u)) >> 16;  // RNE
  return (unsigned short)r;
}

// ---------------- GAT layer 1 linear: h1[N,128] = x[N,64] @ W1[64,128] (bf16 out)
__global__ void k_h1(const float* __restrict__ x, const float* __restrict__ W1,
                     const float* __restrict__ att_src, const float* __restrict__ att_dst,
                     unsigned short* __restrict__ h1, float* __restrict__ a_s,
                     float* __restrict__ a_d, int N) {
  __shared__ __align__(16) float W1s[64 * 128];
  __shared__ __align__(16) float xs[2][64];
  for (int i = threadIdx.x; i < 64 * 128; i += 256) W1s[i] = W1[i];
  const int ln  = threadIdx.x >> 7;   // node slot 0/1
  const int col = threadIdx.x & 127;  // output channel
  const int head = col >> 6;
  const int c = col & 63;
  const float as_w = att_src[head * 64 + c];
  const float ad_w = att_dst[head * 64 + c];
  __syncthreads();
  float wreg[64];
#pragma unroll
  for (int cc = 0; cc < 64; ++cc) wreg[cc] = W1s[cc * 128 + col];

  const int node0 = blockIdx.x * 32;
  for (int it = 0; it < 16; ++it) {
    const int nbase = node0 + it * 2;
    __syncthreads();
    if (threadIdx.x < 128) {
      const int nn = nbase + (threadIdx.x >> 6);
      if (nn < N) xs[threadIdx.x >> 6][threadIdx.x & 63] = x[(size_t)nn * 64 + (threadIdx.x & 63)];
    }
    __syncthreads();
    const int n = nbase + ln;
    if (n >= N) continue;
    float acc = 0.f;
#pragma unroll
    for (int q = 0; q < 16; ++q) {
      const float4 xv = *(const float4*)&xs[ln][q * 4];
      acc = fmaf(xv.x, wreg[q * 4 + 0], acc);
      acc = fmaf(xv.y, wreg[q * 4 + 1], acc);
      acc = fmaf(xv.z, wreg[q * 4 + 2], acc);
      acc = fmaf(xv.w, wreg[q * 4 + 3], acc);
    }
    h1[(size_t)n * 128 + col] = f2bf(acc);
    float vs = acc * as_w;
    float vd = acc * ad_w;
#pragma unroll
    for (int off = 32; off > 0; off >>= 1) {
      vs += __shfl_down(vs, off, 64);
      vd += __shfl_down(vd, off, 64);
    }
    if (c == 0) { a_s[n * 2 + head] = vs; a_d[n * 2 + head] = vd; }
  }
}

// ---------------- CSR build via two-level binning ----------------
// pass 1: per-block LDS histogram of bucket (dst>>NPB_SH), flush to global
__global__ __launch_bounds__(1024) void k_bcount(const int* __restrict__ dst, int E, int Etot,
                                                 int epb, int* __restrict__ bucketCnt, int NB) {
  __shared__ int hist[256];
  const int tid = threadIdx.x;
  if (tid < 256) hist[tid] = 0;
  __syncthreads();
  const int e0 = blockIdx.x * epb;
  const int e1 = min(e0 + epb, Etot);
  for (int e = e0 + tid; e < e1; e += 1024) {
    const int d = (e < E) ? dst[e] : (e - E);
    atomicAdd(&hist[d >> NPB_SH], 1);
  }
  __syncthreads();
  if (tid < NB) {
    const int c = hist[tid];
    if (c) atomicAdd(&bucketCnt[tid], c);
  }
}

// pass 2: single-block scan of bucket counts -> base & cursor; also rowptr[N]
__global__ void k_bscan(const int* __restrict__ bucketCnt, int* __restrict__ bucketBase,
                        int* __restrict__ bucketCursor, int NB, int Etot,
                        int* __restrict__ rowptr, int N) {
  __shared__ int s[256];
  const int tid = threadIdx.x;
  const int v = (tid < NB) ? bucketCnt[tid] : 0;
  s[tid] = v;
  __syncthreads();
  for (int off = 1; off < 256; off <<= 1) {
    const int t = (tid >= off) ? s[tid - off] : 0;
    __syncthreads();
    s[tid] += t;
    __syncthreads();
  }
  if (tid < NB) {
    const int base = s[tid] - v;
    bucketBase[tid] = base;
    bucketCursor[tid] = base;
  }
  if (tid == 0) { bucketBase[NB] = Etot; rowptr[N] = Etot; }
}

// pass 3: chunk-reserved scatter of packed records (src | localdst<<SRC_BITS)
__global__ __launch_bounds__(1024) void k_bscatter(const int* __restrict__ src,
                                                   const int* __restrict__ dst, int E, int Etot,
                                                   int epb, int* __restrict__ bucketCursor,
                                                   unsigned* __restrict__ rec, int NB) {
  __shared__ int hist[256];
  __shared__ int cur[256];
  const int tid = threadIdx.x;
  if (tid < 256) hist[tid] = 0;
  __syncthreads();
  const int e0 = blockIdx.x * epb;
  const int e1 = min(e0 + epb, Etot);
  for (int e = e0 + tid; e < e1; e += 1024) {
    const int d = (e < E) ? dst[e] : (e - E);
    atomicAdd(&hist[d >> NPB_SH], 1);
  }
  __syncthreads();
  if (tid < NB) {
    const int c = hist[tid];
    cur[tid] = c ? atomicAdd(&bucketCursor[tid], c) : 0;
  }
  __syncthreads();
  for (int e = e0 + tid; e < e1; e += 1024) {
    int sv, d;
    if (e < E) { sv = src[e]; d = dst[e]; } else { sv = d = e - E; }
    const int b = d >> NPB_SH;
    const int p = atomicAdd(&cur[b], 1);
    rec[p] = (unsigned)sv | ((unsigned)(d & (NPB - 1)) << SRC_BITS);
  }
}

// pass 4: one block per bucket -> local degree count, scan, LDS scatter, copy out
__global__ __launch_bounds__(1024) void k_bcsr(const unsigned* __restrict__ rec,
                                               const int* __restrict__ bucketBase,
                                               int* __restrict__ rowptr, int* __restrict__ adj,
                                               int N, int NB) {
  __shared__ int ldeg[NPB];
  __shared__ int s[NPB];
  __shared__ int ladj[LCAP];
  const int b = blockIdx.x;
  const int tid = threadIdx.x;
  const int e0 = bucketBase[b];
  const int e1 = bucketBase[b + 1];
  const int cnt = e1 - e0;
  if (tid < NPB) ldeg[tid] = 0;
  __syncthreads();
  for (int i = tid; i < cnt; i += 1024)
    atomicAdd(&ldeg[rec[e0 + i] >> SRC_BITS], 1);
  __syncthreads();
  int v = 0;
  if (tid < NPB) { v = ldeg[tid]; s[tid] = v; }
  __syncthreads();
  for (int off = 1; off < NPB; off <<= 1) {
    int t = 0;
    if (tid < NPB && tid >= off) t = s[tid - off];
    __syncthreads();
    if (tid < NPB) s[tid] += t;
    __syncthreads();
  }
  if (tid < NPB) {
    const int excl = s[tid] - v;
    const int node = b * NPB + tid;
    if (node < N) rowptr[node] = e0 + excl;
    ldeg[tid] = excl;  // reuse as scatter cursor
  }
  __syncthreads();
  if (cnt <= LCAP) {
    for (int i = tid; i < cnt; i += 1024) {
      const unsigned r = rec[e0 + i];
      const int p = atomicAdd(&ldeg[r >> SRC_BITS], 1);
      ladj[p] = (int)(r & ((1u << SRC_BITS) - 1));
    }
    __syncthreads();
    for (int i = tid; i < cnt; i += 1024) adj[e0 + i] = ladj[i];
  } else {  // guaranteed-correct fallback (never expected for this input)
    for (int i = tid; i < cnt; i += 1024) {
      const unsigned r = rec[e0 + i];
      const int p = atomicAdd(&ldeg[r >> SRC_BITS], 1);
      adj[e0 + p] = (int)(r & ((1u << SRC_BITS) - 1));
    }
  }
}

// ---------------- GAT layer 1 aggregate ----------------
__global__ void k_gat1(const unsigned short* __restrict__ h1, const float* __restrict__ as1,
                       const float* __restrict__ ad1, const int* __restrict__ rowptr,
                       const int* __restrict__ adj, const float* __restrict__ b1,
                       float* __restrict__ g, int N) {
  const int w = threadIdx.x >> 6;
  const int l = threadIdx.x & 63;
  const int n = blockIdx.x * 4 + w;
  if (n >= N) return;
  const int half = l >> 5;
  const int q = l & 31;       // channels 4q..4q+3
  const int head = q >> 4;
  const float adh = ad1[n * 2 + head];
  float a0 = 0.f, a1 = 0.f, a2 = 0.f, a3 = 0.f, dsum = 0.f;
  const int kb = rowptr[n], ke = rowptr[n + 1];
  const int kend = ke - 1;
  for (int k = kb + half; k < ke; k += 4) {
    const int eB = k + 2;
    const bool vB = eB < ke;
    const int sA = adj[k];
    const int sB = adj[min(eB, kend)];
    const float xA = as1[sA * 2 + head] + adh;
    const float xB = as1[sB * 2 + head] + adh;
    const uint2 hA = *(const uint2*)(h1 + (size_t)sA * 128 + 4 * q);
    const uint2 hB = *(const uint2*)(h1 + (size_t)sB * 128 + 4 * q);
    const float wA = __expf(leaky(xA));
    const float wB = vB ? __expf(leaky(xB)) : 0.f;
    dsum += wA + wB;
    a0 = fmaf(wA, __uint_as_float(hA.x << 16), a0);
    a1 = fmaf(wA, __uint_as_float(hA.x & 0xFFFF0000u), a1);
    a2 = fmaf(wA, __uint_as_float(hA.y << 16), a2);
    a3 = fmaf(wA, __uint_as_float(hA.y & 0xFFFF0000u), a3);
    a0 = fmaf(wB, __uint_as_float(hB.x << 16), a0);
    a1 = fmaf(wB, __uint_as_float(hB.x & 0xFFFF0000u), a1);
    a2 = fmaf(wB, __uint_as_float(hB.y << 16), a2);
    a3 = fmaf(wB, __uint_as_float(hB.y & 0xFFFF0000u), a3);
  }
  a0 += __shfl_xor(a0, 32, 64);
  a1 += __shfl_xor(a1, 32, 64);
  a2 += __shfl_xor(a2, 32, 64);
  a3 += __shfl_xor(a3, 32, 64);
  dsum += __shfl_xor(dsum, 32, 64);
  if (half == 0) {
    const float inv = 1.f / (dsum + 1e-16f);
    const float4 bv = *(const float4*)(b1 + 4 * q);
    float g0 = fmaf(a0, inv, bv.x);
    float g1 = fmaf(a1, inv, bv.y);
    float g2v = fmaf(a2, inv, bv.z);
    float g3 = fmaf(a3, inv, bv.w);
    g0 = g0 > 0.f ? g0 : expm1f(g0);
    g1 = g1 > 0.f ? g1 : expm1f(g1);
    g2v = g2v > 0.f ? g2v : expm1f(g2v);
    g3 = g3 > 0.f ? g3 : expm1f(g3);
    *(float4*)(g + (size_t)n * 128 + 4 * q) = make_float4(g0, g1, g2v, g3);
  }
}

// ---------------- GAT layer 2 linear: h2[N,64] = g[N,128] @ W2[128,64] (bf16 out)
__global__ void k_h2(const float* __restrict__ g, const float* __restrict__ W2,
                     const float* __restrict__ att_s, const float* __restrict__ att_d,
                     unsigned short* __restrict__ h2, float* __restrict__ a_s,
                     float* __restrict__ a_d, int N) {
  __shared__ __align__(16) float W2s[128 * 64];
  __shared__ __align__(16) float gs[2][128];
  __shared__ float part[2][64];
  for (int i = threadIdx.x; i < 128 * 64; i += 256) W2s[i] = W2[i];
  const int col = threadIdx.x & 63;
  const int kh  = (threadIdx.x >> 6) & 1;
  const int ln  = threadIdx.x >> 7;
  const float as_w = att_s[col], ad_w = att_d[col];
  __syncthreads();
  float wreg[64];
#pragma unroll
  for (int cc = 0; cc < 64; ++cc) wreg[cc] = W2s[(kh * 64 + cc) * 64 + col];

  const int node0 = blockIdx.x * 32;
  for (int it = 0; it < 16; ++it) {
    const int nbase = node0 + it * 2;
    __syncthreads();
    {
      const int nn = nbase + (threadIdx.x >> 7);
      if (nn < N) gs[threadIdx.x >> 7][threadIdx.x & 127] = g[(size_t)nn * 128 + (threadIdx.x & 127)];
    }
    __syncthreads();
    const int n = nbase + ln;
    float acc = 0.f;
    if (n < N) {
#pragma unroll
      for (int q = 0; q < 16; ++q) {
        const float4 gv = *(const float4*)&gs[ln][kh * 64 + q * 4];
        acc = fmaf(gv.x, wreg[q * 4 + 0], acc);
        acc = fmaf(gv.y, wreg[q * 4 + 1], acc);
        acc = fmaf(gv.z, wreg[q * 4 + 2], acc);
        acc = fmaf(gv.w, wreg[q * 4 + 3], acc);
      }
    }
    if (kh == 1) part[ln][col] = acc;
    __syncthreads();
    if (kh == 0 && n < N) {
      acc += part[ln][col];
      h2[(size_t)n * 64 + col] = f2bf(acc);
      float vs = acc * as_w, vd = acc * ad_w;
#pragma unroll
      for (int off = 32; off > 0; off >>= 1) {
        vs += __shfl_down(vs, off, 64);
        vd += __shfl_down(vd, off, 64);
      }
      if (col == 0) { a_s[n] = vs; a_d[n] = vd; }
    }
  }
}

// ---------------- GAT layer 2 aggregate ----------------
__global__ void k_gat2(const unsigned short* __restrict__ h2, const float* __restrict__ as2,
                       const float* __restrict__ ad2, const int* __restrict__ rowptr,
                       const int* __restrict__ adj, const float* __restrict__ b2,
                       float* __restrict__ g2, int N) {
  const int w = threadIdx.x >> 6;
  const int l = threadIdx.x & 63;
  const int n = blockIdx.x * 4 + w;
  if (n >= N) return;
  const int half = l >> 5;
  const int q = l & 31;       // channels 2q, 2q+1
  const float adh = ad2[n];
  float a0 = 0.f, a1 = 0.f, dsum = 0.f;
  const int kb = rowptr[n], ke = rowptr[n + 1];
  const int kend = ke - 1;
  for (int k = kb + half; k < ke; k += 4) {
    const int eB = k + 2;
    const bool vB = eB < ke;
    const int sA = adj[k];
    const int sB = adj[min(eB, kend)];
    const float xA = as2[sA] + adh;
    const float xB = as2[sB] + adh;
    const unsigned hA = *(const unsigned*)(h2 + (size_t)sA * 64 + 2 * q);
    const unsigned hB = *(const unsigned*)(h2 + (size_t)sB * 64 + 2 * q);
    const float wA = __expf(leaky(xA));
    const float wB = vB ? __expf(leaky(xB)) : 0.f;
    dsum += wA + wB;
    a0 = fmaf(wA, __uint_as_float(hA << 16), a0);
    a1 = fmaf(wA, __uint_as_float(hA & 0xFFFF0000u), a1);
    a0 = fmaf(wB, __uint_as_float(hB << 16), a0);
    a1 = fmaf(wB, __uint_as_float(hB & 0xFFFF0000u), a1);
  }
  a0 += __shfl_xor(a0, 32, 64);
  a1 += __shfl_xor(a1, 32, 64);
  dsum += __shfl_xor(dsum, 32, 64);
  if (half == 0) {
    const float inv = 1.f / (dsum + 1e-16f);
    const float2 bv = *(const float2*)(b2 + 2 * q);
    ((float2*)g2)[(size_t)n * 32 + q] =
        make_float2(fmaf(a0, inv, bv.x), fmaf(a1, inv, bv.y));
  }
}

// ---------------- build x matrix, bf16, K-blocked: xb[k/32][512][32] ----------------
__global__ void k_xmat(const int* __restrict__ user_idx, const int* __restrict__ ctx_idx,
                       const float* __restrict__ user_emb, const float* __restrict__ g2,
                       unsigned short* __restrict__ xb) {
  const int b = blockIdx.x;
  const int k = threadIdx.x;  // 0..255
  float v;
  if (k < 64) {
    v = user_emb[(size_t)user_idx[b] * 64 + k];
  } else {
    const int c = (k - 64) >> 6;
    v = g2[(size_t)ctx_idx[b * 3 + c] * 64 + (k & 63)];
  }
  xb[(size_t)(k >> 5) * (512 * 32) + b * 32 + (k & 31)] = f2bf(v);
}

// ---------------- final FC via MFMA, A-in-registers / B-streamed ----------------
__global__ __launch_bounds__(512) void k_fc(const unsigned short* __restrict__ xb,
                                            const float* __restrict__ fc_w,
                                            const float* __restrict__ fc_b,
                                            float* __restrict__ out, int NSRV,
                                            int ntiles, int tpb) {
  __shared__ __align__(16) unsigned short Blds[16 * 264];  // [col][k], 8.25 KB

  const int tid = threadIdx.x;
  const int w = tid >> 6;
  const int lane = tid & 63;
  const int l15 = lane & 15;
  const int kg = lane >> 4;

  // persistent A fragments: afr[mf][ks], row = w*64 + mf*16 + l15
  short8 afr[4][8];
#pragma unroll
  for (int mf = 0; mf < 4; ++mf) {
    const int row = w * 64 + mf * 16 + l15;
#pragma unroll
    for (int ks = 0; ks < 8; ++ks) {
      afr[mf][ks] = *(const short8*)(xb + (size_t)ks * 16384 + row * 32 + kg * 8);
    }
  }

  const int sc = tid & 15;   // stage: col in tile
  const int sk = tid >> 4;   // stage: k row 0..31

  const int t0 = blockIdx.x * tpb;
  const int t1 = min(t0 + tpb, ntiles);
  for (int t = t0; t < t1; ++t) {
    const int j0 = t * 16;
    const int cg = j0 + sc;
    const bool okc = cg < NSRV;
    float v[8];
#pragma unroll
    for (int i = 0; i < 8; ++i)
      v[i] = okc ? fc_w[(size_t)(sk + i * 32) * NSRV + cg] : 0.f;
    __syncthreads();
#pragma unroll
    for (int i = 0; i < 8; ++i)
      Blds[sc * 264 + sk + i * 32] = f2bf(v[i]);
    __syncthreads();
    short8 bfr[8];
#pragma unroll
    for (int ks = 0; ks < 8; ++ks)
      bfr[ks] = *(const short8*)&Blds[l15 * 264 + ks * 32 + kg * 8];
    f32x4 acc[4];
#pragma unroll
    for (int mf = 0; mf < 4; ++mf) acc[mf] = (f32x4){0.f, 0.f, 0.f, 0.f};
#pragma unroll
    for (int ks = 0; ks < 8; ++ks)
#pragma unroll
      for (int mf = 0; mf < 4; ++mf)
        acc[mf] = __builtin_amdgcn_mfma_f32_16x16x32_bf16(afr[mf][ks], bfr[ks], acc[mf], 0, 0, 0);
    const int col = j0 + l15;
    if (col < NSRV) {
      const float bias = fc_b[col];
#pragma unroll
      for (int mf = 0; mf < 4; ++mf) {
        const int rbase = w * 64 + mf * 16 + kg * 4;
#pragma unroll
        for (int r = 0; r < 4; ++r)
          out[(size_t)(rbase + r) * NSRV + col] = acc[mf][r] + bias;
      }
    }
  }
}

// =====================================================================
extern "C" void kernel_launch(void* const* d_in, const int* in_sizes, int n_in,
                              void* d_out, int out_size, void* d_ws, size_t ws_size,
                              hipStream_t stream) {
  const int* user_idx    = (const int*)d_in[0];
  const int* context_idx = (const int*)d_in[1];
  const int* edge_index  = (const int*)d_in[2];
  const float* user_emb  = (const float*)d_in[3];
  const float* service_emb = (const float*)d_in[4];
  const float* W1        = (const float*)d_in[5];
  const float* att_src1  = (const float*)d_in[6];
  const float* att_dst1  = (const float*)d_in[7];
  const float* b1        = (const float*)d_in[8];
  const float* W2        = (const float*)d_in[9];
  const float* att_src2  = (const float*)d_in[10];
  const float* att_dst2  = (const float*)d_in[11];
  const float* b2        = (const float*)d_in[12];
  const float* fc_w      = (const float*)d_in[13];
  const float* fc_b      = (const float*)d_in[14];
  float* out = (float*)d_out;

  const int B    = in_sizes[0];
  const int E    = in_sizes[2] / 2;
  const int N    = in_sizes[4] / 64;
  const int NSRV = in_sizes[14];
  const int Etot = E + N;
  (void)B;

  const int* edge_src = edge_index;
  const int* edge_dst = edge_index + E;

  // ---- workspace layout ----
  char* ws = (char*)d_ws;
  size_t off = 0;
  auto alloc = [&](size_t bytes) {
    void* p = ws + off;
    off = (off + bytes + 255) & ~(size_t)255;
    return p;
  };
  unsigned short* h1 = (unsigned short*)alloc((size_t)N * 128 * 2);  // reused as h2
  float* g      = (float*)alloc((size_t)N * 128 * 4);                // reused as g2
  float* as1    = (float*)alloc((size_t)N * 2 * 4);
  float* ad1    = (float*)alloc((size_t)N * 2 * 4);
  float* as2    = (float*)alloc((size_t)N * 4);
  float* ad2    = (float*)alloc((size_t)N * 4);
  int*   rowptr = (int*)alloc((size_t)(N + 1) * 4);
  int*   adj    = (int*)alloc((size_t)Etot * 4);
  unsigned* rec = (unsigned*)alloc((size_t)Etot * 4);
  int* bucketCnt    = (int*)alloc(256 * 4);
  int* bucketBase   = (int*)alloc(257 * 4);
  int* bucketCursor = (int*)alloc(256 * 4);
  unsigned short* xb = (unsigned short*)alloc((size_t)512 * 256 * 2);
  unsigned short* h2 = h1;
  float* g2 = g;
  (void)ws_size;

  const int NB = (N + NPB - 1) >> NPB_SH;   // 196 for N=100000 (requires <=256)
  const int NBLK2 = 256;
  const int epb = (Etot + NBLK2 - 1) / NBLK2;

  // GAT layer 1 linear
  k_h1<<<(N + 31) / 32, 256, 0, stream>>>(service_emb, W1, att_src1, att_dst1, h1, as1, ad1, N);

  // CSR build (binned)
  hipMemsetAsync(bucketCnt, 0, (size_t)NB * 4, stream);
  k_bcount<<<NBLK2, 1024, 0, stream>>>(edge_dst, E, Etot, epb, bucketCnt, NB);
  k_bscan<<<1, 256, 0, stream>>>(bucketCnt, bucketBase, bucketCursor, NB, Etot, rowptr, N);
  k_bscatter<<<NBLK2, 1024, 0, stream>>>(edge_src, edge_dst, E, Etot, epb, bucketCursor, rec, NB);
  k_bcsr<<<NB, 1024, 0, stream>>>(rec, bucketBase, rowptr, adj, N, NB);

  // layer 1 aggregate -> g (elu'd)
  k_gat1<<<(N + 3) / 4, 256, 0, stream>>>(h1, as1, ad1, rowptr, adj, b1, g, N);

  // layer 2 linear (h2 overlays h1)
  k_h2<<<(N + 31) / 32, 256, 0, stream>>>(g, W2, att_src2, att_dst2, h2, as2, ad2, N);

  // layer 2 aggregate -> g2 (overlays g)
  k_gat2<<<(N + 3) / 4, 256, 0, stream>>>(h2, as2, ad2, rowptr, adj, b2, g2, N);

  // gather features -> bf16 K-blocked
  k_xmat<<<512, 256, 0, stream>>>(user_idx, context_idx, user_emb, g2, xb);

  // final FC (MFMA, A-persistent)
  const int nfct = (NSRV + 15) / 16;
  const int tpb = 5;
  k_fc<<<(nfct + tpb - 1) / tpb, 512, 0, stream>>>(xb, fc_w, fc_b, out, NSRV, nfct, tpb);
}

// Round 7
// 468.052 us; speedup vs baseline: 2.9797x; 1.0131x over previous
//
#include <hip/hip_runtime.h>
#include <hip/hip_bf16.h>
#include <math.h>

#define NEG_SLOPE 0.2f

// CSR binning parameters (N=100000, E+N~1.7M; requires N < 2^18 and NB <= 256)
#define NPB 512       // nodes per bucket
#define NPB_SH 9
#define SRC_BITS 18
#define LCAP 16384    // LDS adj staging capacity (edges) per bucket

typedef __attribute__((ext_vector_type(8))) short short8;
typedef __attribute__((ext_vector_type(4))) float f32x4;

__device__ __forceinline__ float leaky(float x) { return x > 0.f ? x : NEG_SLOPE * x; }

__device__ __forceinline__ unsigned short f2bf(float f) {
  unsigned u = __float_as_uint(f);
  unsigned r = (u + 0x7FFFu + ((u >> 16) & 1u)) >> 16;  // RNE
  return (unsigned short)r;
}

// ---------------- GAT layer 1 linear: h1[N,128] = x[N,64] @ W1[64,128] (bf16 out)
__global__ void k_h1(const float* __restrict__ x, const float* __restrict__ W1,
                     const float* __restrict__ att_src, const float* __restrict__ att_dst,
                     unsigned short* __restrict__ h1, float* __restrict__ a_s,
                     float* __restrict__ a_d, int N) {
  __shared__ __align__(16) float W1s[64 * 128];
  __shared__ __align__(16) float xs[2][64];
  for (int i = threadIdx.x; i < 64 * 128; i += 256) W1s[i] = W1[i];
  const int ln  = threadIdx.x >> 7;   // node slot 0/1
  const int col = threadIdx.x & 127;  // output channel
  const int head = col >> 6;
  const int c = col & 63;
  const float as_w = att_src[head * 64 + c];
  const float ad_w = att_dst[head * 64 + c];
  __syncthreads();
  float wreg[64];
#pragma unroll
  for (int cc = 0; cc < 64; ++cc) wreg[cc] = W1s[cc * 128 + col];

  const int node0 = blockIdx.x * 32;
  for (int it = 0; it < 16; ++it) {
    const int nbase = node0 + it * 2;
    __syncthreads();
    if (threadIdx.x < 128) {
      const int nn = nbase + (threadIdx.x >> 6);
      if (nn < N) xs[threadIdx.x >> 6][threadIdx.x & 63] = x[(size_t)nn * 64 + (threadIdx.x & 63)];
    }
    __syncthreads();
    const int n = nbase + ln;
    if (n >= N) continue;
    float acc = 0.f;
#pragma unroll
    for (int q = 0; q < 16; ++q) {
      const float4 xv = *(const float4*)&xs[ln][q * 4];
      acc = fmaf(xv.x, wreg[q * 4 + 0], acc);
      acc = fmaf(xv.y, wreg[q * 4 + 1], acc);
      acc = fmaf(xv.z, wreg[q * 4 + 2], acc);
      acc = fmaf(xv.w, wreg[q * 4 + 3], acc);
    }
    h1[(size_t)n * 128 + col] = f2bf(acc);
    float vs = acc * as_w;
    float vd = acc * ad_w;
#pragma unroll
    for (int off = 32; off > 0; off >>= 1) {
      vs += __shfl_down(vs, off, 64);
      vd += __shfl_down(vd, off, 64);
    }
    if (c == 0) { a_s[n * 2 + head] = vs; a_d[n * 2 + head] = vd; }
  }
}

// ---------------- CSR build via two-level binning ----------------
__global__ __launch_bounds__(1024) void k_bcount(const int* __restrict__ dst, int E, int Etot,
                                                 int epb, int* __restrict__ bucketCnt, int NB) {
  __shared__ int hist[256];
  const int tid = threadIdx.x;
  if (tid < 256) hist[tid] = 0;
  __syncthreads();
  const int e0 = blockIdx.x * epb;
  const int e1 = min(e0 + epb, Etot);
  for (int e = e0 + tid; e < e1; e += 1024) {
    const int d = (e < E) ? dst[e] : (e - E);
    atomicAdd(&hist[d >> NPB_SH], 1);
  }
  __syncthreads();
  if (tid < NB) {
    const int c = hist[tid];
    if (c) atomicAdd(&bucketCnt[tid], c);
  }
}

__global__ void k_bscan(const int* __restrict__ bucketCnt, int* __restrict__ bucketBase,
                        int* __restrict__ bucketCursor, int NB, int Etot,
                        int* __restrict__ rowptr, int N) {
  __shared__ int s[256];
  const int tid = threadIdx.x;
  const int v = (tid < NB) ? bucketCnt[tid] : 0;
  s[tid] = v;
  __syncthreads();
  for (int off = 1; off < 256; off <<= 1) {
    const int t = (tid >= off) ? s[tid - off] : 0;
    __syncthreads();
    s[tid] += t;
    __syncthreads();
  }
  if (tid < NB) {
    const int base = s[tid] - v;
    bucketBase[tid] = base;
    bucketCursor[tid] = base;
  }
  if (tid == 0) { bucketBase[NB] = Etot; rowptr[N] = Etot; }
}

__global__ __launch_bounds__(1024) void k_bscatter(const int* __restrict__ src,
                                                   const int* __restrict__ dst, int E, int Etot,
                                                   int epb, int* __restrict__ bucketCursor,
                                                   unsigned* __restrict__ rec, int NB) {
  __shared__ int hist[256];
  __shared__ int cur[256];
  const int tid = threadIdx.x;
  if (tid < 256) hist[tid] = 0;
  __syncthreads();
  const int e0 = blockIdx.x * epb;
  const int e1 = min(e0 + epb, Etot);
  for (int e = e0 + tid; e < e1; e += 1024) {
    const int d = (e < E) ? dst[e] : (e - E);
    atomicAdd(&hist[d >> NPB_SH], 1);
  }
  __syncthreads();
  if (tid < NB) {
    const int c = hist[tid];
    cur[tid] = c ? atomicAdd(&bucketCursor[tid], c) : 0;
  }
  __syncthreads();
  for (int e = e0 + tid; e < e1; e += 1024) {
    int sv, d;
    if (e < E) { sv = src[e]; d = dst[e]; } else { sv = d = e - E; }
    const int b = d >> NPB_SH;
    const int p = atomicAdd(&cur[b], 1);
    rec[p] = (unsigned)sv | ((unsigned)(d & (NPB - 1)) << SRC_BITS);
  }
}

__global__ __launch_bounds__(1024) void k_bcsr(const unsigned* __restrict__ rec,
                                               const int* __restrict__ bucketBase,
                                               int* __restrict__ rowptr, int* __restrict__ adj,
                                               int N, int NB) {
  __shared__ int ldeg[NPB];
  __shared__ int s[NPB];
  __shared__ int ladj[LCAP];
  const int b = blockIdx.x;
  const int tid = threadIdx.x;
  const int e0 = bucketBase[b];
  const int e1 = bucketBase[b + 1];
  const int cnt = e1 - e0;
  if (tid < NPB) ldeg[tid] = 0;
  __syncthreads();
  for (int i = tid; i < cnt; i += 1024)
    atomicAdd(&ldeg[rec[e0 + i] >> SRC_BITS], 1);
  __syncthreads();
  int v = 0;
  if (tid < NPB) { v = ldeg[tid]; s[tid] = v; }
  __syncthreads();
  for (int off = 1; off < NPB; off <<= 1) {
    int t = 0;
    if (tid < NPB && tid >= off) t = s[tid - off];
    __syncthreads();
    if (tid < NPB) s[tid] += t;
    __syncthreads();
  }
  if (tid < NPB) {
    const int excl = s[tid] - v;
    const int node = b * NPB + tid;
    if (node < N) rowptr[node] = e0 + excl;
    ldeg[tid] = excl;  // reuse as scatter cursor
  }
  __syncthreads();
  if (cnt <= LCAP) {
    for (int i = tid; i < cnt; i += 1024) {
      const unsigned r = rec[e0 + i];
      const int p = atomicAdd(&ldeg[r >> SRC_BITS], 1);
      ladj[p] = (int)(r & ((1u << SRC_BITS) - 1));
    }
    __syncthreads();
    for (int i = tid; i < cnt; i += 1024) adj[e0 + i] = ladj[i];
  } else {
    for (int i = tid; i < cnt; i += 1024) {
      const unsigned r = rec[e0 + i];
      const int p = atomicAdd(&ldeg[r >> SRC_BITS], 1);
      adj[e0 + p] = (int)(r & ((1u << SRC_BITS) - 1));
    }
  }
}

// ---------------- GAT layer 1 aggregate ----------------
__global__ void k_gat1(const unsigned short* __restrict__ h1, const float* __restrict__ as1,
                       const float* __restrict__ ad1, const int* __restrict__ rowptr,
                       const int* __restrict__ adj, const float* __restrict__ b1,
                       float* __restrict__ g, int N) {
  const int w = threadIdx.x >> 6;
  const int l = threadIdx.x & 63;
  const int n = blockIdx.x * 4 + w;
  if (n >= N) return;
  const int half = l >> 5;
  const int q = l & 31;       // channels 4q..4q+3
  const int head = q >> 4;
  const float adh = ad1[n * 2 + head];
  float a0 = 0.f, a1 = 0.f, a2 = 0.f, a3 = 0.f, dsum = 0.f;
  const int kb = rowptr[n], ke = rowptr[n + 1];
  const int kend = ke - 1;
  for (int k = kb + half; k < ke; k += 4) {
    const int eB = k + 2;
    const bool vB = eB < ke;
    const int sA = adj[k];
    const int sB = adj[min(eB, kend)];
    const float xA = as1[sA * 2 + head] + adh;
    const float xB = as1[sB * 2 + head] + adh;
    const uint2 hA = *(const uint2*)(h1 + (size_t)sA * 128 + 4 * q);
    const uint2 hB = *(const uint2*)(h1 + (size_t)sB * 128 + 4 * q);
    const float wA = __expf(leaky(xA));
    const float wB = vB ? __expf(leaky(xB)) : 0.f;
    dsum += wA + wB;
    a0 = fmaf(wA, __uint_as_float(hA.x << 16), a0);
    a1 = fmaf(wA, __uint_as_float(hA.x & 0xFFFF0000u), a1);
    a2 = fmaf(wA, __uint_as_float(hA.y << 16), a2);
    a3 = fmaf(wA, __uint_as_float(hA.y & 0xFFFF0000u), a3);
    a0 = fmaf(wB, __uint_as_float(hB.x << 16), a0);
    a1 = fmaf(wB, __uint_as_float(hB.x & 0xFFFF0000u), a1);
    a2 = fmaf(wB, __uint_as_float(hB.y << 16), a2);
    a3 = fmaf(wB, __uint_as_float(hB.y & 0xFFFF0000u), a3);
  }
  a0 += __shfl_xor(a0, 32, 64);
  a1 += __shfl_xor(a1, 32, 64);
  a2 += __shfl_xor(a2, 32, 64);
  a3 += __shfl_xor(a3, 32, 64);
  dsum += __shfl_xor(dsum, 32, 64);
  if (half == 0) {
    const float inv = 1.f / (dsum + 1e-16f);
    const float4 bv = *(const float4*)(b1 + 4 * q);
    float g0 = fmaf(a0, inv, bv.x);
    float g1 = fmaf(a1, inv, bv.y);
    float g2v = fmaf(a2, inv, bv.z);
    float g3 = fmaf(a3, inv, bv.w);
    g0 = g0 > 0.f ? g0 : expm1f(g0);
    g1 = g1 > 0.f ? g1 : expm1f(g1);
    g2v = g2v > 0.f ? g2v : expm1f(g2v);
    g3 = g3 > 0.f ? g3 : expm1f(g3);
    *(float4*)(g + (size_t)n * 128 + 4 * q) = make_float4(g0, g1, g2v, g3);
  }
}

// ---------------- GAT layer 2 linear: h2[N,64] = g[N,128] @ W2[128,64] (bf16 out)
__global__ void k_h2(const float* __restrict__ g, const float* __restrict__ W2,
                     const float* __restrict__ att_s, const float* __restrict__ att_d,
                     unsigned short* __restrict__ h2, float* __restrict__ a_s,
                     float* __restrict__ a_d, int N) {
  __shared__ __align__(16) float W2s[128 * 64];
  __shared__ __align__(16) float gs[2][128];
  __shared__ float part[2][64];
  for (int i = threadIdx.x; i < 128 * 64; i += 256) W2s[i] = W2[i];
  const int col = threadIdx.x & 63;
  const int kh  = (threadIdx.x >> 6) & 1;
  const int ln  = threadIdx.x >> 7;
  const float as_w = att_s[col], ad_w = att_d[col];
  __syncthreads();
  float wreg[64];
#pragma unroll
  for (int cc = 0; cc < 64; ++cc) wreg[cc] = W2s[(kh * 64 + cc) * 64 + col];

  const int node0 = blockIdx.x * 32;
  for (int it = 0; it < 16; ++it) {
    const int nbase = node0 + it * 2;
    __syncthreads();
    {
      const int nn = nbase + (threadIdx.x >> 7);
      if (nn < N) gs[threadIdx.x >> 7][threadIdx.x & 127] = g[(size_t)nn * 128 + (threadIdx.x & 127)];
    }
    __syncthreads();
    const int n = nbase + ln;
    float acc = 0.f;
    if (n < N) {
#pragma unroll
      for (int q = 0; q < 16; ++q) {
        const float4 gv = *(const float4*)&gs[ln][kh * 64 + q * 4];
        acc = fmaf(gv.x, wreg[q * 4 + 0], acc);
        acc = fmaf(gv.y, wreg[q * 4 + 1], acc);
        acc = fmaf(gv.z, wreg[q * 4 + 2], acc);
        acc = fmaf(gv.w, wreg[q * 4 + 3], acc);
      }
    }
    if (kh == 1) part[ln][col] = acc;
    __syncthreads();
    if (kh == 0 && n < N) {
      acc += part[ln][col];
      h2[(size_t)n * 64 + col] = f2bf(acc);
      float vs = acc * as_w, vd = acc * ad_w;
#pragma unroll
      for (int off = 32; off > 0; off >>= 1) {
        vs += __shfl_down(vs, off, 64);
        vd += __shfl_down(vd, off, 64);
      }
      if (col == 0) { a_s[n] = vs; a_d[n] = vd; }
    }
  }
}

// ---------------- GAT layer 2 aggregate ----------------
__global__ void k_gat2(const unsigned short* __restrict__ h2, const float* __restrict__ as2,
                       const float* __restrict__ ad2, const int* __restrict__ rowptr,
                       const int* __restrict__ adj, const float* __restrict__ b2,
                       float* __restrict__ g2, int N) {
  const int w = threadIdx.x >> 6;
  const int l = threadIdx.x & 63;
  const int n = blockIdx.x * 4 + w;
  if (n >= N) return;
  const int half = l >> 5;
  const int q = l & 31;       // channels 2q, 2q+1
  const float adh = ad2[n];
  float a0 = 0.f, a1 = 0.f, dsum = 0.f;
  const int kb = rowptr[n], ke = rowptr[n + 1];
  const int kend = ke - 1;
  for (int k = kb + half; k < ke; k += 4) {
    const int eB = k + 2;
    const bool vB = eB < ke;
    const int sA = adj[k];
    const int sB = adj[min(eB, kend)];
    const float xA = as2[sA] + adh;
    const float xB = as2[sB] + adh;
    const unsigned hA = *(const unsigned*)(h2 + (size_t)sA * 64 + 2 * q);
    const unsigned hB = *(const unsigned*)(h2 + (size_t)sB * 64 + 2 * q);
    const float wA = __expf(leaky(xA));
    const float wB = vB ? __expf(leaky(xB)) : 0.f;
    dsum += wA + wB;
    a0 = fmaf(wA, __uint_as_float(hA << 16), a0);
    a1 = fmaf(wA, __uint_as_float(hA & 0xFFFF0000u), a1);
    a0 = fmaf(wB, __uint_as_float(hB << 16), a0);
    a1 = fmaf(wB, __uint_as_float(hB & 0xFFFF0000u), a1);
  }
  a0 += __shfl_xor(a0, 32, 64);
  a1 += __shfl_xor(a1, 32, 64);
  dsum += __shfl_xor(dsum, 32, 64);
  if (half == 0) {
    const float inv = 1.f / (dsum + 1e-16f);
    const float2 bv = *(const float2*)(b2 + 2 * q);
    ((float2*)g2)[(size_t)n * 32 + q] =
        make_float2(fmaf(a0, inv, bv.x), fmaf(a1, inv, bv.y));
  }
}

// ---------------- build x matrix, bf16, K-blocked: xb[k/32][512][32] ----------------
__global__ void k_xmat(const int* __restrict__ user_idx, const int* __restrict__ ctx_idx,
                       const float* __restrict__ user_emb, const float* __restrict__ g2,
                       unsigned short* __restrict__ xb) {
  const int b = blockIdx.x;
  const int k = threadIdx.x;  // 0..255
  float v;
  if (k < 64) {
    v = user_emb[(size_t)user_idx[b] * 64 + k];
  } else {
    const int c = (k - 64) >> 6;
    v = g2[(size_t)ctx_idx[b * 3 + c] * 64 + (k & 63)];
  }
  xb[(size_t)(k >> 5) * (512 * 32) + b * 32 + (k & 31)] = f2bf(v);
}

// ---------------- final FC via MFMA, A-persistent, tile-strided, prefetched ------
// 512 threads = 8 waves; wave w owns x-rows [64w, 64w+64) (4 mf fragments).
// Tiles (16 cols each) are GRID-STRIDED so concurrent blocks write/read adjacent
// 64B segments of the same rows (DRAM page locality). Operands are SWAPPED in the
// MFMA (bfr as A, afr as B) so each lane holds 4 consecutive out-cols -> float4
// stores. Next tile's B is prefetched into registers during compute.
__global__ __launch_bounds__(512) void k_fc(const unsigned short* __restrict__ xb,
                                            const float* __restrict__ fc_w,
                                            const float* __restrict__ fc_b,
                                            float* __restrict__ out, int NSRV,
                                            int ntiles, int gstride) {
  __shared__ __align__(16) unsigned short Blds[16 * 264];  // [col][k], 8.25 KB

  const int tid = threadIdx.x;
  const int w = tid >> 6;
  const int lane = tid & 63;
  const int l15 = lane & 15;
  const int kg = lane >> 4;

  if (blockIdx.x >= (unsigned)ntiles) return;

  // persistent A fragments (serve as the MFMA *B* operand after the swap)
  short8 afr[4][8];
#pragma unroll
  for (int mf = 0; mf < 4; ++mf) {
    const int row = w * 64 + mf * 16 + l15;
#pragma unroll
    for (int ks = 0; ks < 8; ++ks) {
      afr[mf][ks] = *(const short8*)(xb + (size_t)ks * 16384 + row * 32 + kg * 8);
    }
  }

  const int sc = tid & 15;   // stage: col in tile
  const int sk = tid >> 4;   // stage: k row 0..31

  float v[8];
  {
    const int cg = blockIdx.x * 16 + sc;
    const bool okc = cg < NSRV;
#pragma unroll
    for (int i = 0; i < 8; ++i)
      v[i] = okc ? fc_w[(size_t)(sk + i * 32) * NSRV + cg] : 0.f;
  }

  for (int t = blockIdx.x; t < ntiles; t += gstride) {
    __syncthreads();  // previous tile's ds_reads complete
#pragma unroll
    for (int i = 0; i < 8; ++i)
      Blds[sc * 264 + sk + i * 32] = f2bf(v[i]);
    __syncthreads();
    // prefetch next tile's B while we compute this one
    const int tn = t + gstride;
    if (tn < ntiles) {
      const int cg = tn * 16 + sc;
      const bool okc = cg < NSRV;
#pragma unroll
      for (int i = 0; i < 8; ++i)
        v[i] = okc ? fc_w[(size_t)(sk + i * 32) * NSRV + cg] : 0.f;
    }
    short8 bfr[8];
#pragma unroll
    for (int ks = 0; ks < 8; ++ks)
      bfr[ks] = *(const short8*)&Blds[l15 * 264 + ks * 32 + kg * 8];
    f32x4 acc[4];
#pragma unroll
    for (int mf = 0; mf < 4; ++mf) acc[mf] = (f32x4){0.f, 0.f, 0.f, 0.f};
#pragma unroll
    for (int ks = 0; ks < 8; ++ks)
#pragma unroll
      for (int mf = 0; mf < 4; ++mf)
        acc[mf] = __builtin_amdgcn_mfma_f32_16x16x32_bf16(bfr[ks], afr[mf][ks], acc[mf], 0, 0, 0);
    // epilogue: lane holds cols j0+kg*4..+3 of row w*64+mf*16+l15 -> float4
    const int j0 = t * 16;
    const int jc = j0 + kg * 4;
    if (j0 + 16 <= NSRV) {
      const float4 bias = *(const float4*)(fc_b + jc);
#pragma unroll
      for (int mf = 0; mf < 4; ++mf) {
        const int row = w * 64 + mf * 16 + l15;
        float4 o;
        o.x = acc[mf][0] + bias.x;
        o.y = acc[mf][1] + bias.y;
        o.z = acc[mf][2] + bias.z;
        o.w = acc[mf][3] + bias.w;
        *(float4*)(out + (size_t)row * NSRV + jc) = o;
      }
    } else {
#pragma unroll
      for (int mf = 0; mf < 4; ++mf) {
        const int row = w * 64 + mf * 16 + l15;
#pragma unroll
        for (int r = 0; r < 4; ++r) {
          const int j = jc + r;
          if (j < NSRV) out[(size_t)row * NSRV + j] = acc[mf][r] + fc_b[j];
        }
      }
    }
  }
}

// =====================================================================
extern "C" void kernel_launch(void* const* d_in, const int* in_sizes, int n_in,
                              void* d_out, int out_size, void* d_ws, size_t ws_size,
                              hipStream_t stream) {
  const int* user_idx    = (const int*)d_in[0];
  const int* context_idx = (const int*)d_in[1];
  const int* edge_index  = (const int*)d_in[2];
  const float* user_emb  = (const float*)d_in[3];
  const float* service_emb = (const float*)d_in[4];
  const float* W1        = (const float*)d_in[5];
  const float* att_src1  = (const float*)d_in[6];
  const float* att_dst1  = (const float*)d_in[7];
  const float* b1        = (const float*)d_in[8];
  const float* W2        = (const float*)d_in[9];
  const float* att_src2  = (const float*)d_in[10];
  const float* att_dst2  = (const float*)d_in[11];
  const float* b2        = (const float*)d_in[12];
  const float* fc_w      = (const float*)d_in[13];
  const float* fc_b      = (const float*)d_in[14];
  float* out = (float*)d_out;

  const int B    = in_sizes[0];
  const int E    = in_sizes[2] / 2;
  const int N    = in_sizes[4] / 64;
  const int NSRV = in_sizes[14];
  const int Etot = E + N;
  (void)B;

  const int* edge_src = edge_index;
  const int* edge_dst = edge_index + E;

  // ---- workspace layout ----
  char* ws = (char*)d_ws;
  size_t off = 0;
  auto alloc = [&](size_t bytes) {
    void* p = ws + off;
    off = (off + bytes + 255) & ~(size_t)255;
    return p;
  };
  unsigned short* h1 = (unsigned short*)alloc((size_t)N * 128 * 2);  // reused as h2
  float* g      = (float*)alloc((size_t)N * 128 * 4);                // reused as g2
  float* as1    = (float*)alloc((size_t)N * 2 * 4);
  float* ad1    = (float*)alloc((size_t)N * 2 * 4);
  float* as2    = (float*)alloc((size_t)N * 4);
  float* ad2    = (float*)alloc((size_t)N * 4);
  int*   rowptr = (int*)alloc((size_t)(N + 1) * 4);
  int*   adj    = (int*)alloc((size_t)Etot * 4);
  unsigned* rec = (unsigned*)alloc((size_t)Etot * 4);
  int* bucketCnt    = (int*)alloc(256 * 4);
  int* bucketBase   = (int*)alloc(257 * 4);
  int* bucketCursor = (int*)alloc(256 * 4);
  unsigned short* xb = (unsigned short*)alloc((size_t)512 * 256 * 2);
  unsigned short* h2 = h1;
  float* g2 = g;
  (void)ws_size;

  const int NB = (N + NPB - 1) >> NPB_SH;
  const int NBLK2 = 256;
  const int epb = (Etot + NBLK2 - 1) / NBLK2;

  // GAT layer 1 linear
  k_h1<<<(N + 31) / 32, 256, 0, stream>>>(service_emb, W1, att_src1, att_dst1, h1, as1, ad1, N);

  // CSR build (binned)
  hipMemsetAsync(bucketCnt, 0, (size_t)NB * 4, stream);
  k_bcount<<<NBLK2, 1024, 0, stream>>>(edge_dst, E, Etot, epb, bucketCnt, NB);
  k_bscan<<<1, 256, 0, stream>>>(bucketCnt, bucketBase, bucketCursor, NB, Etot, rowptr, N);
  k_bscatter<<<NBLK2, 1024, 0, stream>>>(edge_src, edge_dst, E, Etot, epb, bucketCursor, rec, NB);
  k_bcsr<<<NB, 1024, 0, stream>>>(rec, bucketBase, rowptr, adj, N, NB);

  // layer 1 aggregate -> g (elu'd)
  k_gat1<<<(N + 3) / 4, 256, 0, stream>>>(h1, as1, ad1, rowptr, adj, b1, g, N);

  // layer 2 linear (h2 overlays h1)
  k_h2<<<(N + 31) / 32, 256, 0, stream>>>(g, W2, att_src2, att_dst2, h2, as2, ad2, N);

  // layer 2 aggregate -> g2 (overlays g)
  k_gat2<<<(N + 3) / 4, 256, 0, stream>>>(h2, as2, ad2, rowptr, adj, b2, g2, N);

  // gather features -> bf16 K-blocked
  k_xmat<<<512, 256, 0, stream>>>(user_idx, context_idx, user_emb, g2, xb);

  // final FC (MFMA, A-persistent, grid-strided tiles)
  const int nfct = (NSRV + 15) / 16;
  const int grid = 512;
  k_fc<<<grid, 512, 0, stream>>>(xb, fc_w, fc_b, out, NSRV, nfct, grid);
}

// Round 8
// 441.706 us; speedup vs baseline: 3.1575x; 1.0596x over previous
//
#include <hip/hip_runtime.h>
#include <hip/hip_bf16.h>
#include <math.h>

#define NEG_SLOPE 0.2f

// CSR binning parameters (N=100000, E+N~1.7M; requires N < 2^18 and NB <= 256)
#define NPB 512       // nodes per bucket
#define NPB_SH 9
#define SRC_BITS 18
#define LCAP 16384    // LDS adj staging capacity (edges) per bucket

typedef __attribute__((ext_vector_type(8))) short short8;
typedef __attribute__((ext_vector_type(4))) float f32x4;

__device__ __forceinline__ float leaky(float x) { return x > 0.f ? x : NEG_SLOPE * x; }

__device__ __forceinline__ unsigned short f2bf(float f) {
  unsigned u = __float_as_uint(f);
  unsigned r = (u + 0x7FFFu + ((u >> 16) & 1u)) >> 16;  // RNE
  return (unsigned short)r;
}

// ---------------- GAT layer 1 linear: h1[N,128] = x[N,64] @ W1[64,128] (bf16 out)
__global__ void k_h1(const float* __restrict__ x, const float* __restrict__ W1,
                     const float* __restrict__ att_src, const float* __restrict__ att_dst,
                     unsigned short* __restrict__ h1, float* __restrict__ a_s,
                     float* __restrict__ a_d, int N) {
  __shared__ __align__(16) float W1s[64 * 128];
  __shared__ __align__(16) float xs[2][64];
  for (int i = threadIdx.x; i < 64 * 128; i += 256) W1s[i] = W1[i];
  const int ln  = threadIdx.x >> 7;   // node slot 0/1
  const int col = threadIdx.x & 127;  // output channel
  const int head = col >> 6;
  const int c = col & 63;
  const float as_w = att_src[head * 64 + c];
  const float ad_w = att_dst[head * 64 + c];
  __syncthreads();
  float wreg[64];
#pragma unroll
  for (int cc = 0; cc < 64; ++cc) wreg[cc] = W1s[cc * 128 + col];

  const int node0 = blockIdx.x * 32;
  for (int it = 0; it < 16; ++it) {
    const int nbase = node0 + it * 2;
    __syncthreads();
    if (threadIdx.x < 128) {
      const int nn = nbase + (threadIdx.x >> 6);
      if (nn < N) xs[threadIdx.x >> 6][threadIdx.x & 63] = x[(size_t)nn * 64 + (threadIdx.x & 63)];
    }
    __syncthreads();
    const int n = nbase + ln;
    if (n >= N) continue;
    float acc = 0.f;
#pragma unroll
    for (int q = 0; q < 16; ++q) {
      const float4 xv = *(const float4*)&xs[ln][q * 4];
      acc = fmaf(xv.x, wreg[q * 4 + 0], acc);
      acc = fmaf(xv.y, wreg[q * 4 + 1], acc);
      acc = fmaf(xv.z, wreg[q * 4 + 2], acc);
      acc = fmaf(xv.w, wreg[q * 4 + 3], acc);
    }
    h1[(size_t)n * 128 + col] = f2bf(acc);
    float vs = acc * as_w;
    float vd = acc * ad_w;
#pragma unroll
    for (int off = 32; off > 0; off >>= 1) {
      vs += __shfl_down(vs, off, 64);
      vd += __shfl_down(vd, off, 64);
    }
    if (c == 0) { a_s[n * 2 + head] = vs; a_d[n * 2 + head] = vd; }
  }
}

// ---------------- CSR build via two-level binning ----------------
__global__ __launch_bounds__(1024) void k_bcount(const int* __restrict__ dst, int E, int Etot,
                                                 int epb, int* __restrict__ bucketCnt, int NB) {
  __shared__ int hist[256];
  const int tid = threadIdx.x;
  if (tid < 256) hist[tid] = 0;
  __syncthreads();
  const int e0 = blockIdx.x * epb;
  const int e1 = min(e0 + epb, Etot);
  for (int e = e0 + tid; e < e1; e += 1024) {
    const int d = (e < E) ? dst[e] : (e - E);
    atomicAdd(&hist[d >> NPB_SH], 1);
  }
  __syncthreads();
  if (tid < NB) {
    const int c = hist[tid];
    if (c) atomicAdd(&bucketCnt[tid], c);
  }
}

__global__ void k_bscan(const int* __restrict__ bucketCnt, int* __restrict__ bucketBase,
                        int* __restrict__ bucketCursor, int NB, int Etot,
                        int* __restrict__ rowptr, int N) {
  __shared__ int s[256];
  const int tid = threadIdx.x;
  const int v = (tid < NB) ? bucketCnt[tid] : 0;
  s[tid] = v;
  __syncthreads();
  for (int off = 1; off < 256; off <<= 1) {
    const int t = (tid >= off) ? s[tid - off] : 0;
    __syncthreads();
    s[tid] += t;
    __syncthreads();
  }
  if (tid < NB) {
    const int base = s[tid] - v;
    bucketBase[tid] = base;
    bucketCursor[tid] = base;
  }
  if (tid == 0) { bucketBase[NB] = Etot; rowptr[N] = Etot; }
}

__global__ __launch_bounds__(1024) void k_bscatter(const int* __restrict__ src,
                                                   const int* __restrict__ dst, int E, int Etot,
                                                   int epb, int* __restrict__ bucketCursor,
                                                   unsigned* __restrict__ rec, int NB) {
  __shared__ int hist[256];
  __shared__ int cur[256];
  const int tid = threadIdx.x;
  if (tid < 256) hist[tid] = 0;
  __syncthreads();
  const int e0 = blockIdx.x * epb;
  const int e1 = min(e0 + epb, Etot);
  for (int e = e0 + tid; e < e1; e += 1024) {
    const int d = (e < E) ? dst[e] : (e - E);
    atomicAdd(&hist[d >> NPB_SH], 1);
  }
  __syncthreads();
  if (tid < NB) {
    const int c = hist[tid];
    cur[tid] = c ? atomicAdd(&bucketCursor[tid], c) : 0;
  }
  __syncthreads();
  for (int e = e0 + tid; e < e1; e += 1024) {
    int sv, d;
    if (e < E) { sv = src[e]; d = dst[e]; } else { sv = d = e - E; }
    const int b = d >> NPB_SH;
    const int p = atomicAdd(&cur[b], 1);
    rec[p] = (unsigned)sv | ((unsigned)(d & (NPB - 1)) << SRC_BITS);
  }
}

__global__ __launch_bounds__(1024) void k_bcsr(const unsigned* __restrict__ rec,
                                               const int* __restrict__ bucketBase,
                                               int* __restrict__ rowptr, int* __restrict__ adj,
                                               int N, int NB) {
  __shared__ int ldeg[NPB];
  __shared__ int s[NPB];
  __shared__ int ladj[LCAP];
  const int b = blockIdx.x;
  const int tid = threadIdx.x;
  const int e0 = bucketBase[b];
  const int e1 = bucketBase[b + 1];
  const int cnt = e1 - e0;
  if (tid < NPB) ldeg[tid] = 0;
  __syncthreads();
  for (int i = tid; i < cnt; i += 1024)
    atomicAdd(&ldeg[rec[e0 + i] >> SRC_BITS], 1);
  __syncthreads();
  int v = 0;
  if (tid < NPB) { v = ldeg[tid]; s[tid] = v; }
  __syncthreads();
  for (int off = 1; off < NPB; off <<= 1) {
    int t = 0;
    if (tid < NPB && tid >= off) t = s[tid - off];
    __syncthreads();
    if (tid < NPB) s[tid] += t;
    __syncthreads();
  }
  if (tid < NPB) {
    const int excl = s[tid] - v;
    const int node = b * NPB + tid;
    if (node < N) rowptr[node] = e0 + excl;
    ldeg[tid] = excl;  // reuse as scatter cursor
  }
  __syncthreads();
  if (cnt <= LCAP) {
    for (int i = tid; i < cnt; i += 1024) {
      const unsigned r = rec[e0 + i];
      const int p = atomicAdd(&ldeg[r >> SRC_BITS], 1);
      ladj[p] = (int)(r & ((1u << SRC_BITS) - 1));
    }
    __syncthreads();
    for (int i = tid; i < cnt; i += 1024) adj[e0 + i] = ladj[i];
  } else {
    for (int i = tid; i < cnt; i += 1024) {
      const unsigned r = rec[e0 + i];
      const int p = atomicAdd(&ldeg[r >> SRC_BITS], 1);
      adj[e0 + p] = (int)(r & ((1u << SRC_BITS) - 1));
    }
  }
}

// ---------------- GAT layer 1 aggregate ----------------
__global__ void k_gat1(const unsigned short* __restrict__ h1, const float* __restrict__ as1,
                       const float* __restrict__ ad1, const int* __restrict__ rowptr,
                       const int* __restrict__ adj, const float* __restrict__ b1,
                       float* __restrict__ g, int N) {
  const int w = threadIdx.x >> 6;
  const int l = threadIdx.x & 63;
  const int n = blockIdx.x * 4 + w;
  if (n >= N) return;
  const int half = l >> 5;
  const int q = l & 31;       // channels 4q..4q+3
  const int head = q >> 4;
  const float adh = ad1[n * 2 + head];
  float a0 = 0.f, a1 = 0.f, a2 = 0.f, a3 = 0.f, dsum = 0.f;
  const int kb = rowptr[n], ke = rowptr[n + 1];
  const int kend = ke - 1;
  for (int k = kb + half; k < ke; k += 4) {
    const int eB = k + 2;
    const bool vB = eB < ke;
    const int sA = adj[k];
    const int sB = adj[min(eB, kend)];
    const float xA = as1[sA * 2 + head] + adh;
    const float xB = as1[sB * 2 + head] + adh;
    const uint2 hA = *(const uint2*)(h1 + (size_t)sA * 128 + 4 * q);
    const uint2 hB = *(const uint2*)(h1 + (size_t)sB * 128 + 4 * q);
    const float wA = __expf(leaky(xA));
    const float wB = vB ? __expf(leaky(xB)) : 0.f;
    dsum += wA + wB;
    a0 = fmaf(wA, __uint_as_float(hA.x << 16), a0);
    a1 = fmaf(wA, __uint_as_float(hA.x & 0xFFFF0000u), a1);
    a2 = fmaf(wA, __uint_as_float(hA.y << 16), a2);
    a3 = fmaf(wA, __uint_as_float(hA.y & 0xFFFF0000u), a3);
    a0 = fmaf(wB, __uint_as_float(hB.x << 16), a0);
    a1 = fmaf(wB, __uint_as_float(hB.x & 0xFFFF0000u), a1);
    a2 = fmaf(wB, __uint_as_float(hB.y << 16), a2);
    a3 = fmaf(wB, __uint_as_float(hB.y & 0xFFFF0000u), a3);
  }
  a0 += __shfl_xor(a0, 32, 64);
  a1 += __shfl_xor(a1, 32, 64);
  a2 += __shfl_xor(a2, 32, 64);
  a3 += __shfl_xor(a3, 32, 64);
  dsum += __shfl_xor(dsum, 32, 64);
  if (half == 0) {
    const float inv = 1.f / (dsum + 1e-16f);
    const float4 bv = *(const float4*)(b1 + 4 * q);
    float g0 = fmaf(a0, inv, bv.x);
    float g1 = fmaf(a1, inv, bv.y);
    float g2v = fmaf(a2, inv, bv.z);
    float g3 = fmaf(a3, inv, bv.w);
    g0 = g0 > 0.f ? g0 : expm1f(g0);
    g1 = g1 > 0.f ? g1 : expm1f(g1);
    g2v = g2v > 0.f ? g2v : expm1f(g2v);
    g3 = g3 > 0.f ? g3 : expm1f(g3);
    *(float4*)(g + (size_t)n * 128 + 4 * q) = make_float4(g0, g1, g2v, g3);
  }
}

// ---------------- GAT layer 2 linear: h2[N,64] = g[N,128] @ W2[128,64] (bf16 out)
__global__ void k_h2(const float* __restrict__ g, const float* __restrict__ W2,
                     const float* __restrict__ att_s, const float* __restrict__ att_d,
                     unsigned short* __restrict__ h2, float* __restrict__ a_s,
                     float* __restrict__ a_d, int N) {
  __shared__ __align__(16) float W2s[128 * 64];
  __shared__ __align__(16) float gs[2][128];
  __shared__ float part[2][64];
  for (int i = threadIdx.x; i < 128 * 64; i += 256) W2s[i] = W2[i];
  const int col = threadIdx.x & 63;
  const int kh  = (threadIdx.x >> 6) & 1;
  const int ln  = threadIdx.x >> 7;
  const float as_w = att_s[col], ad_w = att_d[col];
  __syncthreads();
  float wreg[64];
#pragma unroll
  for (int cc = 0; cc < 64; ++cc) wreg[cc] = W2s[(kh * 64 + cc) * 64 + col];

  const int node0 = blockIdx.x * 32;
  for (int it = 0; it < 16; ++it) {
    const int nbase = node0 + it * 2;
    __syncthreads();
    {
      const int nn = nbase + (threadIdx.x >> 7);
      if (nn < N) gs[threadIdx.x >> 7][threadIdx.x & 127] = g[(size_t)nn * 128 + (threadIdx.x & 127)];
    }
    __syncthreads();
    const int n = nbase + ln;
    float acc = 0.f;
    if (n < N) {
#pragma unroll
      for (int q = 0; q < 16; ++q) {
        const float4 gv = *(const float4*)&gs[ln][kh * 64 + q * 4];
        acc = fmaf(gv.x, wreg[q * 4 + 0], acc);
        acc = fmaf(gv.y, wreg[q * 4 + 1], acc);
        acc = fmaf(gv.z, wreg[q * 4 + 2], acc);
        acc = fmaf(gv.w, wreg[q * 4 + 3], acc);
      }
    }
    if (kh == 1) part[ln][col] = acc;
    __syncthreads();
    if (kh == 0 && n < N) {
      acc += part[ln][col];
      h2[(size_t)n * 64 + col] = f2bf(acc);
      float vs = acc * as_w, vd = acc * ad_w;
#pragma unroll
      for (int off = 32; off > 0; off >>= 1) {
        vs += __shfl_down(vs, off, 64);
        vd += __shfl_down(vd, off, 64);
      }
      if (col == 0) { a_s[n] = vs; a_d[n] = vd; }
    }
  }
}

// ---------------- GAT layer 2 aggregate ----------------
__global__ void k_gat2(const unsigned short* __restrict__ h2, const float* __restrict__ as2,
                       const float* __restrict__ ad2, const int* __restrict__ rowptr,
                       const int* __restrict__ adj, const float* __restrict__ b2,
                       float* __restrict__ g2, int N) {
  const int w = threadIdx.x >> 6;
  const int l = threadIdx.x & 63;
  const int n = blockIdx.x * 4 + w;
  if (n >= N) return;
  const int half = l >> 5;
  const int q = l & 31;       // channels 2q, 2q+1
  const float adh = ad2[n];
  float a0 = 0.f, a1 = 0.f, dsum = 0.f;
  const int kb = rowptr[n], ke = rowptr[n + 1];
  const int kend = ke - 1;
  for (int k = kb + half; k < ke; k += 4) {
    const int eB = k + 2;
    const bool vB = eB < ke;
    const int sA = adj[k];
    const int sB = adj[min(eB, kend)];
    const float xA = as2[sA] + adh;
    const float xB = as2[sB] + adh;
    const unsigned hA = *(const unsigned*)(h2 + (size_t)sA * 64 + 2 * q);
    const unsigned hB = *(const unsigned*)(h2 + (size_t)sB * 64 + 2 * q);
    const float wA = __expf(leaky(xA));
    const float wB = vB ? __expf(leaky(xB)) : 0.f;
    dsum += wA + wB;
    a0 = fmaf(wA, __uint_as_float(hA << 16), a0);
    a1 = fmaf(wA, __uint_as_float(hA & 0xFFFF0000u), a1);
    a0 = fmaf(wB, __uint_as_float(hB << 16), a0);
    a1 = fmaf(wB, __uint_as_float(hB & 0xFFFF0000u), a1);
  }
  a0 += __shfl_xor(a0, 32, 64);
  a1 += __shfl_xor(a1, 32, 64);
  dsum += __shfl_xor(dsum, 32, 64);
  if (half == 0) {
    const float inv = 1.f / (dsum + 1e-16f);
    const float2 bv = *(const float2*)(b2 + 2 * q);
    ((float2*)g2)[(size_t)n * 32 + q] =
        make_float2(fmaf(a0, inv, bv.x), fmaf(a1, inv, bv.y));
  }
}

// ---------------- build x matrix, bf16, K-blocked: xb[k/32][512][32] ----------------
__global__ void k_xmat(const int* __restrict__ user_idx, const int* __restrict__ ctx_idx,
                       const float* __restrict__ user_emb, const float* __restrict__ g2,
                       unsigned short* __restrict__ xb) {
  const int b = blockIdx.x;
  const int k = threadIdx.x;  // 0..255
  float v;
  if (k < 64) {
    v = user_emb[(size_t)user_idx[b] * 64 + k];
  } else {
    const int c = (k - 64) >> 6;
    v = g2[(size_t)ctx_idx[b * 3 + c] * 64 + (k & 63)];
  }
  xb[(size_t)(k >> 5) * (512 * 32) + b * 32 + (k & 31)] = f2bf(v);
}

// ---------------- final FC via MFMA, A-persistent, 32-col tiles, prefetched ------
// 512 threads = 8 waves; wave w owns x-rows [64w, 64w+64). Tiles of 32 cols,
// grid-strided. Swapped MFMA (B-tile as A operand) -> lane holds 4 consecutive
// out cols -> float4 stores. Next tile's B prefetched to regs during compute.
__global__ __launch_bounds__(512) void k_fc(const unsigned short* __restrict__ xb,
                                            const float* __restrict__ fc_w,
                                            const float* __restrict__ fc_b,
                                            float* __restrict__ out, int NSRV,
                                            int ntiles, int gstride) {
  __shared__ __align__(16) unsigned short Blds[32 * 264];  // [col][k], 16.5 KB

  const int tid = threadIdx.x;
  const int w = tid >> 6;
  const int lane = tid & 63;
  const int l15 = lane & 15;
  const int kg = lane >> 4;

  if (blockIdx.x >= (unsigned)ntiles) return;

  // persistent A fragments (serve as the MFMA *B* operand after the swap)
  short8 afr[4][8];
#pragma unroll
  for (int mf = 0; mf < 4; ++mf) {
    const int row = w * 64 + mf * 16 + l15;
#pragma unroll
    for (int ks = 0; ks < 8; ++ks) {
      afr[mf][ks] = *(const short8*)(xb + (size_t)ks * 16384 + row * 32 + kg * 8);
    }
  }

  const int sc = tid & 31;   // stage: col in tile
  const int sk = tid >> 5;   // stage: k row 0..15 (covers 256 with 16 iters)

  float v[16];
  {
    const int cg = blockIdx.x * 32 + sc;
    const bool okc = cg < NSRV;
#pragma unroll
    for (int i = 0; i < 16; ++i)
      v[i] = okc ? fc_w[(size_t)(sk + i * 16) * NSRV + cg] : 0.f;
  }

  for (int t = blockIdx.x; t < ntiles; t += gstride) {
    __syncthreads();  // previous tile's ds_reads complete
#pragma unroll
    for (int i = 0; i < 16; ++i)
      Blds[sc * 264 + sk + i * 16] = f2bf(v[i]);
    __syncthreads();
    // prefetch next tile's B while we compute this one
    const int tn = t + gstride;
    if (tn < ntiles) {
      const int cg = tn * 32 + sc;
      const bool okc = cg < NSRV;
#pragma unroll
      for (int i = 0; i < 16; ++i)
        v[i] = okc ? fc_w[(size_t)(sk + i * 16) * NSRV + cg] : 0.f;
    }
    const int j0 = t * 32;
#pragma unroll
    for (int nf = 0; nf < 2; ++nf) {
      short8 bfr[8];
#pragma unroll
      for (int ks = 0; ks < 8; ++ks)
        bfr[ks] = *(const short8*)&Blds[(nf * 16 + l15) * 264 + ks * 32 + kg * 8];
      f32x4 acc[4];
#pragma unroll
      for (int mf = 0; mf < 4; ++mf) acc[mf] = (f32x4){0.f, 0.f, 0.f, 0.f};
#pragma unroll
      for (int ks = 0; ks < 8; ++ks)
#pragma unroll
        for (int mf = 0; mf < 4; ++mf)
          acc[mf] = __builtin_amdgcn_mfma_f32_16x16x32_bf16(bfr[ks], afr[mf][ks], acc[mf], 0, 0, 0);
      // epilogue: lane holds cols jc..jc+3 of row w*64+mf*16+l15 -> float4
      const int jc = j0 + nf * 16 + kg * 4;
      if (j0 + 32 <= NSRV) {
        const float4 bias = *(const float4*)(fc_b + jc);
#pragma unroll
        for (int mf = 0; mf < 4; ++mf) {
          const int row = w * 64 + mf * 16 + l15;
          float4 o;
          o.x = acc[mf][0] + bias.x;
          o.y = acc[mf][1] + bias.y;
          o.z = acc[mf][2] + bias.z;
          o.w = acc[mf][3] + bias.w;
          *(float4*)(out + (size_t)row * NSRV + jc) = o;
        }
      } else {
#pragma unroll
        for (int mf = 0; mf < 4; ++mf) {
          const int row = w * 64 + mf * 16 + l15;
#pragma unroll
          for (int r = 0; r < 4; ++r) {
            const int j = jc + r;
            if (j < NSRV) out[(size_t)row * NSRV + j] = acc[mf][r] + fc_b[j];
          }
        }
      }
    }
  }
}

// =====================================================================
extern "C" void kernel_launch(void* const* d_in, const int* in_sizes, int n_in,
                              void* d_out, int out_size, void* d_ws, size_t ws_size,
                              hipStream_t stream) {
  const int* user_idx    = (const int*)d_in[0];
  const int* context_idx = (const int*)d_in[1];
  const int* edge_index  = (const int*)d_in[2];
  const float* user_emb  = (const float*)d_in[3];
  const float* service_emb = (const float*)d_in[4];
  const float* W1        = (const float*)d_in[5];
  const float* att_src1  = (const float*)d_in[6];
  const float* att_dst1  = (const float*)d_in[7];
  const float* b1        = (const float*)d_in[8];
  const float* W2        = (const float*)d_in[9];
  const float* att_src2  = (const float*)d_in[10];
  const float* att_dst2  = (const float*)d_in[11];
  const float* b2        = (const float*)d_in[12];
  const float* fc_w      = (const float*)d_in[13];
  const float* fc_b      = (const float*)d_in[14];
  float* out = (float*)d_out;

  const int B    = in_sizes[0];
  const int E    = in_sizes[2] / 2;
  const int N    = in_sizes[4] / 64;
  const int NSRV = in_sizes[14];
  const int Etot = E + N;
  (void)B;

  const int* edge_src = edge_index;
  const int* edge_dst = edge_index + E;

  // ---- workspace layout ----
  char* ws = (char*)d_ws;
  size_t off = 0;
  auto alloc = [&](size_t bytes) {
    void* p = ws + off;
    off = (off + bytes + 255) & ~(size_t)255;
    return p;
  };
  unsigned short* h1 = (unsigned short*)alloc((size_t)N * 128 * 2);  // reused as h2
  float* g      = (float*)alloc((size_t)N * 128 * 4);                // reused as g2
  float* as1    = (float*)alloc((size_t)N * 2 * 4);
  float* ad1    = (float*)alloc((size_t)N * 2 * 4);
  float* as2    = (float*)alloc((size_t)N * 4);
  float* ad2    = (float*)alloc((size_t)N * 4);
  int*   rowptr = (int*)alloc((size_t)(N + 1) * 4);
  int*   adj    = (int*)alloc((size_t)Etot * 4);
  unsigned* rec = (unsigned*)alloc((size_t)Etot * 4);
  int* bucketCnt    = (int*)alloc(256 * 4);
  int* bucketBase   = (int*)alloc(257 * 4);
  int* bucketCursor = (int*)alloc(256 * 4);
  unsigned short* xb = (unsigned short*)alloc((size_t)512 * 256 * 2);
  unsigned short* h2 = h1;
  float* g2 = g;
  (void)ws_size;

  const int NB = (N + NPB - 1) >> NPB_SH;
  const int NBLK2 = 256;
  const int epb = (Etot + NBLK2 - 1) / NBLK2;

  // GAT layer 1 linear
  k_h1<<<(N + 31) / 32, 256, 0, stream>>>(service_emb, W1, att_src1, att_dst1, h1, as1, ad1, N);

  // CSR build (binned)
  hipMemsetAsync(bucketCnt, 0, (size_t)NB * 4, stream);
  k_bcount<<<NBLK2, 1024, 0, stream>>>(edge_dst, E, Etot, epb, bucketCnt, NB);
  k_bscan<<<1, 256, 0, stream>>>(bucketCnt, bucketBase, bucketCursor, NB, Etot, rowptr, N);
  k_bscatter<<<NBLK2, 1024, 0, stream>>>(edge_src, edge_dst, E, Etot, epb, bucketCursor, rec, NB);
  k_bcsr<<<NB, 1024, 0, stream>>>(rec, bucketBase, rowptr, adj, N, NB);

  // layer 1 aggregate -> g (elu'd)
  k_gat1<<<(N + 3) / 4, 256, 0, stream>>>(h1, as1, ad1, rowptr, adj, b1, g, N);

  // layer 2 linear (h2 overlays h1)
  k_h2<<<(N + 31) / 32, 256, 0, stream>>>(g, W2, att_src2, att_dst2, h2, as2, ad2, N);

  // layer 2 aggregate -> g2 (overlays g)
  k_gat2<<<(N + 3) / 4, 256, 0, stream>>>(h2, as2, ad2, rowptr, adj, b2, g2, N);

  // gather features -> bf16 K-blocked
  k_xmat<<<512, 256, 0, stream>>>(user_idx, context_idx, user_emb, g2, xb);

  // final FC (MFMA, A-persistent, 32-col grid-strided tiles)
  const int nfct = (NSRV + 31) / 32;
  const int grid = 512;
  k_fc<<<grid, 512, 0, stream>>>(xb, fc_w, fc_b, out, NSRV, nfct, grid);
}

// Round 9
// 413.563 us; speedup vs baseline: 3.3723x; 1.0680x over previous
//
#include <hip/hip_runtime.h>
#include <hip/hip_bf16.h>
#include <math.h>

#define NEG_SLOPE 0.2f

// CSR binning parameters (N=100000, E+N~1.7M; requires N < 2^18 and NB <= 256)
#define NPB 512       // nodes per bucket
#define NPB_SH 9
#define SRC_BITS 18
#define LCAP 16384    // LDS adj staging capacity (edges) per bucket
#define BCAP 16384    // fixed per-bucket record capacity (mean ~8.7K, >70 sigma margin)

typedef __attribute__((ext_vector_type(8))) short short8;
typedef __attribute__((ext_vector_type(4))) float f32x4;

__device__ __forceinline__ float leaky(float x) { return x > 0.f ? x : NEG_SLOPE * x; }

__device__ __forceinline__ unsigned short f2bf(float f) {
  unsigned u = __float_as_uint(f);
  unsigned r = (u + 0x7FFFu + ((u >> 16) & 1u)) >> 16;  // RNE
  return (unsigned short)r;
}

// ---------------- GAT layer 1 linear: h1[N,128] = x[N,64] @ W1[64,128] (bf16 out)
__global__ void k_h1(const float* __restrict__ x, const float* __restrict__ W1,
                     const float* __restrict__ att_src, const float* __restrict__ att_dst,
                     unsigned short* __restrict__ h1, float* __restrict__ a_s,
                     float* __restrict__ a_d, int N) {
  __shared__ __align__(16) float W1s[64 * 128];
  __shared__ __align__(16) float xs[2][64];
  for (int i = threadIdx.x; i < 64 * 128; i += 256) W1s[i] = W1[i];
  const int ln  = threadIdx.x >> 7;   // node slot 0/1
  const int col = threadIdx.x & 127;  // output channel
  const int head = col >> 6;
  const int c = col & 63;
  const float as_w = att_src[head * 64 + c];
  const float ad_w = att_dst[head * 64 + c];
  __syncthreads();
  float wreg[64];
#pragma unroll
  for (int cc = 0; cc < 64; ++cc) wreg[cc] = W1s[cc * 128 + col];

  const int node0 = blockIdx.x * 32;
  for (int it = 0; it < 16; ++it) {
    const int nbase = node0 + it * 2;
    __syncthreads();
    if (threadIdx.x < 128) {
      const int nn = nbase + (threadIdx.x >> 6);
      if (nn < N) xs[threadIdx.x >> 6][threadIdx.x & 63] = x[(size_t)nn * 64 + (threadIdx.x & 63)];
    }
    __syncthreads();
    const int n = nbase + ln;
    if (n >= N) continue;
    float acc = 0.f;
#pragma unroll
    for (int q = 0; q < 16; ++q) {
      const float4 xv = *(const float4*)&xs[ln][q * 4];
      acc = fmaf(xv.x, wreg[q * 4 + 0], acc);
      acc = fmaf(xv.y, wreg[q * 4 + 1], acc);
      acc = fmaf(xv.z, wreg[q * 4 + 2], acc);
      acc = fmaf(xv.w, wreg[q * 4 + 3], acc);
    }
    h1[(size_t)n * 128 + col] = f2bf(acc);
    float vs = acc * as_w;
    float vd = acc * ad_w;
#pragma unroll
    for (int off = 32; off > 0; off >>= 1) {
      vs += __shfl_down(vs, off, 64);
      vd += __shfl_down(vd, off, 64);
    }
    if (c == 0) { a_s[n * 2 + head] = vs; a_d[n * 2 + head] = vd; }
  }
}

// ---------------- CSR build via two-level binning (fixed-capacity buckets) ----------------
// init cursors to bucket region starts (replaces hipMemsetAsync + count pass)
__global__ void k_binit(int* __restrict__ cursor, int NB) {
  const int i = blockIdx.x * 256 + threadIdx.x;
  if (i < NB) cursor[i] = i * BCAP;
}

// chunk-reserved scatter of packed records (src | localdst<<SRC_BITS) into fixed regions
__global__ __launch_bounds__(1024) void k_bscatter(const int* __restrict__ src,
                                                   const int* __restrict__ dst, int E, int Etot,
                                                   int epb, int* __restrict__ cursor,
                                                   unsigned* __restrict__ rec, int NB) {
  __shared__ int hist[256];
  __shared__ int cur[256];
  const int tid = threadIdx.x;
  if (tid < 256) hist[tid] = 0;
  __syncthreads();
  const int e0 = blockIdx.x * epb;
  const int e1 = min(e0 + epb, Etot);
  for (int e = e0 + tid; e < e1; e += 1024) {
    const int d = (e < E) ? dst[e] : (e - E);
    atomicAdd(&hist[d >> NPB_SH], 1);
  }
  __syncthreads();
  if (tid < NB) {
    const int c = hist[tid];
    cur[tid] = c ? atomicAdd(&cursor[tid], c) : 0;
  }
  __syncthreads();
  for (int e = e0 + tid; e < e1; e += 1024) {
    int sv, d;
    if (e < E) { sv = src[e]; d = dst[e]; } else { sv = d = e - E; }
    const int b = d >> NPB_SH;
    const int p = atomicAdd(&cur[b], 1);
    rec[p] = (unsigned)sv | ((unsigned)(d & (NPB - 1)) << SRC_BITS);
  }
}

// scan bucket counts (derived from cursor deltas) -> bucketBase; rowptr[N] = Etot
__global__ void k_bscan2(const int* __restrict__ cursor, int* __restrict__ bucketBase,
                         int NB, int Etot, int* __restrict__ rowptr, int N) {
  __shared__ int s[256];
  const int tid = threadIdx.x;
  const int v = (tid < NB) ? (cursor[tid] - tid * BCAP) : 0;
  s[tid] = v;
  __syncthreads();
  for (int off = 1; off < 256; off <<= 1) {
    const int t = (tid >= off) ? s[tid - off] : 0;
    __syncthreads();
    s[tid] += t;
    __syncthreads();
  }
  if (tid < NB) bucketBase[tid] = s[tid] - v;
  if (tid == 0) { bucketBase[NB] = Etot; rowptr[N] = Etot; }
}

// one block per bucket -> local degree count, scan, LDS scatter, coalesced copy out
__global__ __launch_bounds__(1024) void k_bcsr(const unsigned* __restrict__ rec,
                                               const int* __restrict__ bucketBase,
                                               int* __restrict__ rowptr, int* __restrict__ adj,
                                               int N, int NB) {
  __shared__ int ldeg[NPB];
  __shared__ int s[NPB];
  __shared__ int ladj[LCAP];
  const int b = blockIdx.x;
  const int tid = threadIdx.x;
  const int o0 = bucketBase[b];
  const int cnt = bucketBase[b + 1] - o0;
  const int r0 = b * BCAP;
  if (tid < NPB) ldeg[tid] = 0;
  __syncthreads();
  for (int i = tid; i < cnt; i += 1024)
    atomicAdd(&ldeg[rec[r0 + i] >> SRC_BITS], 1);
  __syncthreads();
  int v = 0;
  if (tid < NPB) { v = ldeg[tid]; s[tid] = v; }
  __syncthreads();
  for (int off = 1; off < NPB; off <<= 1) {
    int t = 0;
    if (tid < NPB && tid >= off) t = s[tid - off];
    __syncthreads();
    if (tid < NPB) s[tid] += t;
    __syncthreads();
  }
  if (tid < NPB) {
    const int excl = s[tid] - v;
    const int node = b * NPB + tid;
    if (node < N) rowptr[node] = o0 + excl;
    ldeg[tid] = excl;  // reuse as scatter cursor
  }
  __syncthreads();
  if (cnt <= LCAP) {
    for (int i = tid; i < cnt; i += 1024) {
      const unsigned r = rec[r0 + i];
      const int p = atomicAdd(&ldeg[r >> SRC_BITS], 1);
      ladj[p] = (int)(r & ((1u << SRC_BITS) - 1));
    }
    __syncthreads();
    for (int i = tid; i < cnt; i += 1024) adj[o0 + i] = ladj[i];
  } else {  // safety fallback (never expected)
    for (int i = tid; i < cnt; i += 1024) {
      const unsigned r = rec[r0 + i];
      const int p = atomicAdd(&ldeg[r >> SRC_BITS], 1);
      adj[o0 + p] = (int)(r & ((1u << SRC_BITS) - 1));
    }
  }
}

// ---------------- GAT layer 1 aggregate (x4 unroll: 8 gathers in flight/lane) -------
__global__ void k_gat1(const unsigned short* __restrict__ h1, const float* __restrict__ as1,
                       const float* __restrict__ ad1, const int* __restrict__ rowptr,
                       const int* __restrict__ adj, const float* __restrict__ b1,
                       float* __restrict__ g, int N) {
  const int w = threadIdx.x >> 6;
  const int l = threadIdx.x & 63;
  const int n = blockIdx.x * 4 + w;
  if (n >= N) return;
  const int half = l >> 5;
  const int q = l & 31;       // channels 4q..4q+3
  const int head = q >> 4;
  const float adh = ad1[n * 2 + head];
  float a0 = 0.f, a1 = 0.f, a2 = 0.f, a3 = 0.f, dsum = 0.f;
  const int kb = rowptr[n], ke = rowptr[n + 1];
  const int kend = ke - 1;
  for (int k = kb + half; k < ke; k += 8) {
    const int e1 = k + 2, e2 = k + 4, e3 = k + 6;
    const int s0 = adj[k];
    const int s1 = adj[min(e1, kend)];
    const int s2 = adj[min(e2, kend)];
    const int s3 = adj[min(e3, kend)];
    const float x0 = as1[s0 * 2 + head] + adh;
    const float x1 = as1[s1 * 2 + head] + adh;
    const float x2 = as1[s2 * 2 + head] + adh;
    const float x3 = as1[s3 * 2 + head] + adh;
    const uint2 u0 = *(const uint2*)(h1 + (size_t)s0 * 128 + 4 * q);
    const uint2 u1 = *(const uint2*)(h1 + (size_t)s1 * 128 + 4 * q);
    const uint2 u2 = *(const uint2*)(h1 + (size_t)s2 * 128 + 4 * q);
    const uint2 u3 = *(const uint2*)(h1 + (size_t)s3 * 128 + 4 * q);
    const float w0 = __expf(leaky(x0));
    const float w1 = (e1 < ke) ? __expf(leaky(x1)) : 0.f;
    const float w2 = (e2 < ke) ? __expf(leaky(x2)) : 0.f;
    const float w3 = (e3 < ke) ? __expf(leaky(x3)) : 0.f;
    dsum += (w0 + w1) + (w2 + w3);
    a0 = fmaf(w0, __uint_as_float(u0.x << 16), a0);
    a1 = fmaf(w0, __uint_as_float(u0.x & 0xFFFF0000u), a1);
    a2 = fmaf(w0, __uint_as_float(u0.y << 16), a2);
    a3 = fmaf(w0, __uint_as_float(u0.y & 0xFFFF0000u), a3);
    a0 = fmaf(w1, __uint_as_float(u1.x << 16), a0);
    a1 = fmaf(w1, __uint_as_float(u1.x & 0xFFFF0000u), a1);
    a2 = fmaf(w1, __uint_as_float(u1.y << 16), a2);
    a3 = fmaf(w1, __uint_as_float(u1.y & 0xFFFF0000u), a3);
    a0 = fmaf(w2, __uint_as_float(u2.x << 16), a0);
    a1 = fmaf(w2, __uint_as_float(u2.x & 0xFFFF0000u), a1);
    a2 = fmaf(w2, __uint_as_float(u2.y << 16), a2);
    a3 = fmaf(w2, __uint_as_float(u2.y & 0xFFFF0000u), a3);
    a0 = fmaf(w3, __uint_as_float(u3.x << 16), a0);
    a1 = fmaf(w3, __uint_as_float(u3.x & 0xFFFF0000u), a1);
    a2 = fmaf(w3, __uint_as_float(u3.y << 16), a2);
    a3 = fmaf(w3, __uint_as_float(u3.y & 0xFFFF0000u), a3);
  }
  a0 += __shfl_xor(a0, 32, 64);
  a1 += __shfl_xor(a1, 32, 64);
  a2 += __shfl_xor(a2, 32, 64);
  a3 += __shfl_xor(a3, 32, 64);
  dsum += __shfl_xor(dsum, 32, 64);
  if (half == 0) {
    const float inv = 1.f / (dsum + 1e-16f);
    const float4 bv = *(const float4*)(b1 + 4 * q);
    float g0 = fmaf(a0, inv, bv.x);
    float g1 = fmaf(a1, inv, bv.y);
    float g2v = fmaf(a2, inv, bv.z);
    float g3 = fmaf(a3, inv, bv.w);
    g0 = g0 > 0.f ? g0 : expm1f(g0);
    g1 = g1 > 0.f ? g1 : expm1f(g1);
    g2v = g2v > 0.f ? g2v : expm1f(g2v);
    g3 = g3 > 0.f ? g3 : expm1f(g3);
    *(float4*)(g + (size_t)n * 128 + 4 * q) = make_float4(g0, g1, g2v, g3);
  }
}

// ---------------- GAT layer 2 linear: h2[N,64] = g[N,128] @ W2[128,64] (bf16 out)
__global__ void k_h2(const float* __restrict__ g, const float* __restrict__ W2,
                     const float* __restrict__ att_s, const float* __restrict__ att_d,
                     unsigned short* __restrict__ h2, float* __restrict__ a_s,
                     float* __restrict__ a_d, int N) {
  __shared__ __align__(16) float W2s[128 * 64];
  __shared__ __align__(16) float gs[2][128];
  __shared__ float part[2][64];
  for (int i = threadIdx.x; i < 128 * 64; i += 256) W2s[i] = W2[i];
  const int col = threadIdx.x & 63;
  const int kh  = (threadIdx.x >> 6) & 1;
  const int ln  = threadIdx.x >> 7;
  const float as_w = att_s[col], ad_w = att_d[col];
  __syncthreads();
  float wreg[64];
#pragma unroll
  for (int cc = 0; cc < 64; ++cc) wreg[cc] = W2s[(kh * 64 + cc) * 64 + col];

  const int node0 = blockIdx.x * 32;
  for (int it = 0; it < 16; ++it) {
    const int nbase = node0 + it * 2;
    __syncthreads();
    {
      const int nn = nbase + (threadIdx.x >> 7);
      if (nn < N) gs[threadIdx.x >> 7][threadIdx.x & 127] = g[(size_t)nn * 128 + (threadIdx.x & 127)];
    }
    __syncthreads();
    const int n = nbase + ln;
    float acc = 0.f;
    if (n < N) {
#pragma unroll
      for (int q = 0; q < 16; ++q) {
        const float4 gv = *(const float4*)&gs[ln][kh * 64 + q * 4];
        acc = fmaf(gv.x, wreg[q * 4 + 0], acc);
        acc = fmaf(gv.y, wreg[q * 4 + 1], acc);
        acc = fmaf(gv.z, wreg[q * 4 + 2], acc);
        acc = fmaf(gv.w, wreg[q * 4 + 3], acc);
      }
    }
    if (kh == 1) part[ln][col] = acc;
    __syncthreads();
    if (kh == 0 && n < N) {
      acc += part[ln][col];
      h2[(size_t)n * 64 + col] = f2bf(acc);
      float vs = acc * as_w, vd = acc * ad_w;
#pragma unroll
      for (int off = 32; off > 0; off >>= 1) {
        vs += __shfl_down(vs, off, 64);
        vd += __shfl_down(vd, off, 64);
      }
      if (col == 0) { a_s[n] = vs; a_d[n] = vd; }
    }
  }
}

// ---------------- GAT layer 2 aggregate (x4 unroll) ----------------
__global__ void k_gat2(const unsigned short* __restrict__ h2, const float* __restrict__ as2,
                       const float* __restrict__ ad2, const int* __restrict__ rowptr,
                       const int* __restrict__ adj, const float* __restrict__ b2,
                       float* __restrict__ g2, int N) {
  const int w = threadIdx.x >> 6;
  const int l = threadIdx.x & 63;
  const int n = blockIdx.x * 4 + w;
  if (n >= N) return;
  const int half = l >> 5;
  const int q = l & 31;       // channels 2q, 2q+1
  const float adh = ad2[n];
  float a0 = 0.f, a1 = 0.f, dsum = 0.f;
  const int kb = rowptr[n], ke = rowptr[n + 1];
  const int kend = ke - 1;
  for (int k = kb + half; k < ke; k += 8) {
    const int e1 = k + 2, e2 = k + 4, e3 = k + 6;
    const int s0 = adj[k];
    const int s1 = adj[min(e1, kend)];
    const int s2 = adj[min(e2, kend)];
    const int s3 = adj[min(e3, kend)];
    const float x0 = as2[s0] + adh;
    const float x1 = as2[s1] + adh;
    const float x2 = as2[s2] + adh;
    const float x3 = as2[s3] + adh;
    const unsigned u0 = *(const unsigned*)(h2 + (size_t)s0 * 64 + 2 * q);
    const unsigned u1 = *(const unsigned*)(h2 + (size_t)s1 * 64 + 2 * q);
    const unsigned u2 = *(const unsigned*)(h2 + (size_t)s2 * 64 + 2 * q);
    const unsigned u3 = *(const unsigned*)(h2 + (size_t)s3 * 64 + 2 * q);
    const float w0 = __expf(leaky(x0));
    const float w1 = (e1 < ke) ? __expf(leaky(x1)) : 0.f;
    const float w2 = (e2 < ke) ? __expf(leaky(x2)) : 0.f;
    const float w3 = (e3 < ke) ? __expf(leaky(x3)) : 0.f;
    dsum += (w0 + w1) + (w2 + w3);
    a0 = fmaf(w0, __uint_as_float(u0 << 16), a0);
    a1 = fmaf(w0, __uint_as_float(u0 & 0xFFFF0000u), a1);
    a0 = fmaf(w1, __uint_as_float(u1 << 16), a0);
    a1 = fmaf(w1, __uint_as_float(u1 & 0xFFFF0000u), a1);
    a0 = fmaf(w2, __uint_as_float(u2 << 16), a0);
    a1 = fmaf(w2, __uint_as_float(u2 & 0xFFFF0000u), a1);
    a0 = fmaf(w3, __uint_as_float(u3 << 16), a0);
    a1 = fmaf(w3, __uint_as_float(u3 & 0xFFFF0000u), a1);
  }
  a0 += __shfl_xor(a0, 32, 64);
  a1 += __shfl_xor(a1, 32, 64);
  dsum += __shfl_xor(dsum, 32, 64);
  if (half == 0) {
    const float inv = 1.f / (dsum + 1e-16f);
    const float2 bv = *(const float2*)(b2 + 2 * q);
    ((float2*)g2)[(size_t)n * 32 + q] =
        make_float2(fmaf(a0, inv, bv.x), fmaf(a1, inv, bv.y));
  }
}

// ---------------- build x matrix, bf16, K-blocked: xb[k/32][512][32] ----------------
__global__ void k_xmat(const int* __restrict__ user_idx, const int* __restrict__ ctx_idx,
                       const float* __restrict__ user_emb, const float* __restrict__ g2,
                       unsigned short* __restrict__ xb) {
  const int b = blockIdx.x;
  const int k = threadIdx.x;  // 0..255
  float v;
  if (k < 64) {
    v = user_emb[(size_t)user_idx[b] * 64 + k];
  } else {
    const int c = (k - 64) >> 6;
    v = g2[(size_t)ctx_idx[b * 3 + c] * 64 + (k & 63)];
  }
  xb[(size_t)(k >> 5) * (512 * 32) + b * 32 + (k & 31)] = f2bf(v);
}

// ---------------- final FC via MFMA, A-persistent, double-buffered LDS ------------
// 512 threads = 8 waves; wave w owns x-rows [64w, 64w+64). 32-col grid-strided tiles.
// Double-buffered B staging: ONE barrier per tile. Depth-2 register prefetch: loads
// for tile t+2 issued while tile t computes; LDS write of t+1 waits on loads issued
// a full tile earlier (latency hidden). Swapped MFMA -> float4 output stores.
__global__ __launch_bounds__(512) void k_fc(const unsigned short* __restrict__ xb,
                                            const float* __restrict__ fc_w,
                                            const float* __restrict__ fc_b,
                                            float* __restrict__ out, int NSRV,
                                            int ntiles, int gstride) {
  __shared__ __align__(16) unsigned short Blds[2][32 * 264];  // 33 KB

  const int tid = threadIdx.x;
  const int w = tid >> 6;
  const int lane = tid & 63;
  const int l15 = lane & 15;
  const int kg = lane >> 4;

  if (blockIdx.x >= (unsigned)ntiles) return;

  // persistent A fragments (serve as the MFMA *B* operand after the swap)
  short8 afr[4][8];
#pragma unroll
  for (int mf = 0; mf < 4; ++mf) {
    const int row = w * 64 + mf * 16 + l15;
#pragma unroll
    for (int ks = 0; ks < 8; ++ks) {
      afr[mf][ks] = *(const short8*)(xb + (size_t)ks * 16384 + row * 32 + kg * 8);
    }
  }

  const int sc = tid & 31;   // stage: col in tile
  const int sk = tid >> 5;   // stage: k row 0..15

  float v[16];
  auto loadv = [&](int t) {
    const int cg = t * 32 + sc;
    const bool okc = cg < NSRV;
#pragma unroll
    for (int i = 0; i < 16; ++i)
      v[i] = okc ? fc_w[(size_t)(sk + i * 16) * NSRV + cg] : 0.f;
  };
  auto writev = [&](int buf) {
#pragma unroll
    for (int i = 0; i < 16; ++i)
      Blds[buf][sc * 264 + sk + i * 16] = f2bf(v[i]);
  };

  // prologue: tile t0 staged, loads for t0+gs in flight
  loadv(blockIdx.x);
  writev(0);
  if (blockIdx.x + gstride < ntiles) loadv(blockIdx.x + gstride);
  __syncthreads();

  int cur = 0;
  for (int t = blockIdx.x; t < ntiles; t += gstride) {
    // stage next tile into other buffer (v loaded a full tile ago)
    if (t + gstride < ntiles) writev(cur ^ 1);
    // issue loads for t+2 (consumed next iteration)
    if (t + 2 * gstride < ntiles) loadv(t + 2 * gstride);
    // compute this tile from buf[cur]
    const int j0 = t * 32;
#pragma unroll
    for (int nf = 0; nf < 2; ++nf) {
      short8 bfr[8];
#pragma unroll
      for (int ks = 0; ks < 8; ++ks)
        bfr[ks] = *(const short8*)&Blds[cur][(nf * 16 + l15) * 264 + ks * 32 + kg * 8];
      f32x4 acc[4];
#pragma unroll
      for (int mf = 0; mf < 4; ++mf) acc[mf] = (f32x4){0.f, 0.f, 0.f, 0.f};
#pragma unroll
      for (int ks = 0; ks < 8; ++ks)
#pragma unroll
        for (int mf = 0; mf < 4; ++mf)
          acc[mf] = __builtin_amdgcn_mfma_f32_16x16x32_bf16(bfr[ks], afr[mf][ks], acc[mf], 0, 0, 0);
      const int jc = j0 + nf * 16 + kg * 4;
      if (j0 + 32 <= NSRV) {
        const float4 bias = *(const float4*)(fc_b + jc);
#pragma unroll
        for (int mf = 0; mf < 4; ++mf) {
          const int row = w * 64 + mf * 16 + l15;
          float4 o;
          o.x = acc[mf][0] + bias.x;
          o.y = acc[mf][1] + bias.y;
          o.z = acc[mf][2] + bias.z;
          o.w = acc[mf][3] + bias.w;
          *(float4*)(out + (size_t)row * NSRV + jc) = o;
        }
      } else {
#pragma unroll
        for (int mf = 0; mf < 4; ++mf) {
          const int row = w * 64 + mf * 16 + l15;
#pragma unroll
          for (int r = 0; r < 4; ++r) {
            const int j = jc + r;
            if (j < NSRV) out[(size_t)row * NSRV + j] = acc[mf][r] + fc_b[j];
          }
        }
      }
    }
    __syncthreads();  // buf[cur^1] staged; buf[cur] reads done -> reusable
    cur ^= 1;
  }
}

// =====================================================================
extern "C" void kernel_launch(void* const* d_in, const int* in_sizes, int n_in,
                              void* d_out, int out_size, void* d_ws, size_t ws_size,
                              hipStream_t stream) {
  const int* user_idx    = (const int*)d_in[0];
  const int* context_idx = (const int*)d_in[1];
  const int* edge_index  = (const int*)d_in[2];
  const float* user_emb  = (const float*)d_in[3];
  const float* service_emb = (const float*)d_in[4];
  const float* W1        = (const float*)d_in[5];
  const float* att_src1  = (const float*)d_in[6];
  const float* att_dst1  = (const float*)d_in[7];
  const float* b1        = (const float*)d_in[8];
  const float* W2        = (const float*)d_in[9];
  const float* att_src2  = (const float*)d_in[10];
  const float* att_dst2  = (const float*)d_in[11];
  const float* b2        = (const float*)d_in[12];
  const float* fc_w      = (const float*)d_in[13];
  const float* fc_b      = (const float*)d_in[14];
  float* out = (float*)d_out;

  const int B    = in_sizes[0];
  const int E    = in_sizes[2] / 2;
  const int N    = in_sizes[4] / 64;
  const int NSRV = in_sizes[14];
  const int Etot = E + N;
  (void)B;

  const int* edge_src = edge_index;
  const int* edge_dst = edge_index + E;

  // ---- workspace layout ----
  char* ws = (char*)d_ws;
  size_t off = 0;
  auto alloc = [&](size_t bytes) {
    void* p = ws + off;
    off = (off + bytes + 255) & ~(size_t)255;
    return p;
  };
  const int NB = (N + NPB - 1) >> NPB_SH;   // 196 for N=100000 (requires <=256)
  unsigned short* h1 = (unsigned short*)alloc((size_t)N * 128 * 2);  // reused as h2
  float* g      = (float*)alloc((size_t)N * 128 * 4);                // reused as g2
  float* as1    = (float*)alloc((size_t)N * 2 * 4);
  float* ad1    = (float*)alloc((size_t)N * 2 * 4);
  float* as2    = (float*)alloc((size_t)N * 4);
  float* ad2    = (float*)alloc((size_t)N * 4);
  int*   rowptr = (int*)alloc((size_t)(N + 1) * 4);
  int*   adj    = (int*)alloc((size_t)Etot * 4);
  unsigned* rec = (unsigned*)alloc((size_t)NB * BCAP * 4);
  int* bucketBase   = (int*)alloc(257 * 4);
  int* bucketCursor = (int*)alloc(256 * 4);
  unsigned short* xb = (unsigned short*)alloc((size_t)512 * 256 * 2);
  unsigned short* h2 = h1;
  float* g2 = g;
  (void)ws_size;

  const int NBLK2 = 256;
  const int epb = (Etot + NBLK2 - 1) / NBLK2;

  // GAT layer 1 linear
  k_h1<<<(N + 31) / 32, 256, 0, stream>>>(service_emb, W1, att_src1, att_dst1, h1, as1, ad1, N);

  // CSR build (binned, fixed-capacity regions — no memset, no count pass)
  k_binit<<<1, 256, 0, stream>>>(bucketCursor, NB);
  k_bscatter<<<NBLK2, 1024, 0, stream>>>(edge_src, edge_dst, E, Etot, epb, bucketCursor, rec, NB);
  k_bscan2<<<1, 256, 0, stream>>>(bucketCursor, bucketBase, NB, Etot, rowptr, N);
  k_bcsr<<<NB, 1024, 0, stream>>>(rec, bucketBase, rowptr, adj, N, NB);

  // layer 1 aggregate -> g (elu'd)
  k_gat1<<<(N + 3) / 4, 256, 0, stream>>>(h1, as1, ad1, rowptr, adj, b1, g, N);

  // layer 2 linear (h2 overlays h1)
  k_h2<<<(N + 31) / 32, 256, 0, stream>>>(g, W2, att_src2, att_dst2, h2, as2, ad2, N);

  // layer 2 aggregate -> g2 (overlays g)
  k_gat2<<<(N + 3) / 4, 256, 0, stream>>>(h2, as2, ad2, rowptr, adj, b2, g2, N);

  // gather features -> bf16 K-blocked
  k_xmat<<<512, 256, 0, stream>>>(user_idx, context_idx, user_emb, g2, xb);

  // final FC (MFMA, A-persistent, double-buffered 32-col grid-strided tiles)
  const int nfct = (NSRV + 31) / 32;
  const int grid = 512;
  k_fc<<<grid, 512, 0, stream>>>(xb, fc_w, fc_b, out, NSRV, nfct, grid);
}

// Round 10
// 307.174 us; speedup vs baseline: 4.5403x; 1.3463x over previous
//
#include <hip/hip_runtime.h>
#include <hip/hip_bf16.h>
#include <math.h>

#define NEG_SLOPE 0.2f

// CSR binning parameters (N=100000, E+N~1.7M; requires N < 2^18 and NB <= 256)
#define NPB 512       // nodes per bucket
#define NPB_SH 9
#define SRC_BITS 18
#define LCAP 16384    // LDS adj staging capacity (edges) per bucket
#define BCAP 16384    // fixed per-bucket record capacity (mean ~8.7K, >70 sigma margin)

typedef __attribute__((ext_vector_type(8))) short short8;
typedef __attribute__((ext_vector_type(4))) float f32x4;

__device__ __forceinline__ float leaky(float x) { return x > 0.f ? x : NEG_SLOPE * x; }

__device__ __forceinline__ unsigned short f2bf(float f) {
  unsigned u = __float_as_uint(f);
  unsigned r = (u + 0x7FFFu + ((u >> 16) & 1u)) >> 16;  // RNE
  return (unsigned short)r;
}

// ---------------- GAT layer 1 linear: h1[N,128] = x[N,64] @ W1[64,128] (bf16 out)
__global__ void k_h1(const float* __restrict__ x, const float* __restrict__ W1,
                     const float* __restrict__ att_src, const float* __restrict__ att_dst,
                     unsigned short* __restrict__ h1, float* __restrict__ a_s,
                     float* __restrict__ a_d, int N) {
  __shared__ __align__(16) float W1s[64 * 128];
  __shared__ __align__(16) float xs[2][64];
  for (int i = threadIdx.x; i < 64 * 128; i += 256) W1s[i] = W1[i];
  const int ln  = threadIdx.x >> 7;   // node slot 0/1
  const int col = threadIdx.x & 127;  // output channel
  const int head = col >> 6;
  const int c = col & 63;
  const float as_w = att_src[head * 64 + c];
  const float ad_w = att_dst[head * 64 + c];
  __syncthreads();
  float wreg[64];
#pragma unroll
  for (int cc = 0; cc < 64; ++cc) wreg[cc] = W1s[cc * 128 + col];

  const int node0 = blockIdx.x * 32;
  for (int it = 0; it < 16; ++it) {
    const int nbase = node0 + it * 2;
    __syncthreads();
    if (threadIdx.x < 128) {
      const int nn = nbase + (threadIdx.x >> 6);
      if (nn < N) xs[threadIdx.x >> 6][threadIdx.x & 63] = x[(size_t)nn * 64 + (threadIdx.x & 63)];
    }
    __syncthreads();
    const int n = nbase + ln;
    if (n >= N) continue;
    float acc = 0.f;
#pragma unroll
    for (int q = 0; q < 16; ++q) {
      const float4 xv = *(const float4*)&xs[ln][q * 4];
      acc = fmaf(xv.x, wreg[q * 4 + 0], acc);
      acc = fmaf(xv.y, wreg[q * 4 + 1], acc);
      acc = fmaf(xv.z, wreg[q * 4 + 2], acc);
      acc = fmaf(xv.w, wreg[q * 4 + 3], acc);
    }
    h1[(size_t)n * 128 + col] = f2bf(acc);
    float vs = acc * as_w;
    float vd = acc * ad_w;
#pragma unroll
    for (int off = 32; off > 0; off >>= 1) {
      vs += __shfl_down(vs, off, 64);
      vd += __shfl_down(vd, off, 64);
    }
    if (c == 0) { a_s[n * 2 + head] = vs; a_d[n * 2 + head] = vd; }
  }
}

// ---------------- CSR build via two-level binning (fixed-capacity buckets) ----------------
__global__ void k_binit(int* __restrict__ cursor, int NB) {
  const int i = blockIdx.x * 256 + threadIdx.x;
  if (i < NB) cursor[i] = i * BCAP;
}

__global__ __launch_bounds__(1024) void k_bscatter(const int* __restrict__ src,
                                                   const int* __restrict__ dst, int E, int Etot,
                                                   int epb, int* __restrict__ cursor,
                                                   unsigned* __restrict__ rec, int NB) {
  __shared__ int hist[256];
  __shared__ int cur[256];
  const int tid = threadIdx.x;
  if (tid < 256) hist[tid] = 0;
  __syncthreads();
  const int e0 = blockIdx.x * epb;
  const int e1 = min(e0 + epb, Etot);
  for (int e = e0 + tid; e < e1; e += 1024) {
    const int d = (e < E) ? dst[e] : (e - E);
    atomicAdd(&hist[d >> NPB_SH], 1);
  }
  __syncthreads();
  if (tid < NB) {
    const int c = hist[tid];
    cur[tid] = c ? atomicAdd(&cursor[tid], c) : 0;
  }
  __syncthreads();
  for (int e = e0 + tid; e < e1; e += 1024) {
    int sv, d;
    if (e < E) { sv = src[e]; d = dst[e]; } else { sv = d = e - E; }
    const int b = d >> NPB_SH;
    const int p = atomicAdd(&cur[b], 1);
    rec[p] = (unsigned)sv | ((unsigned)(d & (NPB - 1)) << SRC_BITS);
  }
}

__global__ void k_bscan2(const int* __restrict__ cursor, int* __restrict__ bucketBase,
                         int NB, int Etot, int* __restrict__ rowptr, int N) {
  __shared__ int s[256];
  const int tid = threadIdx.x;
  const int v = (tid < NB) ? (cursor[tid] - tid * BCAP) : 0;
  s[tid] = v;
  __syncthreads();
  for (int off = 1; off < 256; off <<= 1) {
    const int t = (tid >= off) ? s[tid - off] : 0;
    __syncthreads();
    s[tid] += t;
    __syncthreads();
  }
  if (tid < NB) bucketBase[tid] = s[tid] - v;
  if (tid == 0) { bucketBase[NB] = Etot; rowptr[N] = Etot; }
}

__global__ __launch_bounds__(1024) void k_bcsr(const unsigned* __restrict__ rec,
                                               const int* __restrict__ bucketBase,
                                               int* __restrict__ rowptr, int* __restrict__ adj,
                                               int N, int NB) {
  __shared__ int ldeg[NPB];
  __shared__ int s[NPB];
  __shared__ int ladj[LCAP];
  const int b = blockIdx.x;
  const int tid = threadIdx.x;
  const int o0 = bucketBase[b];
  const int cnt = bucketBase[b + 1] - o0;
  const int r0 = b * BCAP;
  if (tid < NPB) ldeg[tid] = 0;
  __syncthreads();
  for (int i = tid; i < cnt; i += 1024)
    atomicAdd(&ldeg[rec[r0 + i] >> SRC_BITS], 1);
  __syncthreads();
  int v = 0;
  if (tid < NPB) { v = ldeg[tid]; s[tid] = v; }
  __syncthreads();
  for (int off = 1; off < NPB; off <<= 1) {
    int t = 0;
    if (tid < NPB && tid >= off) t = s[tid - off];
    __syncthreads();
    if (tid < NPB) s[tid] += t;
    __syncthreads();
  }
  if (tid < NPB) {
    const int excl = s[tid] - v;
    const int node = b * NPB + tid;
    if (node < N) rowptr[node] = o0 + excl;
    ldeg[tid] = excl;  // reuse as scatter cursor
  }
  __syncthreads();
  if (cnt <= LCAP) {
    for (int i = tid; i < cnt; i += 1024) {
      const unsigned r = rec[r0 + i];
      const int p = atomicAdd(&ldeg[r >> SRC_BITS], 1);
      ladj[p] = (int)(r & ((1u << SRC_BITS) - 1));
    }
    __syncthreads();
    for (int i = tid; i < cnt; i += 1024) adj[o0 + i] = ladj[i];
  } else {  // safety fallback (never expected)
    for (int i = tid; i < cnt; i += 1024) {
      const unsigned r = rec[r0 + i];
      const int p = atomicAdd(&ldeg[r >> SRC_BITS], 1);
      adj[o0 + p] = (int)(r & ((1u << SRC_BITS) - 1));
    }
  }
}

// ---------------- demand-driven frontier construction ----------------
// zero flags + counters each launch (graph-replay safe; never hipMemsetAsync)
__global__ void k_zeroflags(int* __restrict__ flagC, int* __restrict__ flag1,
                            int* __restrict__ cnt, int N) {
  const int i = blockIdx.x * 256 + threadIdx.x;
  if (i < N) { flagC[i] = 0; flag1[i] = 0; }
  if (i < 2) cnt[i] = 0;
}

// mark context nodes -> listC (dedup'd); also seed list1 (C needs h2/ad2 rows)
__global__ void k_markC(const int* __restrict__ ctx, int nctx, int* __restrict__ flagC,
                        int* __restrict__ flag1, int* __restrict__ listC,
                        int* __restrict__ list1, int* __restrict__ cnt) {
  const int i = blockIdx.x * 256 + threadIdx.x;
  if (i >= nctx) return;
  const int n = ctx[i];
  if (atomicExch(&flagC[n], 1) == 0) {
    listC[atomicAdd(&cnt[0], 1)] = n;
    if (atomicExch(&flag1[n], 1) == 0)
      list1[atomicAdd(&cnt[1], 1)] = n;
  }
}

// mark in-neighbors of C -> list1 (these need h2/as2 -> need g -> need gat1)
__global__ void k_markS1(const int* __restrict__ listC, const int* __restrict__ rowptr,
                         const int* __restrict__ adj, int* __restrict__ flag1,
                         int* __restrict__ list1, int* __restrict__ cnt) {
  const int i = blockIdx.x * 256 + threadIdx.x;
  if (i >= cnt[0]) return;
  const int n = listC[i];
  const int kb = rowptr[n], ke = rowptr[n + 1];
  for (int k = kb; k < ke; ++k) {
    const int s = adj[k];
    if (atomicExch(&flag1[s], 1) == 0)
      list1[atomicAdd(&cnt[1], 1)] = s;
  }
}

// ---------------- GAT layer 1 aggregate over list1 (x4 unroll) -------
__global__ void k_gat1(const unsigned short* __restrict__ h1, const float* __restrict__ as1,
                       const float* __restrict__ ad1, const int* __restrict__ rowptr,
                       const int* __restrict__ adj, const float* __restrict__ b1,
                       float* __restrict__ g, const int* __restrict__ list1,
                       const int* __restrict__ cnt) {
  const int w = threadIdx.x >> 6;
  const int l = threadIdx.x & 63;
  const int idx = blockIdx.x * 4 + w;
  if (idx >= cnt[1]) return;
  const int n = list1[idx];
  const int half = l >> 5;
  const int q = l & 31;       // channels 4q..4q+3
  const int head = q >> 4;
  const float adh = ad1[n * 2 + head];
  float a0 = 0.f, a1 = 0.f, a2 = 0.f, a3 = 0.f, dsum = 0.f;
  const int kb = rowptr[n], ke = rowptr[n + 1];
  const int kend = ke - 1;
  for (int k = kb + half; k < ke; k += 8) {
    const int e1 = k + 2, e2 = k + 4, e3 = k + 6;
    const int s0 = adj[k];
    const int s1 = adj[min(e1, kend)];
    const int s2 = adj[min(e2, kend)];
    const int s3 = adj[min(e3, kend)];
    const float x0 = as1[s0 * 2 + head] + adh;
    const float x1 = as1[s1 * 2 + head] + adh;
    const float x2 = as1[s2 * 2 + head] + adh;
    const float x3 = as1[s3 * 2 + head] + adh;
    const uint2 u0 = *(const uint2*)(h1 + (size_t)s0 * 128 + 4 * q);
    const uint2 u1 = *(const uint2*)(h1 + (size_t)s1 * 128 + 4 * q);
    const uint2 u2 = *(const uint2*)(h1 + (size_t)s2 * 128 + 4 * q);
    const uint2 u3 = *(const uint2*)(h1 + (size_t)s3 * 128 + 4 * q);
    const float w0 = __expf(leaky(x0));
    const float w1 = (e1 < ke) ? __expf(leaky(x1)) : 0.f;
    const float w2 = (e2 < ke) ? __expf(leaky(x2)) : 0.f;
    const float w3 = (e3 < ke) ? __expf(leaky(x3)) : 0.f;
    dsum += (w0 + w1) + (w2 + w3);
    a0 = fmaf(w0, __uint_as_float(u0.x << 16), a0);
    a1 = fmaf(w0, __uint_as_float(u0.x & 0xFFFF0000u), a1);
    a2 = fmaf(w0, __uint_as_float(u0.y << 16), a2);
    a3 = fmaf(w0, __uint_as_float(u0.y & 0xFFFF0000u), a3);
    a0 = fmaf(w1, __uint_as_float(u1.x << 16), a0);
    a1 = fmaf(w1, __uint_as_float(u1.x & 0xFFFF0000u), a1);
    a2 = fmaf(w1, __uint_as_float(u1.y << 16), a2);
    a3 = fmaf(w1, __uint_as_float(u1.y & 0xFFFF0000u), a3);
    a0 = fmaf(w2, __uint_as_float(u2.x << 16), a0);
    a1 = fmaf(w2, __uint_as_float(u2.x & 0xFFFF0000u), a1);
    a2 = fmaf(w2, __uint_as_float(u2.y << 16), a2);
    a3 = fmaf(w2, __uint_as_float(u2.y & 0xFFFF0000u), a3);
    a0 = fmaf(w3, __uint_as_float(u3.x << 16), a0);
    a1 = fmaf(w3, __uint_as_float(u3.x & 0xFFFF0000u), a1);
    a2 = fmaf(w3, __uint_as_float(u3.y << 16), a2);
    a3 = fmaf(w3, __uint_as_float(u3.y & 0xFFFF0000u), a3);
  }
  a0 += __shfl_xor(a0, 32, 64);
  a1 += __shfl_xor(a1, 32, 64);
  a2 += __shfl_xor(a2, 32, 64);
  a3 += __shfl_xor(a3, 32, 64);
  dsum += __shfl_xor(dsum, 32, 64);
  if (half == 0) {
    const float inv = 1.f / (dsum + 1e-16f);
    const float4 bv = *(const float4*)(b1 + 4 * q);
    float g0 = fmaf(a0, inv, bv.x);
    float g1 = fmaf(a1, inv, bv.y);
    float g2v = fmaf(a2, inv, bv.z);
    float g3 = fmaf(a3, inv, bv.w);
    g0 = g0 > 0.f ? g0 : expm1f(g0);
    g1 = g1 > 0.f ? g1 : expm1f(g1);
    g2v = g2v > 0.f ? g2v : expm1f(g2v);
    g3 = g3 > 0.f ? g3 : expm1f(g3);
    *(float4*)(g + (size_t)n * 128 + 4 * q) = make_float4(g0, g1, g2v, g3);
  }
}

// ---------------- GAT layer 2 linear over list1: h2 = g @ W2 (bf16 out)
__global__ void k_h2(const float* __restrict__ g, const float* __restrict__ W2,
                     const float* __restrict__ att_s, const float* __restrict__ att_d,
                     unsigned short* __restrict__ h2, float* __restrict__ a_s,
                     float* __restrict__ a_d, const int* __restrict__ list1,
                     const int* __restrict__ cnt) {
  const int cnt1 = cnt[1];
  const int base0 = blockIdx.x * 32;
  if (base0 >= cnt1) return;
  __shared__ __align__(16) float W2s[128 * 64];
  __shared__ __align__(16) float gs[2][128];
  __shared__ float part[2][64];
  for (int i = threadIdx.x; i < 128 * 64; i += 256) W2s[i] = W2[i];
  const int col = threadIdx.x & 63;
  const int kh  = (threadIdx.x >> 6) & 1;
  const int ln  = threadIdx.x >> 7;
  const float as_w = att_s[col], ad_w = att_d[col];
  __syncthreads();
  float wreg[64];
#pragma unroll
  for (int cc = 0; cc < 64; ++cc) wreg[cc] = W2s[(kh * 64 + cc) * 64 + col];

  for (int it = 0; it < 16; ++it) {
    const int sbase = base0 + it * 2;
    __syncthreads();
    {
      const int slot = sbase + (threadIdx.x >> 7);
      if (slot < cnt1) {
        const int nn = list1[slot];
        gs[threadIdx.x >> 7][threadIdx.x & 127] = g[(size_t)nn * 128 + (threadIdx.x & 127)];
      }
    }
    __syncthreads();
    const int slot = sbase + ln;
    const int n = (slot < cnt1) ? list1[slot] : -1;
    float acc = 0.f;
    if (n >= 0) {
#pragma unroll
      for (int q = 0; q < 16; ++q) {
        const float4 gv = *(const float4*)&gs[ln][kh * 64 + q * 4];
        acc = fmaf(gv.x, wreg[q * 4 + 0], acc);
        acc = fmaf(gv.y, wreg[q * 4 + 1], acc);
        acc = fmaf(gv.z, wreg[q * 4 + 2], acc);
        acc = fmaf(gv.w, wreg[q * 4 + 3], acc);
      }
    }
    if (kh == 1) part[ln][col] = acc;
    __syncthreads();
    if (kh == 0 && n >= 0) {
      acc += part[ln][col];
      h2[(size_t)n * 64 + col] = f2bf(acc);
      float vs = acc * as_w, vd = acc * ad_w;
#pragma unroll
      for (int off = 32; off > 0; off >>= 1) {
        vs += __shfl_down(vs, off, 64);
        vd += __shfl_down(vd, off, 64);
      }
      if (col == 0) { a_s[n] = vs; a_d[n] = vd; }
    }
  }
}

// ---------------- GAT layer 2 aggregate over listC (x4 unroll) ----------------
__global__ void k_gat2(const unsigned short* __restrict__ h2, const float* __restrict__ as2,
                       const float* __restrict__ ad2, const int* __restrict__ rowptr,
                       const int* __restrict__ adj, const float* __restrict__ b2,
                       float* __restrict__ g2, const int* __restrict__ listC,
                       const int* __restrict__ cnt) {
  const int w = threadIdx.x >> 6;
  const int l = threadIdx.x & 63;
  const int idx = blockIdx.x * 4 + w;
  if (idx >= cnt[0]) return;
  const int n = listC[idx];
  const int half = l >> 5;
  const int q = l & 31;       // channels 2q, 2q+1
  const float adh = ad2[n];
  float a0 = 0.f, a1 = 0.f, dsum = 0.f;
  const int kb = rowptr[n], ke = rowptr[n + 1];
  const int kend = ke - 1;
  for (int k = kb + half; k < ke; k += 8) {
    const int e1 = k + 2, e2 = k + 4, e3 = k + 6;
    const int s0 = adj[k];
    const int s1 = adj[min(e1, kend)];
    const int s2 = adj[min(e2, kend)];
    const int s3 = adj[min(e3, kend)];
    const float x0 = as2[s0] + adh;
    const float x1 = as2[s1] + adh;
    const float x2 = as2[s2] + adh;
    const float x3 = as2[s3] + adh;
    const unsigned u0 = *(const unsigned*)(h2 + (size_t)s0 * 64 + 2 * q);
    const unsigned u1 = *(const unsigned*)(h2 + (size_t)s1 * 64 + 2 * q);
    const unsigned u2 = *(const unsigned*)(h2 + (size_t)s2 * 64 + 2 * q);
    const unsigned u3 = *(const unsigned*)(h2 + (size_t)s3 * 64 + 2 * q);
    const float w0 = __expf(leaky(x0));
    const float w1 = (e1 < ke) ? __expf(leaky(x1)) : 0.f;
    const float w2 = (e2 < ke) ? __expf(leaky(x2)) : 0.f;
    const float w3 = (e3 < ke) ? __expf(leaky(x3)) : 0.f;
    dsum += (w0 + w1) + (w2 + w3);
    a0 = fmaf(w0, __uint_as_float(u0 << 16), a0);
    a1 = fmaf(w0, __uint_as_float(u0 & 0xFFFF0000u), a1);
    a0 = fmaf(w1, __uint_as_float(u1 << 16), a0);
    a1 = fmaf(w1, __uint_as_float(u1 & 0xFFFF0000u), a1);
    a0 = fmaf(w2, __uint_as_float(u2 << 16), a0);
    a1 = fmaf(w2, __uint_as_float(u2 & 0xFFFF0000u), a1);
    a0 = fmaf(w3, __uint_as_float(u3 << 16), a0);
    a1 = fmaf(w3, __uint_as_float(u3 & 0xFFFF0000u), a1);
  }
  a0 += __shfl_xor(a0, 32, 64);
  a1 += __shfl_xor(a1, 32, 64);
  dsum += __shfl_xor(dsum, 32, 64);
  if (half == 0) {
    const float inv = 1.f / (dsum + 1e-16f);
    const float2 bv = *(const float2*)(b2 + 2 * q);
    ((float2*)g2)[(size_t)n * 32 + q] =
        make_float2(fmaf(a0, inv, bv.x), fmaf(a1, inv, bv.y));
  }
}

// ---------------- build x matrix, bf16, K-blocked: xb[k/32][512][32] ----------------
__global__ void k_xmat(const int* __restrict__ user_idx, const int* __restrict__ ctx_idx,
                       const float* __restrict__ user_emb, const float* __restrict__ g2,
                       unsigned short* __restrict__ xb) {
  const int b = blockIdx.x;
  const int k = threadIdx.x;  // 0..255
  float v;
  if (k < 64) {
    v = user_emb[(size_t)user_idx[b] * 64 + k];
  } else {
    const int c = (k - 64) >> 6;
    v = g2[(size_t)ctx_idx[b * 3 + c] * 64 + (k & 63)];
  }
  xb[(size_t)(k >> 5) * (512 * 32) + b * 32 + (k & 31)] = f2bf(v);
}

// ---------------- final FC via MFMA, A-persistent, double-buffered LDS ------------
__global__ __launch_bounds__(512) void k_fc(const unsigned short* __restrict__ xb,
                                            const float* __restrict__ fc_w,
                                            const float* __restrict__ fc_b,
                                            float* __restrict__ out, int NSRV,
                                            int ntiles, int gstride) {
  __shared__ __align__(16) unsigned short Blds[2][32 * 264];  // 33 KB

  const int tid = threadIdx.x;
  const int w = tid >> 6;
  const int lane = tid & 63;
  const int l15 = lane & 15;
  const int kg = lane >> 4;

  if (blockIdx.x >= (unsigned)ntiles) return;

  // persistent A fragments (serve as the MFMA *B* operand after the swap)
  short8 afr[4][8];
#pragma unroll
  for (int mf = 0; mf < 4; ++mf) {
    const int row = w * 64 + mf * 16 + l15;
#pragma unroll
    for (int ks = 0; ks < 8; ++ks) {
      afr[mf][ks] = *(const short8*)(xb + (size_t)ks * 16384 + row * 32 + kg * 8);
    }
  }

  const int sc = tid & 31;   // stage: col in tile
  const int sk = tid >> 5;   // stage: k row 0..15

  float v[16];
  auto loadv = [&](int t) {
    const int cg = t * 32 + sc;
    const bool okc = cg < NSRV;
#pragma unroll
    for (int i = 0; i < 16; ++i)
      v[i] = okc ? fc_w[(size_t)(sk + i * 16) * NSRV + cg] : 0.f;
  };
  auto writev = [&](int buf) {
#pragma unroll
    for (int i = 0; i < 16; ++i)
      Blds[buf][sc * 264 + sk + i * 16] = f2bf(v[i]);
  };

  // prologue: tile t0 staged, loads for t0+gs in flight
  loadv(blockIdx.x);
  writev(0);
  if (blockIdx.x + gstride < ntiles) loadv(blockIdx.x + gstride);
  __syncthreads();

  int cur = 0;
  for (int t = blockIdx.x; t < ntiles; t += gstride) {
    if (t + gstride < ntiles) writev(cur ^ 1);
    if (t + 2 * gstride < ntiles) loadv(t + 2 * gstride);
    const int j0 = t * 32;
#pragma unroll
    for (int nf = 0; nf < 2; ++nf) {
      short8 bfr[8];
#pragma unroll
      for (int ks = 0; ks < 8; ++ks)
        bfr[ks] = *(const short8*)&Blds[cur][(nf * 16 + l15) * 264 + ks * 32 + kg * 8];
      f32x4 acc[4];
#pragma unroll
      for (int mf = 0; mf < 4; ++mf) acc[mf] = (f32x4){0.f, 0.f, 0.f, 0.f};
#pragma unroll
      for (int ks = 0; ks < 8; ++ks)
#pragma unroll
        for (int mf = 0; mf < 4; ++mf)
          acc[mf] = __builtin_amdgcn_mfma_f32_16x16x32_bf16(bfr[ks], afr[mf][ks], acc[mf], 0, 0, 0);
      const int jc = j0 + nf * 16 + kg * 4;
      if (j0 + 32 <= NSRV) {
        const float4 bias = *(const float4*)(fc_b + jc);
#pragma unroll
        for (int mf = 0; mf < 4; ++mf) {
          const int row = w * 64 + mf * 16 + l15;
          float4 o;
          o.x = acc[mf][0] + bias.x;
          o.y = acc[mf][1] + bias.y;
          o.z = acc[mf][2] + bias.z;
          o.w = acc[mf][3] + bias.w;
          *(float4*)(out + (size_t)row * NSRV + jc) = o;
        }
      } else {
#pragma unroll
        for (int mf = 0; mf < 4; ++mf) {
          const int row = w * 64 + mf * 16 + l15;
#pragma unroll
          for (int r = 0; r < 4; ++r) {
            const int j = jc + r;
            if (j < NSRV) out[(size_t)row * NSRV + j] = acc[mf][r] + fc_b[j];
          }
        }
      }
    }
    __syncthreads();
    cur ^= 1;
  }
}

// =====================================================================
extern "C" void kernel_launch(void* const* d_in, const int* in_sizes, int n_in,
                              void* d_out, int out_size, void* d_ws, size_t ws_size,
                              hipStream_t stream) {
  const int* user_idx    = (const int*)d_in[0];
  const int* context_idx = (const int*)d_in[1];
  const int* edge_index  = (const int*)d_in[2];
  const float* user_emb  = (const float*)d_in[3];
  const float* service_emb = (const float*)d_in[4];
  const float* W1        = (const float*)d_in[5];
  const float* att_src1  = (const float*)d_in[6];
  const float* att_dst1  = (const float*)d_in[7];
  const float* b1        = (const float*)d_in[8];
  const float* W2        = (const float*)d_in[9];
  const float* att_src2  = (const float*)d_in[10];
  const float* att_dst2  = (const float*)d_in[11];
  const float* b2        = (const float*)d_in[12];
  const float* fc_w      = (const float*)d_in[13];
  const float* fc_b      = (const float*)d_in[14];
  float* out = (float*)d_out;

  const int B    = in_sizes[0];
  const int E    = in_sizes[2] / 2;
  const int N    = in_sizes[4] / 64;
  const int NSRV = in_sizes[14];
  const int Etot = E + N;
  const int NCTX = in_sizes[1];  // B*CTX

  const int* edge_src = edge_index;
  const int* edge_dst = edge_index + E;

  // ---- workspace layout ----
  char* ws = (char*)d_ws;
  size_t off = 0;
  auto alloc = [&](size_t bytes) {
    void* p = ws + off;
    off = (off + bytes + 255) & ~(size_t)255;
    return p;
  };
  const int NB = (N + NPB - 1) >> NPB_SH;   // 196 for N=100000 (requires <=256)
  unsigned short* h1 = (unsigned short*)alloc((size_t)N * 128 * 2);  // reused as h2
  float* g      = (float*)alloc((size_t)N * 128 * 4);                // reused as g2
  float* as1    = (float*)alloc((size_t)N * 2 * 4);
  float* ad1    = (float*)alloc((size_t)N * 2 * 4);
  float* as2    = (float*)alloc((size_t)N * 4);
  float* ad2    = (float*)alloc((size_t)N * 4);
  int*   rowptr = (int*)alloc((size_t)(N + 1) * 4);
  int*   adj    = (int*)alloc((size_t)Etot * 4);
  unsigned* rec = (unsigned*)alloc((size_t)NB * BCAP * 4);
  int* bucketBase   = (int*)alloc(257 * 4);
  int* bucketCursor = (int*)alloc(256 * 4);
  int* flagC  = (int*)alloc((size_t)N * 4);
  int* flag1  = (int*)alloc((size_t)N * 4);
  int* listC  = (int*)alloc((size_t)NCTX * 4);
  int* list1  = (int*)alloc((size_t)N * 4);
  int* cnt    = (int*)alloc(2 * 4);
  unsigned short* xb = (unsigned short*)alloc((size_t)512 * 256 * 2);
  unsigned short* h2 = h1;
  float* g2 = g;
  (void)ws_size;

  const int NBLK2 = 256;
  const int epb = (Etot + NBLK2 - 1) / NBLK2;
  const int nblk_N = (N + 255) / 256;

  // GAT layer 1 linear (full N — sources cover ~99% of nodes)
  k_h1<<<(N + 31) / 32, 256, 0, stream>>>(service_emb, W1, att_src1, att_dst1, h1, as1, ad1, N);

  // CSR build (binned, fixed-capacity regions)
  k_binit<<<1, 256, 0, stream>>>(bucketCursor, NB);
  k_bscatter<<<NBLK2, 1024, 0, stream>>>(edge_src, edge_dst, E, Etot, epb, bucketCursor, rec, NB);
  k_bscan2<<<1, 256, 0, stream>>>(bucketCursor, bucketBase, NB, Etot, rowptr, N);
  k_bcsr<<<NB, 1024, 0, stream>>>(rec, bucketBase, rowptr, adj, N, NB);

  // demand-driven frontier: C = ctx nodes; S1 = C ∪ in-neighbors(C)
  k_zeroflags<<<nblk_N, 256, 0, stream>>>(flagC, flag1, cnt, N);
  k_markC<<<(NCTX + 255) / 256, 256, 0, stream>>>(context_idx, NCTX, flagC, flag1, listC, list1, cnt);
  k_markS1<<<(NCTX + 255) / 256, 256, 0, stream>>>(listC, rowptr, adj, flag1, list1, cnt);

  // layer 1 aggregate -> g (elu'd), only for list1 nodes
  k_gat1<<<(N + 3) / 4, 256, 0, stream>>>(h1, as1, ad1, rowptr, adj, b1, g, list1, cnt);

  // layer 2 linear (h2 overlays h1), only for list1 nodes
  k_h2<<<(N + 31) / 32, 256, 0, stream>>>(g, W2, att_src2, att_dst2, h2, as2, ad2, list1, cnt);

  // layer 2 aggregate -> g2 (overlays g), only for C nodes
  k_gat2<<<(NCTX + 3) / 4, 256, 0, stream>>>(h2, as2, ad2, rowptr, adj, b2, g2, listC, cnt);

  // gather features -> bf16 K-blocked
  k_xmat<<<512, 256, 0, stream>>>(user_idx, context_idx, user_emb, g2, xb);

  // final FC (MFMA, A-persistent, double-buffered 32-col grid-strided tiles)
  const int nfct = (NSRV + 31) / 32;
  const int grid = 512;
  k_fc<<<grid, 512, 0, stream>>>(xb, fc_w, fc_b, out, NSRV, nfct, grid);
}

// Round 12
// 295.517 us; speedup vs baseline: 4.7194x; 1.0394x over previous
//
#include <hip/hip_runtime.h>
#include <hip/hip_bf16.h>
#include <math.h>

#define NEG_SLOPE 0.2f

// CSR binning parameters (N=100000, E+N~1.7M; requires N < 2^18 and NB <= 256)
#define NPB 512       // nodes per bucket
#define NPB_SH 9
#define SRC_BITS 18
#define LCAP 16384    // LDS adj staging capacity (edges) per bucket
#define BCAP 16384    // fixed per-bucket record capacity (mean ~8.7K, >70 sigma margin)

typedef __attribute__((ext_vector_type(8))) short short8;
typedef __attribute__((ext_vector_type(4))) float f32x4;

__device__ __forceinline__ float leaky(float x) { return x > 0.f ? x : NEG_SLOPE * x; }

__device__ __forceinline__ unsigned short f2bf(float f) {
  unsigned u = __float_as_uint(f);
  unsigned r = (u + 0x7FFFu + ((u >> 16) & 1u)) >> 16;  // RNE
  return (unsigned short)r;
}

// ---------------- GAT layer 1 linear: h1[N,128] = x[N,64] @ W1[64,128] (bf16 out)
// 32 nodes staged ONCE per block -> single barrier; inner loop barrier-free.
__global__ void k_h1(const float* __restrict__ x, const float* __restrict__ W1,
                     const float* __restrict__ att_src, const float* __restrict__ att_dst,
                     unsigned short* __restrict__ h1, float* __restrict__ a_s,
                     float* __restrict__ a_d, int N) {
  __shared__ __align__(16) float W1s[64 * 128];   // 32 KB
  __shared__ __align__(16) float xs[32][64];      // 8 KB
  const int tid = threadIdx.x;
  for (int i = tid; i < 64 * 128; i += 256) W1s[i] = W1[i];
  const int node0 = blockIdx.x * 32;
  // stage 32 nodes of x: 2048 floats = 512 float4, fully contiguous
  for (int i = tid; i < 512; i += 256) {
    const int nn = node0 + (i >> 4);
    if (nn < N) ((float4*)xs)[i] = *(const float4*)(x + (size_t)nn * 64 + (i & 15) * 4);
  }
  const int ln  = tid >> 7;   // node slot 0/1
  const int col = tid & 127;  // output channel
  const int head = col >> 6;
  const int c = col & 63;
  const float as_w = att_src[head * 64 + c];
  const float ad_w = att_dst[head * 64 + c];
  __syncthreads();  // W1s + xs ready
  float wreg[64];
#pragma unroll
  for (int cc = 0; cc < 64; ++cc) wreg[cc] = W1s[cc * 128 + col];

  for (int it = 0; it < 16; ++it) {
    const int slot = it * 2 + ln;
    const int n = node0 + slot;
    if (n >= N) continue;
    float acc = 0.f;
#pragma unroll
    for (int q = 0; q < 16; ++q) {
      const float4 xv = *(const float4*)&xs[slot][q * 4];
      acc = fmaf(xv.x, wreg[q * 4 + 0], acc);
      acc = fmaf(xv.y, wreg[q * 4 + 1], acc);
      acc = fmaf(xv.z, wreg[q * 4 + 2], acc);
      acc = fmaf(xv.w, wreg[q * 4 + 3], acc);
    }
    h1[(size_t)n * 128 + col] = f2bf(acc);
    float vs = acc * as_w;
    float vd = acc * ad_w;
#pragma unroll
    for (int off = 32; off > 0; off >>= 1) {
      vs += __shfl_down(vs, off, 64);
      vd += __shfl_down(vd, off, 64);
    }
    if (c == 0) { a_s[n * 2 + head] = vs; a_d[n * 2 + head] = vd; }
  }
}

// ---------------- combined init: bucket cursors + frontier flags + counters ----------
__global__ void k_init(int* __restrict__ cursor, int NB, int* __restrict__ flagC,
                       int* __restrict__ flag1, int* __restrict__ cnt, int N) {
  const int i = blockIdx.x * 256 + threadIdx.x;
  if (i < NB) cursor[i] = i * BCAP;
  if (i < N) { flagC[i] = 0; flag1[i] = 0; }
  if (i < 2) cnt[i] = 0;
}

// ---------------- CSR build via two-level binning (fixed-capacity buckets) ----------------
__global__ __launch_bounds__(1024) void k_bscatter(const int* __restrict__ src,
                                                   const int* __restrict__ dst, int E, int Etot,
                                                   int epb, int* __restrict__ cursor,
                                                   unsigned* __restrict__ rec, int NB) {
  __shared__ int hist[256];
  __shared__ int cur[256];
  const int tid = threadIdx.x;
  if (tid < 256) hist[tid] = 0;
  __syncthreads();
  const int e0 = blockIdx.x * epb;
  const int e1 = min(e0 + epb, Etot);
  for (int e = e0 + tid; e < e1; e += 1024) {
    const int d = (e < E) ? dst[e] : (e - E);
    atomicAdd(&hist[d >> NPB_SH], 1);
  }
  __syncthreads();
  if (tid < NB) {
    const int c = hist[tid];
    cur[tid] = c ? atomicAdd(&cursor[tid], c) : 0;
  }
  __syncthreads();
  for (int e = e0 + tid; e < e1; e += 1024) {
    int sv, d;
    if (e < E) { sv = src[e]; d = dst[e]; } else { sv = d = e - E; }
    const int b = d >> NPB_SH;
    const int p = atomicAdd(&cur[b], 1);
    rec[p] = (unsigned)sv | ((unsigned)(d & (NPB - 1)) << SRC_BITS);
  }
}

__global__ void k_bscan2(const int* __restrict__ cursor, int* __restrict__ bucketBase,
                         int NB, int Etot, int* __restrict__ rowptr, int N) {
  __shared__ int s[256];
  const int tid = threadIdx.x;
  const int v = (tid < NB) ? (cursor[tid] - tid * BCAP) : 0;
  s[tid] = v;
  __syncthreads();
  for (int off = 1; off < 256; off <<= 1) {
    const int t = (tid >= off) ? s[tid - off] : 0;
    __syncthreads();
    s[tid] += t;
    __syncthreads();
  }
  if (tid < NB) bucketBase[tid] = s[tid] - v;
  if (tid == 0) { bucketBase[NB] = Etot; rowptr[N] = Etot; }
}

__global__ __launch_bounds__(1024) void k_bcsr(const unsigned* __restrict__ rec,
                                               const int* __restrict__ bucketBase,
                                               int* __restrict__ rowptr, int* __restrict__ adj,
                                               int N, int NB) {
  __shared__ int ldeg[NPB];
  __shared__ int s[NPB];
  __shared__ int ladj[LCAP];
  const int b = blockIdx.x;
  const int tid = threadIdx.x;
  const int o0 = bucketBase[b];
  const int cnt = bucketBase[b + 1] - o0;
  const int r0 = b * BCAP;
  if (tid < NPB) ldeg[tid] = 0;
  __syncthreads();
  for (int i = tid; i < cnt; i += 1024)
    atomicAdd(&ldeg[rec[r0 + i] >> SRC_BITS], 1);
  __syncthreads();
  int v = 0;
  if (tid < NPB) { v = ldeg[tid]; s[tid] = v; }
  __syncthreads();
  for (int off = 1; off < NPB; off <<= 1) {
    int t = 0;
    if (tid < NPB && tid >= off) t = s[tid - off];
    __syncthreads();
    if (tid < NPB) s[tid] += t;
    __syncthreads();
  }
  if (tid < NPB) {
    const int excl = s[tid] - v;
    const int node = b * NPB + tid;
    if (node < N) rowptr[node] = o0 + excl;
    ldeg[tid] = excl;  // reuse as scatter cursor
  }
  __syncthreads();
  if (cnt <= LCAP) {
    for (int i = tid; i < cnt; i += 1024) {
      const unsigned r = rec[r0 + i];
      const int p = atomicAdd(&ldeg[r >> SRC_BITS], 1);
      ladj[p] = (int)(r & ((1u << SRC_BITS) - 1));
    }
    __syncthreads();
    for (int i = tid; i < cnt; i += 1024) adj[o0 + i] = ladj[i];
  } else {  // safety fallback (never expected)
    for (int i = tid; i < cnt; i += 1024) {
      const unsigned r = rec[r0 + i];
      const int p = atomicAdd(&ldeg[r >> SRC_BITS], 1);
      adj[o0 + p] = (int)(r & ((1u << SRC_BITS) - 1));
    }
  }
}

// ---------------- demand-driven frontier construction ----------------
__global__ void k_markC(const int* __restrict__ ctx, int nctx, int* __restrict__ flagC,
                        int* __restrict__ flag1, int* __restrict__ listC,
                        int* __restrict__ list1, int* __restrict__ cnt) {
  const int i = blockIdx.x * 256 + threadIdx.x;
  if (i >= nctx) return;
  const int n = ctx[i];
  if (atomicExch(&flagC[n], 1) == 0) {
    listC[atomicAdd(&cnt[0], 1)] = n;
    if (atomicExch(&flag1[n], 1) == 0)
      list1[atomicAdd(&cnt[1], 1)] = n;
  }
}

__global__ void k_markS1(const int* __restrict__ listC, const int* __restrict__ rowptr,
                         const int* __restrict__ adj, int* __restrict__ flag1,
                         int* __restrict__ list1, int* __restrict__ cnt) {
  const int i = blockIdx.x * 256 + threadIdx.x;
  if (i >= cnt[0]) return;
  const int n = listC[i];
  const int kb = rowptr[n], ke = rowptr[n + 1];
  for (int k = kb; k < ke; ++k) {
    const int s = adj[k];
    if (atomicExch(&flag1[s], 1) == 0)
      list1[atomicAdd(&cnt[1], 1)] = s;
  }
}

// ---------------- GAT layer 1 aggregate over list1 (x4 unroll) -------
__global__ void k_gat1(const unsigned short* __restrict__ h1, const float* __restrict__ as1,
                       const float* __restrict__ ad1, const int* __restrict__ rowptr,
                       const int* __restrict__ adj, const float* __restrict__ b1,
                       float* __restrict__ g, const int* __restrict__ list1,
                       const int* __restrict__ cnt) {
  const int w = threadIdx.x >> 6;
  const int l = threadIdx.x & 63;
  const int idx = blockIdx.x * 4 + w;
  if (idx >= cnt[1]) return;
  const int n = list1[idx];
  const int half = l >> 5;
  const int q = l & 31;       // channels 4q..4q+3
  const int head = q >> 4;
  const float adh = ad1[n * 2 + head];
  float a0 = 0.f, a1 = 0.f, a2 = 0.f, a3 = 0.f, dsum = 0.f;
  const int kb = rowptr[n], ke = rowptr[n + 1];
  const int kend = ke - 1;
  for (int k = kb + half; k < ke; k += 8) {
    const int e1 = k + 2, e2 = k + 4, e3 = k + 6;
    const int s0 = adj[k];
    const int s1 = adj[min(e1, kend)];
    const int s2 = adj[min(e2, kend)];
    const int s3 = adj[min(e3, kend)];
    const float x0 = as1[s0 * 2 + head] + adh;
    const float x1 = as1[s1 * 2 + head] + adh;
    const float x2 = as1[s2 * 2 + head] + adh;
    const float x3 = as1[s3 * 2 + head] + adh;
    const uint2 u0 = *(const uint2*)(h1 + (size_t)s0 * 128 + 4 * q);
    const uint2 u1 = *(const uint2*)(h1 + (size_t)s1 * 128 + 4 * q);
    const uint2 u2 = *(const uint2*)(h1 + (size_t)s2 * 128 + 4 * q);
    const uint2 u3 = *(const uint2*)(h1 + (size_t)s3 * 128 + 4 * q);
    const float w0 = __expf(leaky(x0));
    const float w1 = (e1 < ke) ? __expf(leaky(x1)) : 0.f;
    const float w2 = (e2 < ke) ? __expf(leaky(x2)) : 0.f;
    const float w3 = (e3 < ke) ? __expf(leaky(x3)) : 0.f;
    dsum += (w0 + w1) + (w2 + w3);
    a0 = fmaf(w0, __uint_as_float(u0.x << 16), a0);
    a1 = fmaf(w0, __uint_as_float(u0.x & 0xFFFF0000u), a1);
    a2 = fmaf(w0, __uint_as_float(u0.y << 16), a2);
    a3 = fmaf(w0, __uint_as_float(u0.y & 0xFFFF0000u), a3);
    a0 = fmaf(w1, __uint_as_float(u1.x << 16), a0);
    a1 = fmaf(w1, __uint_as_float(u1.x & 0xFFFF0000u), a1);
    a2 = fmaf(w1, __uint_as_float(u1.y << 16), a2);
    a3 = fmaf(w1, __uint_as_float(u1.y & 0xFFFF0000u), a3);
    a0 = fmaf(w2, __uint_as_float(u2.x << 16), a0);
    a1 = fmaf(w2, __uint_as_float(u2.x & 0xFFFF0000u), a1);
    a2 = fmaf(w2, __uint_as_float(u2.y << 16), a2);
    a3 = fmaf(w2, __uint_as_float(u2.y & 0xFFFF0000u), a3);
    a0 = fmaf(w3, __uint_as_float(u3.x << 16), a0);
    a1 = fmaf(w3, __uint_as_float(u3.x & 0xFFFF0000u), a1);
    a2 = fmaf(w3, __uint_as_float(u3.y << 16), a2);
    a3 = fmaf(w3, __uint_as_float(u3.y & 0xFFFF0000u), a3);
  }
  a0 += __shfl_xor(a0, 32, 64);
  a1 += __shfl_xor(a1, 32, 64);
  a2 += __shfl_xor(a2, 32, 64);
  a3 += __shfl_xor(a3, 32, 64);
  dsum += __shfl_xor(dsum, 32, 64);
  if (half == 0) {
    const float inv = 1.f / (dsum + 1e-16f);
    const float4 bv = *(const float4*)(b1 + 4 * q);
    float g0 = fmaf(a0, inv, bv.x);
    float g1 = fmaf(a1, inv, bv.y);
    float g2v = fmaf(a2, inv, bv.z);
    float g3 = fmaf(a3, inv, bv.w);
    g0 = g0 > 0.f ? g0 : expm1f(g0);
    g1 = g1 > 0.f ? g1 : expm1f(g1);
    g2v = g2v > 0.f ? g2v : expm1f(g2v);
    g3 = g3 > 0.f ? g3 : expm1f(g3);
    *(float4*)(g + (size_t)n * 128 + 4 * q) = make_float4(g0, g1, g2v, g3);
  }
}

// ---------------- GAT layer 2 linear over list1: h2 = g @ W2 (bf16 out)
__global__ void k_h2(const float* __restrict__ g, const float* __restrict__ W2,
                     const float* __restrict__ att_s, const float* __restrict__ att_d,
                     unsigned short* __restrict__ h2, float* __restrict__ a_s,
                     float* __restrict__ a_d, const int* __restrict__ list1,
                     const int* __restrict__ cnt) {
  const int cnt1 = cnt[1];
  const int base0 = blockIdx.x * 32;
  if (base0 >= cnt1) return;
  __shared__ __align__(16) float W2s[128 * 64];
  __shared__ __align__(16) float gs[2][128];
  __shared__ float part[2][64];
  for (int i = threadIdx.x; i < 128 * 64; i += 256) W2s[i] = W2[i];
  const int col = threadIdx.x & 63;
  const int kh  = (threadIdx.x >> 6) & 1;
  const int ln  = threadIdx.x >> 7;
  const float as_w = att_s[col], ad_w = att_d[col];
  __syncthreads();
  float wreg[64];
#pragma unroll
  for (int cc = 0; cc < 64; ++cc) wreg[cc] = W2s[(kh * 64 + cc) * 64 + col];

  for (int it = 0; it < 16; ++it) {
    const int sbase = base0 + it * 2;
    __syncthreads();
    {
      const int slot = sbase + (threadIdx.x >> 7);
      if (slot < cnt1) {
        const int nn = list1[slot];
        gs[threadIdx.x >> 7][threadIdx.x & 127] = g[(size_t)nn * 128 + (threadIdx.x & 127)];
      }
    }
    __syncthreads();
    const int slot = sbase + ln;
    const int n = (slot < cnt1) ? list1[slot] : -1;
    float acc = 0.f;
    if (n >= 0) {
#pragma unroll
      for (int q = 0; q < 16; ++q) {
        const float4 gv = *(const float4*)&gs[ln][kh * 64 + q * 4];
        acc = fmaf(gv.x, wreg[q * 4 + 0], acc);
        acc = fmaf(gv.y, wreg[q * 4 + 1], acc);
        acc = fmaf(gv.z, wreg[q * 4 + 2], acc);
        acc = fmaf(gv.w, wreg[q * 4 + 3], acc);
      }
    }
    if (kh == 1) part[ln][col] = acc;
    __syncthreads();
    if (kh == 0 && n >= 0) {
      acc += part[ln][col];
      h2[(size_t)n * 64 + col] = f2bf(acc);
      float vs = acc * as_w, vd = acc * ad_w;
#pragma unroll
      for (int off = 32; off > 0; off >>= 1) {
        vs += __shfl_down(vs, off, 64);
        vd += __shfl_down(vd, off, 64);
      }
      if (col == 0) { a_s[n] = vs; a_d[n] = vd; }
    }
  }
}

// ---------------- GAT layer 2 aggregate over listC (x4 unroll) ----------------
__global__ void k_gat2(const unsigned short* __restrict__ h2, const float* __restrict__ as2,
                       const float* __restrict__ ad2, const int* __restrict__ rowptr,
                       const int* __restrict__ adj, const float* __restrict__ b2,
                       float* __restrict__ g2, const int* __restrict__ listC,
                       const int* __restrict__ cnt) {
  const int w = threadIdx.x >> 6;
  const int l = threadIdx.x & 63;
  const int idx = blockIdx.x * 4 + w;
  if (idx >= cnt[0]) return;
  const int n = listC[idx];
  const int half = l >> 5;
  const int q = l & 31;       // channels 2q, 2q+1
  const float adh = ad2[n];
  float a0 = 0.f, a1 = 0.f, dsum = 0.f;
  const int kb = rowptr[n], ke = rowptr[n + 1];
  const int kend = ke - 1;
  for (int k = kb + half; k < ke; k += 8) {
    const int e1 = k + 2, e2 = k + 4, e3 = k + 6;
    const int s0 = adj[k];
    const int s1 = adj[min(e1, kend)];
    const int s2 = adj[min(e2, kend)];
    const int s3 = adj[min(e3, kend)];
    const float x0 = as2[s0] + adh;
    const float x1 = as2[s1] + adh;
    const float x2 = as2[s2] + adh;
    const float x3 = as2[s3] + adh;
    const unsigned u0 = *(const unsigned*)(h2 + (size_t)s0 * 64 + 2 * q);
    const unsigned u1 = *(const unsigned*)(h2 + (size_t)s1 * 64 + 2 * q);
    const unsigned u2 = *(const unsigned*)(h2 + (size_t)s2 * 64 + 2 * q);
    const unsigned u3 = *(const unsigned*)(h2 + (size_t)s3 * 64 + 2 * q);
    const float w0 = __expf(leaky(x0));
    const float w1 = (e1 < ke) ? __expf(leaky(x1)) : 0.f;
    const float w2 = (e2 < ke) ? __expf(leaky(x2)) : 0.f;
    const float w3 = (e3 < ke) ? __expf(leaky(x3)) : 0.f;
    dsum += (w0 + w1) + (w2 + w3);
    a0 = fmaf(w0, __uint_as_float(u0 << 16), a0);
    a1 = fmaf(w0, __uint_as_float(u0 & 0xFFFF0000u), a1);
    a0 = fmaf(w1, __uint_as_float(u1 << 16), a0);
    a1 = fmaf(w1, __uint_as_float(u1 & 0xFFFF0000u), a1);
    a0 = fmaf(w2, __uint_as_float(u2 << 16), a0);
    a1 = fmaf(w2, __uint_as_float(u2 & 0xFFFF0000u), a1);
    a0 = fmaf(w3, __uint_as_float(u3 << 16), a0);
    a1 = fmaf(w3, __uint_as_float(u3 & 0xFFFF0000u), a1);
  }
  a0 += __shfl_xor(a0, 32, 64);
  a1 += __shfl_xor(a1, 32, 64);
  dsum += __shfl_xor(dsum, 32, 64);
  if (half == 0) {
    const float inv = 1.f / (dsum + 1e-16f);
    const float2 bv = *(const float2*)(b2 + 2 * q);
    ((float2*)g2)[(size_t)n * 32 + q] =
        make_float2(fmaf(a0, inv, bv.x), fmaf(a1, inv, bv.y));
  }
}

// ---------------- build x matrix, bf16, K-blocked: xb[k/32][512][32] ----------------
__global__ void k_xmat(const int* __restrict__ user_idx, const int* __restrict__ ctx_idx,
                       const float* __restrict__ user_emb, const float* __restrict__ g2,
                       unsigned short* __restrict__ xb) {
  const int b = blockIdx.x;
  const int k = threadIdx.x;  // 0..255
  float v;
  if (k < 64) {
    v = user_emb[(size_t)user_idx[b] * 64 + k];
  } else {
    const int c = (k - 64) >> 6;
    v = g2[(size_t)ctx_idx[b * 3 + c] * 64 + (k & 63)];
  }
  xb[(size_t)(k >> 5) * (512 * 32) + b * 32 + (k & 31)] = f2bf(v);
}

// ---------------- final FC via MFMA, A-persistent, double-buffered LDS, NT hints ---
__global__ __launch_bounds__(512) void k_fc(const unsigned short* __restrict__ xb,
                                            const float* __restrict__ fc_w,
                                            const float* __restrict__ fc_b,
                                            float* __restrict__ out, int NSRV,
                                            int ntiles, int gstride) {
  __shared__ __align__(16) unsigned short Blds[2][32 * 264];  // 33 KB

  const int tid = threadIdx.x;
  const int w = tid >> 6;
  const int lane = tid & 63;
  const int l15 = lane & 15;
  const int kg = lane >> 4;

  if (blockIdx.x >= (unsigned)ntiles) return;

  // persistent A fragments (serve as the MFMA *B* operand after the swap)
  short8 afr[4][8];
#pragma unroll
  for (int mf = 0; mf < 4; ++mf) {
    const int row = w * 64 + mf * 16 + l15;
#pragma unroll
    for (int ks = 0; ks < 8; ++ks) {
      afr[mf][ks] = *(const short8*)(xb + (size_t)ks * 16384 + row * 32 + kg * 8);
    }
  }

  const int sc = tid & 31;   // stage: col in tile
  const int sk = tid >> 5;   // stage: k row 0..15

  float v[16];
  auto loadv = [&](int t) {
    const int cg = t * 32 + sc;
    const bool okc = cg < NSRV;
#pragma unroll
    for (int i = 0; i < 16; ++i)
      v[i] = okc ? __builtin_nontemporal_load(fc_w + (size_t)(sk + i * 16) * NSRV + cg) : 0.f;
  };
  auto writev = [&](int buf) {
#pragma unroll
    for (int i = 0; i < 16; ++i)
      Blds[buf][sc * 264 + sk + i * 16] = f2bf(v[i]);
  };

  // prologue: tile t0 staged, loads for t0+gs in flight
  loadv(blockIdx.x);
  writev(0);
  if (blockIdx.x + gstride < ntiles) loadv(blockIdx.x + gstride);
  __syncthreads();

  int cur = 0;
  for (int t = blockIdx.x; t < ntiles; t += gstride) {
    if (t + gstride < ntiles) writev(cur ^ 1);
    if (t + 2 * gstride < ntiles) loadv(t + 2 * gstride);
    const int j0 = t * 32;
#pragma unroll
    for (int nf = 0; nf < 2; ++nf) {
      short8 bfr[8];
#pragma unroll
      for (int ks = 0; ks < 8; ++ks)
        bfr[ks] = *(const short8*)&Blds[cur][(nf * 16 + l15) * 264 + ks * 32 + kg * 8];
      f32x4 acc[4];
#pragma unroll
      for (int mf = 0; mf < 4; ++mf) acc[mf] = (f32x4){0.f, 0.f, 0.f, 0.f};
#pragma unroll
      for (int ks = 0; ks < 8; ++ks)
#pragma unroll
        for (int mf = 0; mf < 4; ++mf)
          acc[mf] = __builtin_amdgcn_mfma_f32_16x16x32_bf16(bfr[ks], afr[mf][ks], acc[mf], 0, 0, 0);
      const int jc = j0 + nf * 16 + kg * 4;
      if (j0 + 32 <= NSRV) {
        const float4 bias = *(const float4*)(fc_b + jc);
#pragma unroll
        for (int mf = 0; mf < 4; ++mf) {
          const int row = w * 64 + mf * 16 + l15;
          f32x4 o;
          o[0] = acc[mf][0] + bias.x;
          o[1] = acc[mf][1] + bias.y;
          o[2] = acc[mf][2] + bias.z;
          o[3] = acc[mf][3] + bias.w;
          __builtin_nontemporal_store(o, (f32x4*)(out + (size_t)row * NSRV + jc));
        }
      } else {
#pragma unroll
        for (int mf = 0; mf < 4; ++mf) {
          const int row = w * 64 + mf * 16 + l15;
#pragma unroll
          for (int r = 0; r < 4; ++r) {
            const int j = jc + r;
            if (j < NSRV) out[(size_t)row * NSRV + j] = acc[mf][r] + fc_b[j];
          }
        }
      }
    }
    __syncthreads();
    cur ^= 1;
  }
}

// =====================================================================
extern "C" void kernel_launch(void* const* d_in, const int* in_sizes, int n_in,
                              void* d_out, int out_size, void* d_ws, size_t ws_size,
                              hipStream_t stream) {
  const int* user_idx    = (const int*)d_in[0];
  const int* context_idx = (const int*)d_in[1];
  const int* edge_index  = (const int*)d_in[2];
  const float* user_emb  = (const float*)d_in[3];
  const float* service_emb = (const float*)d_in[4];
  const float* W1        = (const float*)d_in[5];
  const float* att_src1  = (const float*)d_in[6];
  const float* att_dst1  = (const float*)d_in[7];
  const float* b1        = (const float*)d_in[8];
  const float* W2        = (const float*)d_in[9];
  const float* att_src2  = (const float*)d_in[10];
  const float* att_dst2  = (const float*)d_in[11];
  const float* b2        = (const float*)d_in[12];
  const float* fc_w      = (const float*)d_in[13];
  const float* fc_b      = (const float*)d_in[14];
  float* out = (float*)d_out;

  const int B    = in_sizes[0];
  const int E    = in_sizes[2] / 2;
  const int N    = in_sizes[4] / 64;
  const int NSRV = in_sizes[14];
  const int Etot = E + N;
  const int NCTX = in_sizes[1];  // B*CTX
  (void)B;

  const int* edge_src = edge_index;
  const int* edge_dst = edge_index + E;

  // ---- workspace layout ----
  char* ws = (char*)d_ws;
  size_t off = 0;
  auto alloc = [&](size_t bytes) {
    void* p = ws + off;
    off = (off + bytes + 255) & ~(size_t)255;
    return p;
  };
  const int NB = (N + NPB - 1) >> NPB_SH;   // 196 for N=100000 (requires <=256)
  unsigned short* h1 = (unsigned short*)alloc((size_t)N * 128 * 2);  // reused as h2
  float* g      = (float*)alloc((size_t)N * 128 * 4);                // reused as g2
  float* as1    = (float*)alloc((size_t)N * 2 * 4);
  float* ad1    = (float*)alloc((size_t)N * 2 * 4);
  float* as2    = (float*)alloc((size_t)N * 4);
  float* ad2    = (float*)alloc((size_t)N * 4);
  int*   rowptr = (int*)alloc((size_t)(N + 1) * 4);
  int*   adj    = (int*)alloc((size_t)Etot * 4);
  unsigned* rec = (unsigned*)alloc((size_t)NB * BCAP * 4);
  int* bucketBase   = (int*)alloc(257 * 4);
  int* bucketCursor = (int*)alloc(256 * 4);
  int* flagC  = (int*)alloc((size_t)N * 4);
  int* flag1  = (int*)alloc((size_t)N * 4);
  int* listC  = (int*)alloc((size_t)NCTX * 4);
  int* list1  = (int*)alloc((size_t)N * 4);
  int* cnt    = (int*)alloc(2 * 4);
  unsigned short* xb = (unsigned short*)alloc((size_t)512 * 256 * 2);
  unsigned short* h2 = h1;
  float* g2 = g;
  (void)ws_size;

  const int NBLK2 = 256;
  const int epb = (Etot + NBLK2 - 1) / NBLK2;
  const int nblk_N = (N + 255) / 256;

  // combined init (bucket cursors + frontier flags)
  k_init<<<nblk_N, 256, 0, stream>>>(bucketCursor, NB, flagC, flag1, cnt, N);

  // GAT layer 1 linear (full N — sources cover ~99% of nodes)
  k_h1<<<(N + 31) / 32, 256, 0, stream>>>(service_emb, W1, att_src1, att_dst1, h1, as1, ad1, N);

  // CSR build (binned, fixed-capacity regions)
  k_bscatter<<<NBLK2, 1024, 0, stream>>>(edge_src, edge_dst, E, Etot, epb, bucketCursor, rec, NB);
  k_bscan2<<<1, 256, 0, stream>>>(bucketCursor, bucketBase, NB, Etot, rowptr, N);
  k_bcsr<<<NB, 1024, 0, stream>>>(rec, bucketBase, rowptr, adj, N, NB);

  // demand-driven frontier: C = ctx nodes; S1 = C ∪ in-neighbors(C)
  k_markC<<<(NCTX + 255) / 256, 256, 0, stream>>>(context_idx, NCTX, flagC, flag1, listC, list1, cnt);
  k_markS1<<<(NCTX + 255) / 256, 256, 0, stream>>>(listC, rowptr, adj, flag1, list1, cnt);

  // layer 1 aggregate -> g (elu'd), only for list1 nodes
  k_gat1<<<(N + 3) / 4, 256, 0, stream>>>(h1, as1, ad1, rowptr, adj, b1, g, list1, cnt);

  // layer 2 linear (h2 overlays h1), only for list1 nodes
  k_h2<<<(N + 31) / 32, 256, 0, stream>>>(g, W2, att_src2, att_dst2, h2, as2, ad2, list1, cnt);

  // layer 2 aggregate -> g2 (overlays g), only for C nodes
  k_gat2<<<(NCTX + 3) / 4, 256, 0, stream>>>(h2, as2, ad2, rowptr, adj, b2, g2, listC, cnt);

  // gather features -> bf16 K-blocked
  k_xmat<<<512, 256, 0, stream>>>(user_idx, context_idx, user_emb, g2, xb);

  // final FC (MFMA, A-persistent, double-buffered 32-col grid-strided tiles)
  const int nfct = (NSRV + 31) / 32;
  const int grid = 512;
  k_fc<<<grid, 512, 0, stream>>>(xb, fc_w, fc_b, out, NSRV, nfct, grid);
}